// Round 1
// baseline (885.055 us; speedup 1.0000x reference)
//
#include <hip/hip_runtime.h>

#define CC 256
#define HWN 1024
#define NTOKN 2048
#define EPSV 1e-5f

// ---------------- transpose (R,Cd) -> (Cd,R), batched ----------------
__global__ __launch_bounds__(256) void k_transpose(const float* __restrict__ in,
                                                   float* __restrict__ out, int R, int Cd) {
    __shared__ float tile[32][33];
    int b = blockIdx.z;
    int r0 = blockIdx.y * 32, c0 = blockIdx.x * 32;
    int tx = threadIdx.x, ty = threadIdx.y; // 32 x 8
    const float* inb = in + (size_t)b * R * Cd;
    float* outb = out + (size_t)b * R * Cd;
#pragma unroll
    for (int i = 0; i < 32; i += 8)
        tile[ty + i][tx] = inb[(size_t)(r0 + ty + i) * Cd + c0 + tx];
    __syncthreads();
#pragma unroll
    for (int i = 0; i < 32; i += 8)
        outb[(size_t)(c0 + ty + i) * R + r0 + tx] = tile[tx][ty + i];
}

// ---------------- tiled fp32 matmul: C = epi(A[M,K] @ W[K,N]) ----------------
// ACT: 0 none, 1 relu, 2 sigmoid, 3 gate: out = res*(1+sigmoid(acc+bias))
// for ACT!=3, res (if non-null) is added after activation.
template <int ACT>
__global__ __launch_bounds__(256) void k_matmul(const float* __restrict__ A,
                                                const float* __restrict__ W,
                                                const float* __restrict__ bias,
                                                const float* __restrict__ res,
                                                float* __restrict__ Cp,
                                                int M, int N, int K) {
    __shared__ float As[16][68]; // [k][row], padded: 272B rows (16B aligned, banks spread)
    __shared__ float Bs[16][64]; // [k][col]
    int tid = threadIdx.x;
    int tx = tid & 15, ty = tid >> 4;
    int row0 = blockIdx.y * 64, col0 = blockIdx.x * 64;
    float acc[4][4] = {};
    for (int k0 = 0; k0 < K; k0 += 16) {
#pragma unroll
        for (int l = 0; l < 4; l++) {
            int idx = tid + l * 256;
            int r = idx >> 4, kk = idx & 15;
            int gr = row0 + r, gk = k0 + kk;
            As[kk][r] = (gr < M && gk < K) ? A[(size_t)gr * K + gk] : 0.f;
        }
#pragma unroll
        for (int l = 0; l < 4; l++) {
            int idx = tid + l * 256;
            int kk = idx >> 6, c = idx & 63;
            int gk = k0 + kk, gc = col0 + c;
            Bs[kk][c] = (gk < K && gc < N) ? W[(size_t)gk * N + gc] : 0.f;
        }
        __syncthreads();
#pragma unroll
        for (int kk = 0; kk < 16; kk++) {
            float4 a4 = *(const float4*)&As[kk][ty * 4];
            float4 b4 = *(const float4*)&Bs[kk][tx * 4];
            float av[4] = {a4.x, a4.y, a4.z, a4.w};
            float bv[4] = {b4.x, b4.y, b4.z, b4.w};
#pragma unroll
            for (int i = 0; i < 4; i++)
#pragma unroll
                for (int j = 0; j < 4; j++)
                    acc[i][j] = fmaf(av[i], bv[j], acc[i][j]);
        }
        __syncthreads();
    }
#pragma unroll
    for (int i = 0; i < 4; i++) {
        int r = row0 + ty * 4 + i;
        if (r >= M) continue;
#pragma unroll
        for (int j = 0; j < 4; j++) {
            int c = col0 + tx * 4 + j;
            if (c >= N) continue;
            float v = acc[i][j];
            if (bias) v += bias[c];
            if (ACT == 1) v = fmaxf(v, 0.f);
            if (ACT == 2) v = 1.f / (1.f + __expf(-v));
            if (ACT == 3) {
                float s = 1.f / (1.f + __expf(-v));
                v = res[(size_t)r * N + c] * (1.f + s);
            } else if (res) {
                v += res[(size_t)r * N + c];
            }
            Cp[(size_t)r * N + c] = v;
        }
    }
}

// ---------------- group-norm stats: in (NTOK,C) token-major -> mean,rstd per (b,g) ----------------
__global__ __launch_bounds__(256) void k_gstats(const float* __restrict__ in, float* __restrict__ stats) {
    int bg = blockIdx.x; // 0..63
    int b = bg >> 5, g = bg & 31;
    int tid = threadIdx.x;
    float s = 0.f, s2 = 0.f;
    for (int idx = tid; idx < HWN * 8; idx += 256) {
        int t = idx >> 3, cc = idx & 7;
        float v = in[(size_t)(b * HWN + t) * CC + g * 8 + cc];
        s += v;
        s2 += v * v;
    }
    __shared__ float sh[2][256];
    sh[0][tid] = s; sh[1][tid] = s2;
    __syncthreads();
    for (int off = 128; off > 0; off >>= 1) {
        if (tid < off) { sh[0][tid] += sh[0][tid + off]; sh[1][tid] += sh[1][tid + off]; }
        __syncthreads();
    }
    if (tid == 0) {
        float mean = sh[0][0] * (1.f / (HWN * 8));
        float var = sh[1][0] * (1.f / (HWN * 8)) - mean * mean;
        stats[bg * 2] = mean;
        stats[bg * 2 + 1] = rsqrtf(var + EPSV);
    }
}

__global__ __launch_bounds__(256) void k_gnorm_apply(const float* __restrict__ in,
                                                     const float* __restrict__ stats,
                                                     const float* __restrict__ w,
                                                     const float* __restrict__ bb,
                                                     float* __restrict__ out) {
    int idx = blockIdx.x * 256 + threadIdx.x; // over NTOK*C, c fast
    int c = idx & 255;
    int t = idx >> 8;
    int b = t >> 10;
    int g = c >> 3;
    float mean = stats[(b * 32 + g) * 2], rstd = stats[(b * 32 + g) * 2 + 1];
    out[idx] = (in[idx] - mean) * rstd * w[c] + bb[c];
}

// ---------------- halo patch gather: p[blk*196+pos][c] ----------------
__global__ __launch_bounds__(256) void k_patch(const float* __restrict__ xT, float* __restrict__ p) {
    int rowid = blockIdx.x; // 0..6271
    int blk = rowid / 196, pos = rowid % 196;
    int b = blk >> 4, hb = (blk >> 2) & 3, wb = blk & 3;
    int i = pos / 14, j = pos % 14;
    int y = hb * 8 + i - 3, xx = wb * 8 + j - 3;
    int c = threadIdx.x;
    float v = 0.f;
    if (y >= 0 && y < 32 && xx >= 0 && xx < 32)
        v = xT[(size_t)(b * HWN + y * 32 + xx) * CC + c];
    p[(size_t)rowid * CC + c] = v;
}

// ---------------- full attention (seq=1024, d=16, 16 heads) ----------------
// qkv rows token-major (NTOK,768): q at h*16, k at 256+h*16, v at 512+h*16
__global__ __launch_bounds__(128) void k_attn_full(const float* __restrict__ qkv, float* __restrict__ out) {
    int bh = blockIdx.x; // 0..31
    int b = bh >> 4, h = bh & 15;
    int tid = threadIdx.x;
    int t = blockIdx.y * 128 + tid;
    const float* base = qkv + (size_t)b * HWN * 768;
    float q[16];
    {
        const float4* qp = (const float4*)(base + (size_t)t * 768 + h * 16);
#pragma unroll
        for (int i = 0; i < 4; i++) {
            float4 v = qp[i];
            q[i * 4] = v.x; q[i * 4 + 1] = v.y; q[i * 4 + 2] = v.z; q[i * 4 + 3] = v.w;
        }
    }
    float m = -1e30f, l = 0.f, acc[16] = {};
    __shared__ float Ks[64][16];
    __shared__ float Vs[64][16];
    for (int k0 = 0; k0 < HWN; k0 += 64) {
        __syncthreads();
#pragma unroll
        for (int ld = 0; ld < 2; ld++) {
            int idx = tid + ld * 128;
            int kk = idx >> 2, part = idx & 3;
            const float* rowp = base + (size_t)(k0 + kk) * 768 + h * 16 + part * 4;
            *(float4*)&Ks[kk][part * 4] = *(const float4*)(rowp + 256);
            *(float4*)&Vs[kk][part * 4] = *(const float4*)(rowp + 512);
        }
        __syncthreads();
        for (int kk = 0; kk < 64; kk++) {
            float s = 0.f;
#pragma unroll
            for (int dd = 0; dd < 16; dd++) s = fmaf(q[dd], Ks[kk][dd], s);
            s *= 0.25f;
            if (s <= m) {
                float e = __expf(s - m);
                l += e;
#pragma unroll
                for (int dd = 0; dd < 16; dd++) acc[dd] = fmaf(e, Vs[kk][dd], acc[dd]);
            } else {
                float corr = __expf(m - s);
                l = fmaf(l, corr, 1.f);
#pragma unroll
                for (int dd = 0; dd < 16; dd++) acc[dd] = fmaf(acc[dd], corr, Vs[kk][dd]);
                m = s;
            }
        }
    }
    float inv = 1.f / l;
    float4* op = (float4*)(out + (size_t)(b * HWN + t) * CC + h * 16);
#pragma unroll
    for (int i = 0; i < 4; i++)
        op[i] = make_float4(acc[i * 4] * inv, acc[i * 4 + 1] * inv, acc[i * 4 + 2] * inv, acc[i * 4 + 3] * inv);
}

// ---------------- halo attention: 32 blocks x 16 heads, 64 center q, 196 k ----------------
__global__ __launch_bounds__(64) void k_attn_halo(const float* __restrict__ qkv, float* __restrict__ out) {
    int blk = blockIdx.x; // 0..31
    int h = blockIdx.y;   // 0..15
    int tid = threadIdx.x;
    __shared__ float Ks[196][16];
    __shared__ float Vs[196][16];
    const float* base = qkv + (size_t)blk * 196 * 768;
    for (int idx = tid; idx < 196 * 4; idx += 64) {
        int kk = idx >> 2, part = idx & 3;
        const float* rowp = base + (size_t)kk * 768 + h * 16 + part * 4;
        *(float4*)&Ks[kk][part * 4] = *(const float4*)(rowp + 256);
        *(float4*)&Vs[kk][part * 4] = *(const float4*)(rowp + 512);
    }
    __syncthreads();
    int ci = tid >> 3, cj = tid & 7;
    int cpos = (3 + ci) * 14 + (3 + cj);
    float q[16];
    {
        const float4* qp = (const float4*)(base + (size_t)cpos * 768 + h * 16);
#pragma unroll
        for (int i = 0; i < 4; i++) {
            float4 v = qp[i];
            q[i * 4] = v.x; q[i * 4 + 1] = v.y; q[i * 4 + 2] = v.z; q[i * 4 + 3] = v.w;
        }
    }
    float m = -1e30f, l = 0.f, acc[16] = {};
    for (int kk = 0; kk < 196; kk++) {
        float s = 0.f;
#pragma unroll
        for (int dd = 0; dd < 16; dd++) s = fmaf(q[dd], Ks[kk][dd], s);
        s *= 0.25f;
        if (s <= m) {
            float e = __expf(s - m);
            l += e;
#pragma unroll
            for (int dd = 0; dd < 16; dd++) acc[dd] = fmaf(e, Vs[kk][dd], acc[dd]);
        } else {
            float corr = __expf(m - s);
            l = fmaf(l, corr, 1.f);
#pragma unroll
            for (int dd = 0; dd < 16; dd++) acc[dd] = fmaf(acc[dd], corr, Vs[kk][dd]);
            m = s;
        }
    }
    float inv = 1.f / l;
    int b = blk >> 4, hb = (blk >> 2) & 3, wb = blk & 3;
    int t = (hb * 8 + ci) * 32 + wb * 8 + cj;
    float4* op = (float4*)(out + (size_t)(b * HWN + t) * CC + h * 16);
#pragma unroll
    for (int i = 0; i < 4; i++)
        op[i] = make_float4(acc[i * 4] * inv, acc[i * 4 + 1] * inv, acc[i * 4 + 2] * inv, acc[i * 4 + 3] * inv);
}

// ---------------- weighted combine ----------------
__global__ __launch_bounds__(256) void k_combine(const float* __restrict__ sp, const float* __restrict__ ha,
                                                 const float* __restrict__ qo, const float* __restrict__ ro,
                                                 const float* __restrict__ aw, float* __restrict__ comb) {
    int idx = blockIdx.x * 256 + threadIdx.x;
    float a0 = aw[0], a1 = aw[1], a2 = aw[2], a3 = aw[3];
    float mx = fmaxf(fmaxf(a0, a1), fmaxf(a2, a3));
    float e0 = __expf(a0 - mx), e1 = __expf(a1 - mx), e2 = __expf(a2 - mx), e3 = __expf(a3 - mx);
    float inv = 1.f / (e0 + e1 + e2 + e3);
    comb[idx] = (sp[idx] * e0 + ha[idx] * e1 + qo[idx] * e2 + ro[idx] * e3) * inv;
}

extern "C" void kernel_launch(void* const* d_in, const int* in_sizes, int n_in,
                              void* d_out, int out_size, void* d_ws, size_t ws_size,
                              hipStream_t stream) {
    const float* x        = (const float*)d_in[0];
    const float* sa_w1    = (const float*)d_in[1];
    const float* sa_b1    = (const float*)d_in[2];
    const float* sa_w2    = (const float*)d_in[3];
    const float* sa_b2    = (const float*)d_in[4];
    const float* sa_gn_w  = (const float*)d_in[5];
    const float* sa_gn_b  = (const float*)d_in[6];
    const float* ha_qkv_w = (const float*)d_in[7];
    const float* ha_proj_w= (const float*)d_in[8];
    const float* ha_proj_b= (const float*)d_in[9];
    const float* ra_gn_w  = (const float*)d_in[10];
    const float* ra_gn_b  = (const float*)d_in[11];
    const float* ra_qkv_w = (const float*)d_in[12];
    const float* ra_proj_w= (const float*)d_in[13];
    const float* ra_proj_b= (const float*)d_in[14];
    const float* gn_w     = (const float*)d_in[15];
    const float* gn_b     = (const float*)d_in[16];
    const float* toqkv_w  = (const float*)d_in[17];
    const float* toqkv_b  = (const float*)d_in[18];
    const float* attn_w   = (const float*)d_in[19];
    const float* proj_w   = (const float*)d_in[20];
    const float* proj_b   = (const float*)d_in[21];
    float* out = (float*)d_out;

    float* ws = (float*)d_ws;
    size_t off = 0;
    float* xT   = ws + off; off += 524288;
    float* sp   = ws + off; off += 524288;
    float* xn   = ws + off; off += 524288; // reused as comb (xn dead after qkv_ra)
    float* nf   = ws + off; off += 524288; // reused as out_tok (nf dead after qkv_g)
    float* ha   = ws + off; off += 524288;
    float* ro   = ws + off; off += 524288;
    float* qo   = ws + off; off += 524288;
    float* abuf = ws + off; off += 524288;
    float* stats= ws + off; off += 256;     // [0..128) sp stats, [128..256) x stats
    float* big0 = ws + off; off += 4816896; // qkv_ha; later qkv_ra (0) + qkv_g (+1572864)
    float* big1 = ws + off; off += 1605632; // pbuf; later s1 (0) + spre (+65536)
    float* comb = xn;
    float* otok = nf;
    float* qkv_ha = big0;
    float* qkv_ra = big0;
    float* qkv_g  = big0 + 1572864;
    float* pbuf = big1;
    float* s1   = big1;
    float* spre = big1 + 65536;

    dim3 blk256(256), blkT(32, 8);

    // x (B,256,1024) -> xT (B,1024,256) token-major
    k_transpose<<<dim3(32, 8, 2), blkT, 0, stream>>>(x, xT, 256, 1024);

    // ---- halo branch ----
    k_patch<<<dim3(6272), blk256, 0, stream>>>(xT, pbuf);
    k_matmul<0><<<dim3(12, 98), blk256, 0, stream>>>(pbuf, ha_qkv_w, nullptr, nullptr, qkv_ha, 6272, 768, 256);
    k_attn_halo<<<dim3(32, 16), dim3(64), 0, stream>>>(qkv_ha, abuf);
    k_matmul<0><<<dim3(4, 32), blk256, 0, stream>>>(abuf, ha_proj_w, ha_proj_b, nullptr, ha, 2048, 256, 256);

    // ---- spatial branch ----
    k_matmul<1><<<dim3(1, 32), blk256, 0, stream>>>(xT, sa_w1, sa_b1, nullptr, s1, 2048, 32, 256);
    k_matmul<3><<<dim3(4, 32), blk256, 0, stream>>>(s1, sa_w2, sa_b2, xT, spre, 2048, 256, 32);
    k_gstats<<<dim3(64), blk256, 0, stream>>>(spre, stats);
    k_gnorm_apply<<<dim3(2048), blk256, 0, stream>>>(spre, stats, sa_gn_w, sa_gn_b, sp);

    // ---- shared gnorm stats of x; two affines ----
    k_gstats<<<dim3(64), blk256, 0, stream>>>(xT, stats + 128);
    k_gnorm_apply<<<dim3(2048), blk256, 0, stream>>>(xT, stats + 128, ra_gn_w, ra_gn_b, xn);
    k_gnorm_apply<<<dim3(2048), blk256, 0, stream>>>(xT, stats + 128, gn_w, gn_b, nf);

    // ---- rotation branch (all 4 rotations identical by permutation equivariance) ----
    k_matmul<0><<<dim3(12, 32), blk256, 0, stream>>>(xn, ra_qkv_w, nullptr, nullptr, qkv_ra, 2048, 768, 256);
    k_attn_full<<<dim3(32, 8), dim3(128), 0, stream>>>(qkv_ra, abuf);
    k_matmul<0><<<dim3(4, 32), blk256, 0, stream>>>(abuf, ra_proj_w, ra_proj_b, xT, ro, 2048, 256, 256);

    // ---- global branch ----
    k_matmul<0><<<dim3(12, 32), blk256, 0, stream>>>(nf, toqkv_w, toqkv_b, nullptr, qkv_g, 2048, 768, 256);
    k_attn_full<<<dim3(32, 8), dim3(128), 0, stream>>>(qkv_g, qo);

    // ---- combine + final proj + residual ----
    k_combine<<<dim3(2048), blk256, 0, stream>>>(sp, ha, qo, ro, attn_w, comb);
    k_matmul<0><<<dim3(4, 32), blk256, 0, stream>>>(comb, proj_w, proj_b, xT, otok, 2048, 256, 256);
    k_transpose<<<dim3(8, 32, 2), blkT, 0, stream>>>(otok, out, 1024, 256);
}

// Round 4
// 605.590 us; speedup vs baseline: 1.4615x; 1.4615x over previous
//
#include <hip/hip_runtime.h>

#define CC 256
#define HWN 1024
#define EPSV 1e-5f
#define KSPLIT 4

// ---------------- transpose (R,Cd) -> (Cd,R), batched ----------------
__global__ __launch_bounds__(256) void k_transpose(const float* __restrict__ in,
                                                   float* __restrict__ out, int R, int Cd) {
    __shared__ float tile[32][33];
    int b = blockIdx.z;
    int r0 = blockIdx.y * 32, c0 = blockIdx.x * 32;
    int tx = threadIdx.x, ty = threadIdx.y; // 32 x 8
    const float* inb = in + (size_t)b * R * Cd;
    float* outb = out + (size_t)b * R * Cd;
#pragma unroll
    for (int i = 0; i < 32; i += 8)
        tile[ty + i][tx] = inb[(size_t)(r0 + ty + i) * Cd + c0 + tx];
    __syncthreads();
#pragma unroll
    for (int i = 0; i < 32; i += 8)
        outb[(size_t)(c0 + ty + i) * R + r0 + tx] = tile[tx][ty + i];
}

// ---------------- tiled fp32 matmul: C = epi(A[M,K] @ W[K,N]) ----------------
// ACT: 0 none, 1 relu, 2 sigmoid, 3 gate: out = res*(1+sigmoid(acc+bias))
template <int ACT>
__global__ __launch_bounds__(256) void k_matmul(const float* __restrict__ A,
                                                const float* __restrict__ W,
                                                const float* __restrict__ bias,
                                                const float* __restrict__ res,
                                                float* __restrict__ Cp,
                                                int M, int N, int K) {
    __shared__ float As[16][68];
    __shared__ float Bs[16][64];
    int tid = threadIdx.x;
    int tx = tid & 15, ty = tid >> 4;
    int row0 = blockIdx.y * 64, col0 = blockIdx.x * 64;
    float acc[4][4] = {};
    for (int k0 = 0; k0 < K; k0 += 16) {
#pragma unroll
        for (int l = 0; l < 4; l++) {
            int idx = tid + l * 256;
            int r = idx >> 4, kk = idx & 15;
            int gr = row0 + r, gk = k0 + kk;
            As[kk][r] = (gr < M && gk < K) ? A[(size_t)gr * K + gk] : 0.f;
        }
#pragma unroll
        for (int l = 0; l < 4; l++) {
            int idx = tid + l * 256;
            int kk = idx >> 6, c = idx & 63;
            int gk = k0 + kk, gc = col0 + c;
            Bs[kk][c] = (gk < K && gc < N) ? W[(size_t)gk * N + gc] : 0.f;
        }
        __syncthreads();
#pragma unroll
        for (int kk = 0; kk < 16; kk++) {
            float4 a4 = *(const float4*)&As[kk][ty * 4];
            float4 b4 = *(const float4*)&Bs[kk][tx * 4];
            float av[4] = {a4.x, a4.y, a4.z, a4.w};
            float bv[4] = {b4.x, b4.y, b4.z, b4.w};
#pragma unroll
            for (int i = 0; i < 4; i++)
#pragma unroll
                for (int j = 0; j < 4; j++)
                    acc[i][j] = fmaf(av[i], bv[j], acc[i][j]);
        }
        __syncthreads();
    }
#pragma unroll
    for (int i = 0; i < 4; i++) {
        int r = row0 + ty * 4 + i;
        if (r >= M) continue;
#pragma unroll
        for (int j = 0; j < 4; j++) {
            int c = col0 + tx * 4 + j;
            if (c >= N) continue;
            float v = acc[i][j];
            if (bias) v += bias[c];
            if (ACT == 1) v = fmaxf(v, 0.f);
            if (ACT == 2) v = 1.f / (1.f + __expf(-v));
            if (ACT == 3) {
                float s = 1.f / (1.f + __expf(-v));
                v = res[(size_t)r * N + c] * (1.f + s);
            } else if (res) {
                v += res[(size_t)r * N + c];
            }
            Cp[(size_t)r * N + c] = v;
        }
    }
}

// ---------------- group-norm stats ----------------
__global__ __launch_bounds__(256) void k_gstats(const float* __restrict__ in, float* __restrict__ stats) {
    int bg = blockIdx.x;
    int b = bg >> 5, g = bg & 31;
    int tid = threadIdx.x;
    float s = 0.f, s2 = 0.f;
    for (int idx = tid; idx < HWN * 8; idx += 256) {
        int t = idx >> 3, cc = idx & 7;
        float v = in[(size_t)(b * HWN + t) * CC + g * 8 + cc];
        s += v;
        s2 += v * v;
    }
    __shared__ float sh[2][256];
    sh[0][tid] = s; sh[1][tid] = s2;
    __syncthreads();
    for (int off = 128; off > 0; off >>= 1) {
        if (tid < off) { sh[0][tid] += sh[0][tid + off]; sh[1][tid] += sh[1][tid + off]; }
        __syncthreads();
    }
    if (tid == 0) {
        float mean = sh[0][0] * (1.f / (HWN * 8));
        float var = sh[1][0] * (1.f / (HWN * 8)) - mean * mean;
        stats[bg * 2] = mean;
        stats[bg * 2 + 1] = rsqrtf(var + EPSV);
    }
}

__global__ __launch_bounds__(256) void k_gnorm_apply(const float* __restrict__ in,
                                                     const float* __restrict__ stats,
                                                     const float* __restrict__ w,
                                                     const float* __restrict__ bb,
                                                     float* __restrict__ out) {
    int idx = blockIdx.x * 256 + threadIdx.x;
    int c = idx & 255;
    int t = idx >> 8;
    int b = t >> 10;
    int g = c >> 3;
    float mean = stats[(b * 32 + g) * 2], rstd = stats[(b * 32 + g) * 2 + 1];
    out[idx] = (in[idx] - mean) * rstd * w[c] + bb[c];
}

// ---------------- halo patch gather ----------------
__global__ __launch_bounds__(256) void k_patch(const float* __restrict__ xT, float* __restrict__ p) {
    int rowid = blockIdx.x;
    int blk = rowid / 196, pos = rowid % 196;
    int b = blk >> 4, hb = (blk >> 2) & 3, wb = blk & 3;
    int i = pos / 14, j = pos % 14;
    int y = hb * 8 + i - 3, xx = wb * 8 + j - 3;
    int c = threadIdx.x;
    float v = 0.f;
    if (y >= 0 && y < 32 && xx >= 0 && xx < 32)
        v = xT[(size_t)(b * HWN + y * 32 + xx) * CC + c];
    p[(size_t)rowid * CC + c] = v;
}

// ---------------- full attention, restructured ----------------
// Branchless softmax (no max subtraction: |scores*scale| < ~6, exp safe in fp32).
// Grid (32 bh, 2 qchunk, KSPLIT). 256 thr, 2 queries/thread. Partials out.
__global__ __launch_bounds__(256) void k_attn_full2(const float* __restrict__ qkv,
                                                    float* __restrict__ pacc,
                                                    float* __restrict__ pl) {
    int bh = blockIdx.x;
    int b = bh >> 4, h = bh & 15;
    int tid = threadIdx.x;
    int q0 = blockIdx.y * 512 + tid; // and q0+256
    int ks = blockIdx.z;
    const float* base = qkv + (size_t)b * HWN * 768 + h * 16;
    float q[2][16];
#pragma unroll
    for (int w = 0; w < 2; w++) {
        const float4* qp = (const float4*)(base + (size_t)(q0 + w * 256) * 768);
#pragma unroll
        for (int i = 0; i < 4; i++) {
            float4 v = qp[i];
            q[w][i * 4] = v.x; q[w][i * 4 + 1] = v.y; q[w][i * 4 + 2] = v.z; q[w][i * 4 + 3] = v.w;
        }
    }
    float l[2] = {0.f, 0.f};
    float acc[2][16] = {};
    __shared__ float Ks[64][16];
    __shared__ float Vs[64][16];
    int kbase = ks * (HWN / KSPLIT);
    for (int t = 0; t < (HWN / KSPLIT) / 64; t++) {
        __syncthreads();
        {
            int kk = tid >> 2, part = tid & 3;
            const float* rowp = base + (size_t)(kbase + t * 64 + kk) * 768 + part * 4;
            *(float4*)&Ks[kk][part * 4] = *(const float4*)(rowp + 256);
            *(float4*)&Vs[kk][part * 4] = *(const float4*)(rowp + 512);
        }
        __syncthreads();
        for (int k4 = 0; k4 < 64; k4 += 4) {
            float s[2][4] = {};
#pragma unroll
            for (int j = 0; j < 4; j++) {
                const float4* kp = (const float4*)&Ks[k4 + j][0];
#pragma unroll
                for (int i = 0; i < 4; i++) {
                    float4 kv = kp[i];
                    s[0][j] = fmaf(q[0][i * 4], kv.x, s[0][j]);
                    s[0][j] = fmaf(q[0][i * 4 + 1], kv.y, s[0][j]);
                    s[0][j] = fmaf(q[0][i * 4 + 2], kv.z, s[0][j]);
                    s[0][j] = fmaf(q[0][i * 4 + 3], kv.w, s[0][j]);
                    s[1][j] = fmaf(q[1][i * 4], kv.x, s[1][j]);
                    s[1][j] = fmaf(q[1][i * 4 + 1], kv.y, s[1][j]);
                    s[1][j] = fmaf(q[1][i * 4 + 2], kv.z, s[1][j]);
                    s[1][j] = fmaf(q[1][i * 4 + 3], kv.w, s[1][j]);
                }
            }
            float e[2][4];
#pragma unroll
            for (int j = 0; j < 4; j++) {
                e[0][j] = __expf(s[0][j] * 0.25f);
                e[1][j] = __expf(s[1][j] * 0.25f);
            }
            l[0] += (e[0][0] + e[0][1]) + (e[0][2] + e[0][3]);
            l[1] += (e[1][0] + e[1][1]) + (e[1][2] + e[1][3]);
#pragma unroll
            for (int j = 0; j < 4; j++) {
                const float4* vp = (const float4*)&Vs[k4 + j][0];
#pragma unroll
                for (int i = 0; i < 4; i++) {
                    float4 vv = vp[i];
                    acc[0][i * 4]     = fmaf(e[0][j], vv.x, acc[0][i * 4]);
                    acc[0][i * 4 + 1] = fmaf(e[0][j], vv.y, acc[0][i * 4 + 1]);
                    acc[0][i * 4 + 2] = fmaf(e[0][j], vv.z, acc[0][i * 4 + 2]);
                    acc[0][i * 4 + 3] = fmaf(e[0][j], vv.w, acc[0][i * 4 + 3]);
                    acc[1][i * 4]     = fmaf(e[1][j], vv.x, acc[1][i * 4]);
                    acc[1][i * 4 + 1] = fmaf(e[1][j], vv.y, acc[1][i * 4 + 1]);
                    acc[1][i * 4 + 2] = fmaf(e[1][j], vv.z, acc[1][i * 4 + 2]);
                    acc[1][i * 4 + 3] = fmaf(e[1][j], vv.w, acc[1][i * 4 + 3]);
                }
            }
        }
    }
#pragma unroll
    for (int w = 0; w < 2; w++) {
        int qidx = bh * HWN + q0 + w * 256;
        float4* pp = (float4*)&pacc[((size_t)qidx * KSPLIT + ks) * 16];
#pragma unroll
        for (int i = 0; i < 4; i++)
            pp[i] = make_float4(acc[w][i * 4], acc[w][i * 4 + 1], acc[w][i * 4 + 2], acc[w][i * 4 + 3]);
        pl[qidx * KSPLIT + ks] = l[w];
    }
}

__global__ __launch_bounds__(256) void k_attn_comb(const float* __restrict__ pacc,
                                                   const float* __restrict__ pl,
                                                   float* __restrict__ out) {
    int idx = blockIdx.x * 256 + threadIdx.x; // qidx*16 + d
    int qidx = idx >> 4, d = idx & 15;
    float a = 0.f, l = 0.f;
#pragma unroll
    for (int ks = 0; ks < KSPLIT; ks++) {
        a += pacc[((size_t)qidx * KSPLIT + ks) * 16 + d];
        l += pl[qidx * KSPLIT + ks];
    }
    int bh = qidx >> 10, t = qidx & 1023;
    int b = bh >> 4, h = bh & 15;
    out[(size_t)(b * HWN + t) * CC + h * 16 + d] = a / l;
}

// ---------------- halo attention, branchless ----------------
__global__ __launch_bounds__(64) void k_attn_halo(const float* __restrict__ qkv, float* __restrict__ out) {
    int blk = blockIdx.x;
    int h = blockIdx.y;
    int tid = threadIdx.x;
    __shared__ float Ks[196][16];
    __shared__ float Vs[196][16];
    const float* base = qkv + (size_t)blk * 196 * 768 + h * 16;
    for (int idx = tid; idx < 196 * 4; idx += 64) {
        int kk = idx >> 2, part = idx & 3;
        const float* rowp = base + (size_t)kk * 768 + part * 4;
        *(float4*)&Ks[kk][part * 4] = *(const float4*)(rowp + 256);
        *(float4*)&Vs[kk][part * 4] = *(const float4*)(rowp + 512);
    }
    __syncthreads();
    int ci = tid >> 3, cj = tid & 7;
    int cpos = (3 + ci) * 14 + (3 + cj);
    float q[16];
    {
        const float4* qp = (const float4*)(base + (size_t)cpos * 768);
#pragma unroll
        for (int i = 0; i < 4; i++) {
            float4 v = qp[i];
            q[i * 4] = v.x; q[i * 4 + 1] = v.y; q[i * 4 + 2] = v.z; q[i * 4 + 3] = v.w;
        }
    }
    float l = 0.f, acc[16] = {};
    for (int k4 = 0; k4 < 196; k4 += 4) {
        float s[4] = {};
#pragma unroll
        for (int j = 0; j < 4; j++) {
            const float4* kp = (const float4*)&Ks[k4 + j][0];
#pragma unroll
            for (int i = 0; i < 4; i++) {
                float4 kv = kp[i];
                s[j] = fmaf(q[i * 4], kv.x, s[j]);
                s[j] = fmaf(q[i * 4 + 1], kv.y, s[j]);
                s[j] = fmaf(q[i * 4 + 2], kv.z, s[j]);
                s[j] = fmaf(q[i * 4 + 3], kv.w, s[j]);
            }
        }
        float e[4];
#pragma unroll
        for (int j = 0; j < 4; j++) e[j] = __expf(s[j] * 0.25f);
        l += (e[0] + e[1]) + (e[2] + e[3]);
#pragma unroll
        for (int j = 0; j < 4; j++) {
            const float4* vp = (const float4*)&Vs[k4 + j][0];
#pragma unroll
            for (int i = 0; i < 4; i++) {
                float4 vv = vp[i];
                acc[i * 4]     = fmaf(e[j], vv.x, acc[i * 4]);
                acc[i * 4 + 1] = fmaf(e[j], vv.y, acc[i * 4 + 1]);
                acc[i * 4 + 2] = fmaf(e[j], vv.z, acc[i * 4 + 2]);
                acc[i * 4 + 3] = fmaf(e[j], vv.w, acc[i * 4 + 3]);
            }
        }
    }
    float inv = 1.f / l;
    int b = blk >> 4, hb = (blk >> 2) & 3, wb = blk & 3;
    int t = (hb * 8 + ci) * 32 + wb * 8 + cj;
    float4* op = (float4*)(out + (size_t)(b * HWN + t) * CC + h * 16);
#pragma unroll
    for (int i = 0; i < 4; i++)
        op[i] = make_float4(acc[i * 4] * inv, acc[i * 4 + 1] * inv, acc[i * 4 + 2] * inv, acc[i * 4 + 3] * inv);
}

// ---------------- weighted combine ----------------
__global__ __launch_bounds__(256) void k_combine(const float* __restrict__ sp, const float* __restrict__ ha,
                                                 const float* __restrict__ qo, const float* __restrict__ ro,
                                                 const float* __restrict__ aw, float* __restrict__ comb) {
    int idx = blockIdx.x * 256 + threadIdx.x;
    float a0 = aw[0], a1 = aw[1], a2 = aw[2], a3 = aw[3];
    float mx = fmaxf(fmaxf(a0, a1), fmaxf(a2, a3));
    float e0 = __expf(a0 - mx), e1 = __expf(a1 - mx), e2 = __expf(a2 - mx), e3 = __expf(a3 - mx);
    float inv = 1.f / (e0 + e1 + e2 + e3);
    comb[idx] = (sp[idx] * e0 + ha[idx] * e1 + qo[idx] * e2 + ro[idx] * e3) * inv;
}

extern "C" void kernel_launch(void* const* d_in, const int* in_sizes, int n_in,
                              void* d_out, int out_size, void* d_ws, size_t ws_size,
                              hipStream_t stream) {
    const float* x        = (const float*)d_in[0];
    const float* sa_w1    = (const float*)d_in[1];
    const float* sa_b1    = (const float*)d_in[2];
    const float* sa_w2    = (const float*)d_in[3];
    const float* sa_b2    = (const float*)d_in[4];
    const float* sa_gn_w  = (const float*)d_in[5];
    const float* sa_gn_b  = (const float*)d_in[6];
    const float* ha_qkv_w = (const float*)d_in[7];
    const float* ha_proj_w= (const float*)d_in[8];
    const float* ha_proj_b= (const float*)d_in[9];
    const float* ra_gn_w  = (const float*)d_in[10];
    const float* ra_gn_b  = (const float*)d_in[11];
    const float* ra_qkv_w = (const float*)d_in[12];
    const float* ra_proj_w= (const float*)d_in[13];
    const float* ra_proj_b= (const float*)d_in[14];
    const float* gn_w     = (const float*)d_in[15];
    const float* gn_b     = (const float*)d_in[16];
    const float* toqkv_w  = (const float*)d_in[17];
    const float* toqkv_b  = (const float*)d_in[18];
    const float* attn_w   = (const float*)d_in[19];
    const float* proj_w   = (const float*)d_in[20];
    const float* proj_b   = (const float*)d_in[21];
    float* out = (float*)d_out;

    float* ws = (float*)d_ws;
    size_t off = 0;
    float* xT   = ws + off; off += 524288;
    float* sp   = ws + off; off += 524288;
    float* xn   = ws + off; off += 524288;
    float* nf   = ws + off; off += 524288;
    float* ha   = ws + off; off += 524288;
    float* ro   = ws + off; off += 524288;
    float* qo   = ws + off; off += 524288;
    float* abuf = ws + off; off += 524288;
    float* stats= ws + off; off += 256;
    float* big0 = ws + off; off += 4816896;
    float* big1 = ws + off; off += 1605632;
    float* pacc = ws + off; off += 2097152; // 32768 * KSPLIT * 16
    float* pl   = ws + off; off += 131072;  // 32768 * KSPLIT
    float* comb = xn;
    float* otok = nf;
    float* qkv_ha = big0;
    float* qkv_ra = big0;
    float* qkv_g  = big0 + 1572864;
    float* pbuf = big1;
    float* s1   = big1;
    float* spre = big1 + 65536;

    dim3 blk256(256), blkT(32, 8);

    // x (B,256,1024) -> xT (B,1024,256) token-major
    k_transpose<<<dim3(32, 8, 2), blkT, 0, stream>>>(x, xT, 256, 1024);

    // ---- halo branch ----
    k_patch<<<dim3(6272), blk256, 0, stream>>>(xT, pbuf);
    k_matmul<0><<<dim3(12, 98), blk256, 0, stream>>>(pbuf, ha_qkv_w, nullptr, nullptr, qkv_ha, 6272, 768, 256);
    k_attn_halo<<<dim3(32, 16), dim3(64), 0, stream>>>(qkv_ha, abuf);
    k_matmul<0><<<dim3(4, 32), blk256, 0, stream>>>(abuf, ha_proj_w, ha_proj_b, nullptr, ha, 2048, 256, 256);

    // ---- spatial branch ----
    k_matmul<1><<<dim3(1, 32), blk256, 0, stream>>>(xT, sa_w1, sa_b1, nullptr, s1, 2048, 32, 256);
    k_matmul<3><<<dim3(4, 32), blk256, 0, stream>>>(s1, sa_w2, sa_b2, xT, spre, 2048, 256, 32);
    k_gstats<<<dim3(64), blk256, 0, stream>>>(spre, stats);
    k_gnorm_apply<<<dim3(2048), blk256, 0, stream>>>(spre, stats, sa_gn_w, sa_gn_b, sp);

    // ---- shared gnorm stats of x; two affines ----
    k_gstats<<<dim3(64), blk256, 0, stream>>>(xT, stats + 128);
    k_gnorm_apply<<<dim3(2048), blk256, 0, stream>>>(xT, stats + 128, ra_gn_w, ra_gn_b, xn);
    k_gnorm_apply<<<dim3(2048), blk256, 0, stream>>>(xT, stats + 128, gn_w, gn_b, nf);

    // ---- rotation branch (4 rotations identical by permutation equivariance) ----
    k_matmul<0><<<dim3(12, 32), blk256, 0, stream>>>(xn, ra_qkv_w, nullptr, nullptr, qkv_ra, 2048, 768, 256);
    k_attn_full2<<<dim3(32, 2, KSPLIT), blk256, 0, stream>>>(qkv_ra, pacc, pl);
    k_attn_comb<<<dim3(2048), blk256, 0, stream>>>(pacc, pl, abuf);
    k_matmul<0><<<dim3(4, 32), blk256, 0, stream>>>(abuf, ra_proj_w, ra_proj_b, xT, ro, 2048, 256, 256);

    // ---- global branch ----
    k_matmul<0><<<dim3(12, 32), blk256, 0, stream>>>(nf, toqkv_w, toqkv_b, nullptr, qkv_g, 2048, 768, 256);
    k_attn_full2<<<dim3(32, 2, KSPLIT), blk256, 0, stream>>>(qkv_g, pacc, pl);
    k_attn_comb<<<dim3(2048), blk256, 0, stream>>>(pacc, pl, qo);

    // ---- combine + final proj + residual ----
    k_combine<<<dim3(2048), blk256, 0, stream>>>(sp, ha, qo, ro, attn_w, comb);
    k_matmul<0><<<dim3(4, 32), blk256, 0, stream>>>(comb, proj_w, proj_b, xT, otok, 2048, 256, 256);
    k_transpose<<<dim3(8, 32, 2), blkT, 0, stream>>>(otok, out, 1024, 256);
}

// Round 7
// 417.648 us; speedup vs baseline: 2.1191x; 1.4500x over previous
//
#include <hip/hip_runtime.h>

#define CC 256
#define HWN 1024
#define EPSV 1e-5f
#define KSPLIT 4

typedef __attribute__((ext_vector_type(8))) short bf16x8;
typedef __attribute__((ext_vector_type(4))) float f32x4;

__device__ inline ushort f2bf(float f) {
    union { float f; unsigned u; } v; v.f = f;
    unsigned u = v.u;
    u += 0x7fffu + ((u >> 16) & 1u); // round-to-nearest-even
    return (ushort)(u >> 16);
}

// ---------------- transpose (R,Cd) -> (Cd,R), batched, fp32 ----------------
__global__ __launch_bounds__(256) void k_transpose(const float* __restrict__ in,
                                                   float* __restrict__ out, int R, int Cd) {
    __shared__ float tile[32][33];
    int b = blockIdx.z;
    int r0 = blockIdx.y * 32, c0 = blockIdx.x * 32;
    int tx = threadIdx.x, ty = threadIdx.y; // 32 x 8
    const float* inb = in + (size_t)b * R * Cd;
    float* outb = out + (size_t)b * R * Cd;
#pragma unroll
    for (int i = 0; i < 32; i += 8)
        tile[ty + i][tx] = inb[(size_t)(r0 + ty + i) * Cd + c0 + tx];
    __syncthreads();
#pragma unroll
    for (int i = 0; i < 32; i += 8)
        outb[(size_t)(c0 + ty + i) * R + r0 + tx] = tile[tx][ty + i];
}

// ---------------- weight transpose+convert: in fp32 [K][N] -> out bf16 [N][K] ----------------
__global__ __launch_bounds__(256) void k_wtc(const float* __restrict__ in, ushort* __restrict__ out,
                                             int K, int N) {
    __shared__ float tile[32][33];
    int k0 = blockIdx.y * 32, n0 = blockIdx.x * 32;
    int tx = threadIdx.x, ty = threadIdx.y; // 32 x 8
#pragma unroll
    for (int i = 0; i < 32; i += 8)
        tile[ty + i][tx] = in[(size_t)(k0 + ty + i) * N + n0 + tx];
    __syncthreads();
#pragma unroll
    for (int i = 0; i < 32; i += 8)
        out[(size_t)(n0 + ty + i) * K + k0 + tx] = f2bf(tile[tx][ty + i]);
}

// ---------------- bf16 MFMA matmul: out fp32[M,N] = A fp32[M,K] @ Wt bf16[N,K]^T ----------------
// M%64==0, N%64==0, K%32==0. 256 thr = 4 waves, 64x64 tile, wave = 32x32 quadrant.
__global__ __launch_bounds__(256) void k_mm_bf(const float* __restrict__ A,
                                               const ushort* __restrict__ Wt,
                                               const float* __restrict__ bias,
                                               const float* __restrict__ res,
                                               float* __restrict__ Cp,
                                               int M, int N, int K) {
    __shared__ __align__(16) ushort As[64][40]; // [row][k], +8 pad: 80B row stride
    __shared__ __align__(16) ushort Bs[64][40]; // [col][k]
    int tid = threadIdx.x;
    int lane = tid & 63, wid = tid >> 6;
    int wr = (wid >> 1) * 32, wc = (wid & 1) * 32;
    int row0 = blockIdx.y * 64, col0 = blockIdx.x * 64;
    int sr = tid >> 2, skq = (tid & 3) * 8;       // staging: row/col, k-offset
    int l16 = lane & 15, kg = (lane >> 4) * 8;    // fragment coords
    f32x4 acc[2][2] = {};
    for (int k0 = 0; k0 < K; k0 += 32) {
        // stage A rows (fp32 -> bf16)
        const float* ap = &A[(size_t)(row0 + sr) * K + k0 + skq];
        float4 a0 = *(const float4*)ap, a1 = *(const float4*)(ap + 4);
        bf16x8 av;
        av[0] = (short)f2bf(a0.x); av[1] = (short)f2bf(a0.y);
        av[2] = (short)f2bf(a0.z); av[3] = (short)f2bf(a0.w);
        av[4] = (short)f2bf(a1.x); av[5] = (short)f2bf(a1.y);
        av[6] = (short)f2bf(a1.z); av[7] = (short)f2bf(a1.w);
        *(bf16x8*)&As[sr][skq] = av;
        // stage B cols (already bf16, [N][K] layout: contiguous 16B)
        *(bf16x8*)&Bs[sr][skq] = *(const bf16x8*)&Wt[(size_t)(col0 + sr) * K + k0 + skq];
        __syncthreads();
        bf16x8 af0 = *(bf16x8*)&As[wr + l16][kg];
        bf16x8 af1 = *(bf16x8*)&As[wr + 16 + l16][kg];
        bf16x8 bf0 = *(bf16x8*)&Bs[wc + l16][kg];
        bf16x8 bf1 = *(bf16x8*)&Bs[wc + 16 + l16][kg];
        acc[0][0] = __builtin_amdgcn_mfma_f32_16x16x32_bf16(af0, bf0, acc[0][0], 0, 0, 0);
        acc[0][1] = __builtin_amdgcn_mfma_f32_16x16x32_bf16(af0, bf1, acc[0][1], 0, 0, 0);
        acc[1][0] = __builtin_amdgcn_mfma_f32_16x16x32_bf16(af1, bf0, acc[1][0], 0, 0, 0);
        acc[1][1] = __builtin_amdgcn_mfma_f32_16x16x32_bf16(af1, bf1, acc[1][1], 0, 0, 0);
        __syncthreads();
    }
    // epilogue: C/D mapping col=lane&15, row=(lane>>4)*4+reg (m89-verified)
#pragma unroll
    for (int fr = 0; fr < 2; fr++)
#pragma unroll
        for (int fc = 0; fc < 2; fc++)
#pragma unroll
            for (int reg = 0; reg < 4; reg++) {
                int r = row0 + wr + fr * 16 + (lane >> 4) * 4 + reg;
                int c = col0 + wc + fc * 16 + l16;
                float v = acc[fr][fc][reg];
                if (bias) v += bias[c];
                if (res) v += res[(size_t)r * N + c];
                Cp[(size_t)r * N + c] = v;
            }
}

// ---------------- tiled fp32 matmul (small spatial matmuls only) ----------------
// ACT: 0 none, 1 relu, 3 gate: out = res*(1+sigmoid(acc+bias))
template <int ACT>
__global__ __launch_bounds__(256) void k_matmul(const float* __restrict__ A,
                                                const float* __restrict__ W,
                                                const float* __restrict__ bias,
                                                const float* __restrict__ res,
                                                float* __restrict__ Cp,
                                                int M, int N, int K) {
    __shared__ float As[16][68];
    __shared__ float Bs[16][64];
    int tid = threadIdx.x;
    int tx = tid & 15, ty = tid >> 4;
    int row0 = blockIdx.y * 64, col0 = blockIdx.x * 64;
    float acc[4][4] = {};
    for (int k0 = 0; k0 < K; k0 += 16) {
#pragma unroll
        for (int l = 0; l < 4; l++) {
            int idx = tid + l * 256;
            int r = idx >> 4, kk = idx & 15;
            int gr = row0 + r, gk = k0 + kk;
            As[kk][r] = (gr < M && gk < K) ? A[(size_t)gr * K + gk] : 0.f;
        }
#pragma unroll
        for (int l = 0; l < 4; l++) {
            int idx = tid + l * 256;
            int kk = idx >> 6, c = idx & 63;
            int gk = k0 + kk, gc = col0 + c;
            Bs[kk][c] = (gk < K && gc < N) ? W[(size_t)gk * N + gc] : 0.f;
        }
        __syncthreads();
#pragma unroll
        for (int kk = 0; kk < 16; kk++) {
            float4 a4 = *(const float4*)&As[kk][ty * 4];
            float4 b4 = *(const float4*)&Bs[kk][tx * 4];
            float av[4] = {a4.x, a4.y, a4.z, a4.w};
            float bv[4] = {b4.x, b4.y, b4.z, b4.w};
#pragma unroll
            for (int i = 0; i < 4; i++)
#pragma unroll
                for (int j = 0; j < 4; j++)
                    acc[i][j] = fmaf(av[i], bv[j], acc[i][j]);
        }
        __syncthreads();
    }
#pragma unroll
    for (int i = 0; i < 4; i++) {
        int r = row0 + ty * 4 + i;
        if (r >= M) continue;
#pragma unroll
        for (int j = 0; j < 4; j++) {
            int c = col0 + tx * 4 + j;
            if (c >= N) continue;
            float v = acc[i][j];
            if (bias) v += bias[c];
            if (ACT == 1) v = fmaxf(v, 0.f);
            if (ACT == 3) {
                float s = 1.f / (1.f + __expf(-v));
                v = res[(size_t)r * N + c] * (1.f + s);
            } else if (res) {
                v += res[(size_t)r * N + c];
            }
            Cp[(size_t)r * N + c] = v;
        }
    }
}

// ---------------- group-norm stats ----------------
__global__ __launch_bounds__(256) void k_gstats(const float* __restrict__ in, float* __restrict__ stats) {
    int bg = blockIdx.x;
    int b = bg >> 5, g = bg & 31;
    int tid = threadIdx.x;
    float s = 0.f, s2 = 0.f;
    for (int idx = tid; idx < HWN * 8; idx += 256) {
        int t = idx >> 3, cc = idx & 7;
        float v = in[(size_t)(b * HWN + t) * CC + g * 8 + cc];
        s += v;
        s2 += v * v;
    }
    __shared__ float sh[2][256];
    sh[0][tid] = s; sh[1][tid] = s2;
    __syncthreads();
    for (int off = 128; off > 0; off >>= 1) {
        if (tid < off) { sh[0][tid] += sh[0][tid + off]; sh[1][tid] += sh[1][tid + off]; }
        __syncthreads();
    }
    if (tid == 0) {
        float mean = sh[0][0] * (1.f / (HWN * 8));
        float var = sh[1][0] * (1.f / (HWN * 8)) - mean * mean;
        stats[bg * 2] = mean;
        stats[bg * 2 + 1] = rsqrtf(var + EPSV);
    }
}

__global__ __launch_bounds__(256) void k_gnorm_apply(const float* __restrict__ in,
                                                     const float* __restrict__ stats,
                                                     const float* __restrict__ w,
                                                     const float* __restrict__ bb,
                                                     float* __restrict__ out) {
    int idx = blockIdx.x * 256 + threadIdx.x;
    int c = idx & 255;
    int t = idx >> 8;
    int b = t >> 10;
    int g = c >> 3;
    float mean = stats[(b * 32 + g) * 2], rstd = stats[(b * 32 + g) * 2 + 1];
    out[idx] = (in[idx] - mean) * rstd * w[c] + bb[c];
}

// ---------------- halo patch gather ----------------
__global__ __launch_bounds__(256) void k_patch(const float* __restrict__ xT, float* __restrict__ p) {
    int rowid = blockIdx.x;
    int blk = rowid / 196, pos = rowid % 196;
    int b = blk >> 4, hb = (blk >> 2) & 3, wb = blk & 3;
    int i = pos / 14, j = pos % 14;
    int y = hb * 8 + i - 3, xx = wb * 8 + j - 3;
    int c = threadIdx.x;
    float v = 0.f;
    if (y >= 0 && y < 32 && xx >= 0 && xx < 32)
        v = xT[(size_t)(b * HWN + y * 32 + xx) * CC + c];
    p[(size_t)rowid * CC + c] = v;
}

// ---------------- full attention (unchanged from R4) ----------------
__global__ __launch_bounds__(256) void k_attn_full2(const float* __restrict__ qkv,
                                                    float* __restrict__ pacc,
                                                    float* __restrict__ pl) {
    int bh = blockIdx.x;
    int b = bh >> 4, h = bh & 15;
    int tid = threadIdx.x;
    int q0 = blockIdx.y * 512 + tid;
    int ks = blockIdx.z;
    const float* base = qkv + (size_t)b * HWN * 768 + h * 16;
    float q[2][16];
#pragma unroll
    for (int w = 0; w < 2; w++) {
        const float4* qp = (const float4*)(base + (size_t)(q0 + w * 256) * 768);
#pragma unroll
        for (int i = 0; i < 4; i++) {
            float4 v = qp[i];
            q[w][i * 4] = v.x; q[w][i * 4 + 1] = v.y; q[w][i * 4 + 2] = v.z; q[w][i * 4 + 3] = v.w;
        }
    }
    float l[2] = {0.f, 0.f};
    float acc[2][16] = {};
    __shared__ float Ks[64][16];
    __shared__ float Vs[64][16];
    int kbase = ks * (HWN / KSPLIT);
    for (int t = 0; t < (HWN / KSPLIT) / 64; t++) {
        __syncthreads();
        {
            int kk = tid >> 2, part = tid & 3;
            const float* rowp = base + (size_t)(kbase + t * 64 + kk) * 768 + part * 4;
            *(float4*)&Ks[kk][part * 4] = *(const float4*)(rowp + 256);
            *(float4*)&Vs[kk][part * 4] = *(const float4*)(rowp + 512);
        }
        __syncthreads();
        for (int k4 = 0; k4 < 64; k4 += 4) {
            float s[2][4] = {};
#pragma unroll
            for (int j = 0; j < 4; j++) {
                const float4* kp = (const float4*)&Ks[k4 + j][0];
#pragma unroll
                for (int i = 0; i < 4; i++) {
                    float4 kv = kp[i];
                    s[0][j] = fmaf(q[0][i * 4], kv.x, s[0][j]);
                    s[0][j] = fmaf(q[0][i * 4 + 1], kv.y, s[0][j]);
                    s[0][j] = fmaf(q[0][i * 4 + 2], kv.z, s[0][j]);
                    s[0][j] = fmaf(q[0][i * 4 + 3], kv.w, s[0][j]);
                    s[1][j] = fmaf(q[1][i * 4], kv.x, s[1][j]);
                    s[1][j] = fmaf(q[1][i * 4 + 1], kv.y, s[1][j]);
                    s[1][j] = fmaf(q[1][i * 4 + 2], kv.z, s[1][j]);
                    s[1][j] = fmaf(q[1][i * 4 + 3], kv.w, s[1][j]);
                }
            }
            float e[2][4];
#pragma unroll
            for (int j = 0; j < 4; j++) {
                e[0][j] = __expf(s[0][j] * 0.25f);
                e[1][j] = __expf(s[1][j] * 0.25f);
            }
            l[0] += (e[0][0] + e[0][1]) + (e[0][2] + e[0][3]);
            l[1] += (e[1][0] + e[1][1]) + (e[1][2] + e[1][3]);
#pragma unroll
            for (int j = 0; j < 4; j++) {
                const float4* vp = (const float4*)&Vs[k4 + j][0];
#pragma unroll
                for (int i = 0; i < 4; i++) {
                    float4 vv = vp[i];
                    acc[0][i * 4]     = fmaf(e[0][j], vv.x, acc[0][i * 4]);
                    acc[0][i * 4 + 1] = fmaf(e[0][j], vv.y, acc[0][i * 4 + 1]);
                    acc[0][i * 4 + 2] = fmaf(e[0][j], vv.z, acc[0][i * 4 + 2]);
                    acc[0][i * 4 + 3] = fmaf(e[0][j], vv.w, acc[0][i * 4 + 3]);
                    acc[1][i * 4]     = fmaf(e[1][j], vv.x, acc[1][i * 4]);
                    acc[1][i * 4 + 1] = fmaf(e[1][j], vv.y, acc[1][i * 4 + 1]);
                    acc[1][i * 4 + 2] = fmaf(e[1][j], vv.z, acc[1][i * 4 + 2]);
                    acc[1][i * 4 + 3] = fmaf(e[1][j], vv.w, acc[1][i * 4 + 3]);
                }
            }
        }
    }
#pragma unroll
    for (int w = 0; w < 2; w++) {
        int qidx = bh * HWN + q0 + w * 256;
        float4* pp = (float4*)&pacc[((size_t)qidx * KSPLIT + ks) * 16];
#pragma unroll
        for (int i = 0; i < 4; i++)
            pp[i] = make_float4(acc[w][i * 4], acc[w][i * 4 + 1], acc[w][i * 4 + 2], acc[w][i * 4 + 3]);
        pl[qidx * KSPLIT + ks] = l[w];
    }
}

__global__ __launch_bounds__(256) void k_attn_comb(const float* __restrict__ pacc,
                                                   const float* __restrict__ pl,
                                                   float* __restrict__ out) {
    int idx = blockIdx.x * 256 + threadIdx.x;
    int qidx = idx >> 4, d = idx & 15;
    float a = 0.f, l = 0.f;
#pragma unroll
    for (int ks = 0; ks < KSPLIT; ks++) {
        a += pacc[((size_t)qidx * KSPLIT + ks) * 16 + d];
        l += pl[qidx * KSPLIT + ks];
    }
    int bh = qidx >> 10, t = qidx & 1023;
    int b = bh >> 4, h = bh & 15;
    out[(size_t)(b * HWN + t) * CC + h * 16 + d] = a / l;
}

// ---------------- halo attention ----------------
__global__ __launch_bounds__(64) void k_attn_halo(const float* __restrict__ qkv, float* __restrict__ out) {
    int blk = blockIdx.x;
    int h = blockIdx.y;
    int tid = threadIdx.x;
    __shared__ float Ks[196][16];
    __shared__ float Vs[196][16];
    const float* base = qkv + (size_t)blk * 196 * 768 + h * 16;
    for (int idx = tid; idx < 196 * 4; idx += 64) {
        int kk = idx >> 2, part = idx & 3;
        const float* rowp = base + (size_t)kk * 768 + part * 4;
        *(float4*)&Ks[kk][part * 4] = *(const float4*)(rowp + 256);
        *(float4*)&Vs[kk][part * 4] = *(const float4*)(rowp + 512);
    }
    __syncthreads();
    int ci = tid >> 3, cj = tid & 7;
    int cpos = (3 + ci) * 14 + (3 + cj);
    float q[16];
    {
        const float4* qp = (const float4*)(base + (size_t)cpos * 768);
#pragma unroll
        for (int i = 0; i < 4; i++) {
            float4 v = qp[i];
            q[i * 4] = v.x; q[i * 4 + 1] = v.y; q[i * 4 + 2] = v.z; q[i * 4 + 3] = v.w;
        }
    }
    float l = 0.f, acc[16] = {};
    for (int k4 = 0; k4 < 196; k4 += 4) {
        float s[4] = {};
#pragma unroll
        for (int j = 0; j < 4; j++) {
            const float4* kp = (const float4*)&Ks[k4 + j][0];
#pragma unroll
            for (int i = 0; i < 4; i++) {
                float4 kv = kp[i];
                s[j] = fmaf(q[i * 4], kv.x, s[j]);
                s[j] = fmaf(q[i * 4 + 1], kv.y, s[j]);
                s[j] = fmaf(q[i * 4 + 2], kv.z, s[j]);
                s[j] = fmaf(q[i * 4 + 3], kv.w, s[j]);
            }
        }
        float e[4];
#pragma unroll
        for (int j = 0; j < 4; j++) e[j] = __expf(s[j] * 0.25f);
        l += (e[0] + e[1]) + (e[2] + e[3]);
#pragma unroll
        for (int j = 0; j < 4; j++) {
            const float4* vp = (const float4*)&Vs[k4 + j][0];
#pragma unroll
            for (int i = 0; i < 4; i++) {
                float4 vv = vp[i];
                acc[i * 4]     = fmaf(e[j], vv.x, acc[i * 4]);
                acc[i * 4 + 1] = fmaf(e[j], vv.y, acc[i * 4 + 1]);
                acc[i * 4 + 2] = fmaf(e[j], vv.z, acc[i * 4 + 2]);
                acc[i * 4 + 3] = fmaf(e[j], vv.w, acc[i * 4 + 3]);
            }
        }
    }
    float inv = 1.f / l;
    int b = blk >> 4, hb = (blk >> 2) & 3, wb = blk & 3;
    int t = (hb * 8 + ci) * 32 + wb * 8 + cj;
    float4* op = (float4*)(out + (size_t)(b * HWN + t) * CC + h * 16);
#pragma unroll
    for (int i = 0; i < 4; i++)
        op[i] = make_float4(acc[i * 4] * inv, acc[i * 4 + 1] * inv, acc[i * 4 + 2] * inv, acc[i * 4 + 3] * inv);
}

// ---------------- weighted combine ----------------
__global__ __launch_bounds__(256) void k_combine(const float* __restrict__ sp, const float* __restrict__ ha,
                                                 const float* __restrict__ qo, const float* __restrict__ ro,
                                                 const float* __restrict__ aw, float* __restrict__ comb) {
    int idx = blockIdx.x * 256 + threadIdx.x;
    float a0 = aw[0], a1 = aw[1], a2 = aw[2], a3 = aw[3];
    float mx = fmaxf(fmaxf(a0, a1), fmaxf(a2, a3));
    float e0 = __expf(a0 - mx), e1 = __expf(a1 - mx), e2 = __expf(a2 - mx), e3 = __expf(a3 - mx);
    float inv = 1.f / (e0 + e1 + e2 + e3);
    comb[idx] = (sp[idx] * e0 + ha[idx] * e1 + qo[idx] * e2 + ro[idx] * e3) * inv;
}

extern "C" void kernel_launch(void* const* d_in, const int* in_sizes, int n_in,
                              void* d_out, int out_size, void* d_ws, size_t ws_size,
                              hipStream_t stream) {
    const float* x        = (const float*)d_in[0];
    const float* sa_w1    = (const float*)d_in[1];
    const float* sa_b1    = (const float*)d_in[2];
    const float* sa_w2    = (const float*)d_in[3];
    const float* sa_b2    = (const float*)d_in[4];
    const float* sa_gn_w  = (const float*)d_in[5];
    const float* sa_gn_b  = (const float*)d_in[6];
    const float* ha_qkv_w = (const float*)d_in[7];
    const float* ha_proj_w= (const float*)d_in[8];
    const float* ha_proj_b= (const float*)d_in[9];
    const float* ra_gn_w  = (const float*)d_in[10];
    const float* ra_gn_b  = (const float*)d_in[11];
    const float* ra_qkv_w = (const float*)d_in[12];
    const float* ra_proj_w= (const float*)d_in[13];
    const float* ra_proj_b= (const float*)d_in[14];
    const float* gn_w     = (const float*)d_in[15];
    const float* gn_b     = (const float*)d_in[16];
    const float* toqkv_w  = (const float*)d_in[17];
    const float* toqkv_b  = (const float*)d_in[18];
    const float* attn_w   = (const float*)d_in[19];
    const float* proj_w   = (const float*)d_in[20];
    const float* proj_b   = (const float*)d_in[21];
    float* out = (float*)d_out;

    float* ws = (float*)d_ws;
    size_t off = 0;
    float* xT   = ws + off; off += 524288;
    float* sp   = ws + off; off += 524288;
    float* xn   = ws + off; off += 524288;
    float* nf   = ws + off; off += 524288;
    float* ha   = ws + off; off += 524288;
    float* ro   = ws + off; off += 524288;
    float* qo   = ws + off; off += 524288;
    float* abuf = ws + off; off += 524288;
    float* stats= ws + off; off += 256;
    float* big0 = ws + off; off += 4816896;
    float* big1 = ws + off; off += 1605632;
    float* pacc = ws + off; off += 2097152; // 32768 * KSPLIT * 16
    float* pl   = ws + off; off += 131072;  // 32768 * KSPLIT
    // bf16 weight buffers ([N][K] transposed)
    ushort* wt_ha_qkv = (ushort*)(ws + off); off += 98304; // 768*256 bf16
    ushort* wt_ra_qkv = (ushort*)(ws + off); off += 98304;
    ushort* wt_toqkv  = (ushort*)(ws + off); off += 98304;
    ushort* wt_ha_pj  = (ushort*)(ws + off); off += 32768; // 256*256 bf16
    ushort* wt_ra_pj  = (ushort*)(ws + off); off += 32768;
    ushort* wt_pj     = (ushort*)(ws + off); off += 32768;
    float* comb = xn;
    float* otok = nf;
    float* qkv_ha = big0;
    float* qkv_ra = big0;
    float* qkv_g  = big0 + 1572864;
    float* pbuf = big1;
    float* s1   = big1;
    float* spre = big1 + 65536;

    dim3 blk256(256), blkT(32, 8);

    // ---- one-time weight transpose+convert to bf16 [N][K] ----
    k_wtc<<<dim3(24, 8), blkT, 0, stream>>>(ha_qkv_w, wt_ha_qkv, 256, 768);
    k_wtc<<<dim3(24, 8), blkT, 0, stream>>>(ra_qkv_w, wt_ra_qkv, 256, 768);
    k_wtc<<<dim3(24, 8), blkT, 0, stream>>>(toqkv_w,  wt_toqkv,  256, 768);
    k_wtc<<<dim3(8, 8),  blkT, 0, stream>>>(ha_proj_w, wt_ha_pj, 256, 256);
    k_wtc<<<dim3(8, 8),  blkT, 0, stream>>>(ra_proj_w, wt_ra_pj, 256, 256);
    k_wtc<<<dim3(8, 8),  blkT, 0, stream>>>(proj_w,    wt_pj,    256, 256);

    // x (B,256,1024) -> xT (B,1024,256) token-major
    k_transpose<<<dim3(32, 8, 2), blkT, 0, stream>>>(x, xT, 256, 1024);

    // ---- halo branch ----
    k_patch<<<dim3(6272), blk256, 0, stream>>>(xT, pbuf);
    k_mm_bf<<<dim3(12, 98), blk256, 0, stream>>>(pbuf, wt_ha_qkv, nullptr, nullptr, qkv_ha, 6272, 768, 256);
    k_attn_halo<<<dim3(32, 16), dim3(64), 0, stream>>>(qkv_ha, abuf);
    k_mm_bf<<<dim3(4, 32), blk256, 0, stream>>>(abuf, wt_ha_pj, ha_proj_b, nullptr, ha, 2048, 256, 256);

    // ---- spatial branch (small matmuls stay fp32) ----
    k_matmul<1><<<dim3(1, 32), blk256, 0, stream>>>(xT, sa_w1, sa_b1, nullptr, s1, 2048, 32, 256);
    k_matmul<3><<<dim3(4, 32), blk256, 0, stream>>>(s1, sa_w2, sa_b2, xT, spre, 2048, 256, 32);
    k_gstats<<<dim3(64), blk256, 0, stream>>>(spre, stats);
    k_gnorm_apply<<<dim3(2048), blk256, 0, stream>>>(spre, stats, sa_gn_w, sa_gn_b, sp);

    // ---- shared gnorm stats of x; two affines ----
    k_gstats<<<dim3(64), blk256, 0, stream>>>(xT, stats + 128);
    k_gnorm_apply<<<dim3(2048), blk256, 0, stream>>>(xT, stats + 128, ra_gn_w, ra_gn_b, xn);
    k_gnorm_apply<<<dim3(2048), blk256, 0, stream>>>(xT, stats + 128, gn_w, gn_b, nf);

    // ---- rotation branch (4 rotations identical by permutation equivariance) ----
    k_mm_bf<<<dim3(12, 32), blk256, 0, stream>>>(xn, wt_ra_qkv, nullptr, nullptr, qkv_ra, 2048, 768, 256);
    k_attn_full2<<<dim3(32, 2, KSPLIT), blk256, 0, stream>>>(qkv_ra, pacc, pl);
    k_attn_comb<<<dim3(2048), blk256, 0, stream>>>(pacc, pl, abuf);
    k_mm_bf<<<dim3(4, 32), blk256, 0, stream>>>(abuf, wt_ra_pj, ra_proj_b, xT, ro, 2048, 256, 256);

    // ---- global branch ----
    k_mm_bf<<<dim3(12, 32), blk256, 0, stream>>>(nf, wt_toqkv, toqkv_b, nullptr, qkv_g, 2048, 768, 256);
    k_attn_full2<<<dim3(32, 2, KSPLIT), blk256, 0, stream>>>(qkv_g, pacc, pl);
    k_attn_comb<<<dim3(2048), blk256, 0, stream>>>(pacc, pl, qo);

    // ---- combine + final proj + residual ----
    k_combine<<<dim3(2048), blk256, 0, stream>>>(sp, ha, qo, ro, attn_w, comb);
    k_mm_bf<<<dim3(4, 32), blk256, 0, stream>>>(comb, wt_pj, proj_b, xT, otok, 2048, 256, 256);
    k_transpose<<<dim3(8, 32, 2), blkT, 0, stream>>>(otok, out, 1024, 256);
}

// Round 8
// 386.551 us; speedup vs baseline: 2.2896x; 1.0804x over previous
//
#include <hip/hip_runtime.h>

#define CC 256
#define HWN 1024
#define EPSV 1e-5f

typedef __attribute__((ext_vector_type(8))) short bf16x8;
typedef __attribute__((ext_vector_type(4))) float f32x4;

__device__ inline ushort f2bf(float f) {
    union { float f; unsigned u; } v; v.f = f;
    unsigned u = v.u;
    u += 0x7fffu + ((u >> 16) & 1u); // round-to-nearest-even
    return (ushort)(u >> 16);
}

// ---------------- transpose (R,Cd) -> (Cd,R), batched, fp32 ----------------
__global__ __launch_bounds__(256) void k_transpose(const float* __restrict__ in,
                                                   float* __restrict__ out, int R, int Cd) {
    __shared__ float tile[32][33];
    int b = blockIdx.z;
    int r0 = blockIdx.y * 32, c0 = blockIdx.x * 32;
    int tx = threadIdx.x, ty = threadIdx.y; // 32 x 8
    const float* inb = in + (size_t)b * R * Cd;
    float* outb = out + (size_t)b * R * Cd;
#pragma unroll
    for (int i = 0; i < 32; i += 8)
        tile[ty + i][tx] = inb[(size_t)(r0 + ty + i) * Cd + c0 + tx];
    __syncthreads();
#pragma unroll
    for (int i = 0; i < 32; i += 8)
        outb[(size_t)(c0 + ty + i) * R + r0 + tx] = tile[tx][ty + i];
}

// ---------------- weight transpose+convert: in fp32 [K][N] -> out bf16 [N][K] ----------------
__global__ __launch_bounds__(256) void k_wtc(const float* __restrict__ in, ushort* __restrict__ out,
                                             int K, int N) {
    __shared__ float tile[32][33];
    int k0 = blockIdx.y * 32, n0 = blockIdx.x * 32;
    int tx = threadIdx.x, ty = threadIdx.y; // 32 x 8
#pragma unroll
    for (int i = 0; i < 32; i += 8)
        tile[ty + i][tx] = in[(size_t)(k0 + ty + i) * N + n0 + tx];
    __syncthreads();
#pragma unroll
    for (int i = 0; i < 32; i += 8)
        out[(size_t)(n0 + ty + i) * K + k0 + tx] = f2bf(tile[tx][ty + i]);
}

// ---------------- bf16 MFMA matmul: out fp32[M,N] = A fp32[M,K] @ Wt bf16[N,K]^T ----------------
__global__ __launch_bounds__(256) void k_mm_bf(const float* __restrict__ A,
                                               const ushort* __restrict__ Wt,
                                               const float* __restrict__ bias,
                                               const float* __restrict__ res,
                                               float* __restrict__ Cp,
                                               int M, int N, int K) {
    __shared__ __align__(16) ushort As[64][40];
    __shared__ __align__(16) ushort Bs[64][40];
    int tid = threadIdx.x;
    int lane = tid & 63, wid = tid >> 6;
    int wr = (wid >> 1) * 32, wc = (wid & 1) * 32;
    int row0 = blockIdx.y * 64, col0 = blockIdx.x * 64;
    int sr = tid >> 2, skq = (tid & 3) * 8;
    int l16 = lane & 15, kg = (lane >> 4) * 8;
    f32x4 acc[2][2] = {};
    for (int k0 = 0; k0 < K; k0 += 32) {
        const float* ap = &A[(size_t)(row0 + sr) * K + k0 + skq];
        float4 a0 = *(const float4*)ap, a1 = *(const float4*)(ap + 4);
        bf16x8 av;
        av[0] = (short)f2bf(a0.x); av[1] = (short)f2bf(a0.y);
        av[2] = (short)f2bf(a0.z); av[3] = (short)f2bf(a0.w);
        av[4] = (short)f2bf(a1.x); av[5] = (short)f2bf(a1.y);
        av[6] = (short)f2bf(a1.z); av[7] = (short)f2bf(a1.w);
        *(bf16x8*)&As[sr][skq] = av;
        *(bf16x8*)&Bs[sr][skq] = *(const bf16x8*)&Wt[(size_t)(col0 + sr) * K + k0 + skq];
        __syncthreads();
        bf16x8 af0 = *(bf16x8*)&As[wr + l16][kg];
        bf16x8 af1 = *(bf16x8*)&As[wr + 16 + l16][kg];
        bf16x8 bf0 = *(bf16x8*)&Bs[wc + l16][kg];
        bf16x8 bf1 = *(bf16x8*)&Bs[wc + 16 + l16][kg];
        acc[0][0] = __builtin_amdgcn_mfma_f32_16x16x32_bf16(af0, bf0, acc[0][0], 0, 0, 0);
        acc[0][1] = __builtin_amdgcn_mfma_f32_16x16x32_bf16(af0, bf1, acc[0][1], 0, 0, 0);
        acc[1][0] = __builtin_amdgcn_mfma_f32_16x16x32_bf16(af1, bf0, acc[1][0], 0, 0, 0);
        acc[1][1] = __builtin_amdgcn_mfma_f32_16x16x32_bf16(af1, bf1, acc[1][1], 0, 0, 0);
        __syncthreads();
    }
#pragma unroll
    for (int fr = 0; fr < 2; fr++)
#pragma unroll
        for (int fc = 0; fc < 2; fc++)
#pragma unroll
            for (int reg = 0; reg < 4; reg++) {
                int r = row0 + wr + fr * 16 + (lane >> 4) * 4 + reg;
                int c = col0 + wc + fc * 16 + l16;
                float v = acc[fr][fc][reg];
                if (bias) v += bias[c];
                if (res) v += res[(size_t)r * N + c];
                Cp[(size_t)r * N + c] = v;
            }
}

// ---------------- tiled fp32 matmul (small spatial matmuls only) ----------------
template <int ACT>
__global__ __launch_bounds__(256) void k_matmul(const float* __restrict__ A,
                                                const float* __restrict__ W,
                                                const float* __restrict__ bias,
                                                const float* __restrict__ res,
                                                float* __restrict__ Cp,
                                                int M, int N, int K) {
    __shared__ float As[16][68];
    __shared__ float Bs[16][64];
    int tid = threadIdx.x;
    int tx = tid & 15, ty = tid >> 4;
    int row0 = blockIdx.y * 64, col0 = blockIdx.x * 64;
    float acc[4][4] = {};
    for (int k0 = 0; k0 < K; k0 += 16) {
#pragma unroll
        for (int l = 0; l < 4; l++) {
            int idx = tid + l * 256;
            int r = idx >> 4, kk = idx & 15;
            int gr = row0 + r, gk = k0 + kk;
            As[kk][r] = (gr < M && gk < K) ? A[(size_t)gr * K + gk] : 0.f;
        }
#pragma unroll
        for (int l = 0; l < 4; l++) {
            int idx = tid + l * 256;
            int kk = idx >> 6, c = idx & 63;
            int gk = k0 + kk, gc = col0 + c;
            Bs[kk][c] = (gk < K && gc < N) ? W[(size_t)gk * N + gc] : 0.f;
        }
        __syncthreads();
#pragma unroll
        for (int kk = 0; kk < 16; kk++) {
            float4 a4 = *(const float4*)&As[kk][ty * 4];
            float4 b4 = *(const float4*)&Bs[kk][tx * 4];
            float av[4] = {a4.x, a4.y, a4.z, a4.w};
            float bv[4] = {b4.x, b4.y, b4.z, b4.w};
#pragma unroll
            for (int i = 0; i < 4; i++)
#pragma unroll
                for (int j = 0; j < 4; j++)
                    acc[i][j] = fmaf(av[i], bv[j], acc[i][j]);
        }
        __syncthreads();
    }
#pragma unroll
    for (int i = 0; i < 4; i++) {
        int r = row0 + ty * 4 + i;
        if (r >= M) continue;
#pragma unroll
        for (int j = 0; j < 4; j++) {
            int c = col0 + tx * 4 + j;
            if (c >= N) continue;
            float v = acc[i][j];
            if (bias) v += bias[c];
            if (ACT == 1) v = fmaxf(v, 0.f);
            if (ACT == 3) {
                float s = 1.f / (1.f + __expf(-v));
                v = res[(size_t)r * N + c] * (1.f + s);
            } else if (res) {
                v += res[(size_t)r * N + c];
            }
            Cp[(size_t)r * N + c] = v;
        }
    }
}

// ---------------- group-norm stats ----------------
__global__ __launch_bounds__(256) void k_gstats(const float* __restrict__ in, float* __restrict__ stats) {
    int bg = blockIdx.x;
    int b = bg >> 5, g = bg & 31;
    int tid = threadIdx.x;
    float s = 0.f, s2 = 0.f;
    for (int idx = tid; idx < HWN * 8; idx += 256) {
        int t = idx >> 3, cc = idx & 7;
        float v = in[(size_t)(b * HWN + t) * CC + g * 8 + cc];
        s += v;
        s2 += v * v;
    }
    __shared__ float sh[2][256];
    sh[0][tid] = s; sh[1][tid] = s2;
    __syncthreads();
    for (int off = 128; off > 0; off >>= 1) {
        if (tid < off) { sh[0][tid] += sh[0][tid + off]; sh[1][tid] += sh[1][tid + off]; }
        __syncthreads();
    }
    if (tid == 0) {
        float mean = sh[0][0] * (1.f / (HWN * 8));
        float var = sh[1][0] * (1.f / (HWN * 8)) - mean * mean;
        stats[bg * 2] = mean;
        stats[bg * 2 + 1] = rsqrtf(var + EPSV);
    }
}

__global__ __launch_bounds__(256) void k_gnorm_apply(const float* __restrict__ in,
                                                     const float* __restrict__ stats,
                                                     const float* __restrict__ w,
                                                     const float* __restrict__ bb,
                                                     float* __restrict__ out) {
    int idx = blockIdx.x * 256 + threadIdx.x;
    int c = idx & 255;
    int t = idx >> 8;
    int b = t >> 10;
    int g = c >> 3;
    float mean = stats[(b * 32 + g) * 2], rstd = stats[(b * 32 + g) * 2 + 1];
    out[idx] = (in[idx] - mean) * rstd * w[c] + bb[c];
}

// ---------------- halo patch gather ----------------
__global__ __launch_bounds__(256) void k_patch(const float* __restrict__ xT, float* __restrict__ p) {
    int rowid = blockIdx.x;
    int blk = rowid / 196, pos = rowid % 196;
    int b = blk >> 4, hb = (blk >> 2) & 3, wb = blk & 3;
    int i = pos / 14, j = pos % 14;
    int y = hb * 8 + i - 3, xx = wb * 8 + j - 3;
    int c = threadIdx.x;
    float v = 0.f;
    if (y >= 0 && y < 32 && xx >= 0 && xx < 32)
        v = xT[(size_t)(b * HWN + y * 32 + xx) * CC + c];
    p[(size_t)rowid * CC + c] = v;
}

// ---------------- batched full attention ----------------
// Both sources (ra + global) in one launch. Grid (64, 16): x = src*32+bh, y = qchunk.
// Block = 4 waves; wave w owns key-quarter [w*256, w*256+256), staged 64 keys at a
// time in its PRIVATE LDS region (no barriers in K-loop; within-wave lgkmcnt ordering).
// 1 query/lane. K/V LDS reads are wave-uniform broadcasts (conflict-free). Staging
// writes use XOR slot swizzle (slot ^ (lane&7)) to spread 128B-stride rows over all
// banks. Branchless softmax (|s|*0.25 bounded; exp safe). Cross-wave (acc,l) combine
// in LDS — no pacc/pl HBM round trip.
__global__ __launch_bounds__(256, 4) void k_attn_batch(const float* __restrict__ qkv0,
                                                       const float* __restrict__ qkv1,
                                                       float* __restrict__ out0,
                                                       float* __restrict__ out1) {
    __shared__ float smem[4][64][32]; // 32 KB staging; reused as [4][64][20] combine
    int gx = blockIdx.x;
    int src = gx >> 5, bh = gx & 31;
    int b = bh >> 4, h = bh & 15;
    const float* qkv = src ? qkv1 : qkv0;
    float* out = src ? out1 : out0;
    int tid = threadIdx.x;
    int lane = tid & 63, wid = tid >> 6;
    const float* base = qkv + (size_t)b * HWN * 768 + h * 16;
    int q0 = blockIdx.y * 64 + lane;
    float q[16];
    {
        const float4* qp = (const float4*)(base + (size_t)q0 * 768);
#pragma unroll
        for (int i = 0; i < 4; i++) {
            float4 v = qp[i];
            q[i * 4] = v.x; q[i * 4 + 1] = v.y; q[i * 4 + 2] = v.z; q[i * 4 + 3] = v.w;
        }
    }
    float l = 0.f, acc[16] = {};
    int kbase = wid * 256;
    int swl = lane & 7;
    for (int t = 0; t < 4; t++) {
        // stage 64 keys: lane stages key (kbase + t*64 + lane), swizzled slots
        {
            const float4* rp = (const float4*)(base + (size_t)(kbase + t * 64 + lane) * 768);
#pragma unroll
            for (int j = 0; j < 4; j++) {
                float4 kv = rp[64 + j];   // K at +256 floats
                *(float4*)&smem[wid][lane][(j ^ swl) * 4] = kv;
                float4 vv = rp[128 + j];  // V at +512 floats
                *(float4*)&smem[wid][lane][((j + 4) ^ swl) * 4] = vv;
            }
        }
        for (int kk = 0; kk < 64; kk++) {
            int sw = kk & 7;
            const float* kr = &smem[wid][kk][0];
            float4 k0 = *(const float4*)&kr[(0 ^ sw) * 4];
            float4 k1 = *(const float4*)&kr[(1 ^ sw) * 4];
            float4 k2 = *(const float4*)&kr[(2 ^ sw) * 4];
            float4 k3 = *(const float4*)&kr[(3 ^ sw) * 4];
            float s0 = q[0] * k0.x, s1 = q[4] * k1.x, s2 = q[8] * k2.x, s3 = q[12] * k3.x;
            s0 = fmaf(q[1], k0.y, s0); s1 = fmaf(q[5], k1.y, s1);
            s2 = fmaf(q[9], k2.y, s2); s3 = fmaf(q[13], k3.y, s3);
            s0 = fmaf(q[2], k0.z, s0); s1 = fmaf(q[6], k1.z, s1);
            s2 = fmaf(q[10], k2.z, s2); s3 = fmaf(q[14], k3.z, s3);
            s0 = fmaf(q[3], k0.w, s0); s1 = fmaf(q[7], k1.w, s1);
            s2 = fmaf(q[11], k2.w, s2); s3 = fmaf(q[15], k3.w, s3);
            float e = __expf(((s0 + s1) + (s2 + s3)) * 0.25f);
            l += e;
            float4 v0 = *(const float4*)&kr[(4 ^ sw) * 4];
            float4 v1 = *(const float4*)&kr[(5 ^ sw) * 4];
            float4 v2 = *(const float4*)&kr[(6 ^ sw) * 4];
            float4 v3 = *(const float4*)&kr[(7 ^ sw) * 4];
            acc[0]  = fmaf(e, v0.x, acc[0]);  acc[1]  = fmaf(e, v0.y, acc[1]);
            acc[2]  = fmaf(e, v0.z, acc[2]);  acc[3]  = fmaf(e, v0.w, acc[3]);
            acc[4]  = fmaf(e, v1.x, acc[4]);  acc[5]  = fmaf(e, v1.y, acc[5]);
            acc[6]  = fmaf(e, v1.z, acc[6]);  acc[7]  = fmaf(e, v1.w, acc[7]);
            acc[8]  = fmaf(e, v2.x, acc[8]);  acc[9]  = fmaf(e, v2.y, acc[9]);
            acc[10] = fmaf(e, v2.z, acc[10]); acc[11] = fmaf(e, v2.w, acc[11]);
            acc[12] = fmaf(e, v3.x, acc[12]); acc[13] = fmaf(e, v3.y, acc[13]);
            acc[14] = fmaf(e, v3.z, acc[14]); acc[15] = fmaf(e, v3.w, acc[15]);
        }
    }
    // ---- cross-wave combine in LDS (reuse smem as [4][64][20]) ----
    __syncthreads(); // all waves done reading their staging regions
    {
        float* pb = &((float*)smem)[(wid * 64 + lane) * 20];
#pragma unroll
        for (int i = 0; i < 16; i++) pb[i] = acc[i];
        pb[16] = l;
    }
    __syncthreads();
    {
        const float* pr = (const float*)smem;
        int qq = tid >> 2, dg = (tid & 3) * 4;
        float ax = 0.f, ay = 0.f, az = 0.f, aw = 0.f, lt = 0.f;
#pragma unroll
        for (int w = 0; w < 4; w++) {
            const float* row = &pr[(w * 64 + qq) * 20];
            ax += row[dg]; ay += row[dg + 1]; az += row[dg + 2]; aw += row[dg + 3];
            lt += row[16];
        }
        float inv = 1.f / lt;
        int qidx = blockIdx.y * 64 + qq;
        *(float4*)(out + (size_t)(b * HWN + qidx) * CC + h * 16 + dg) =
            make_float4(ax * inv, ay * inv, az * inv, aw * inv);
    }
}

// ---------------- halo attention (unchanged) ----------------
__global__ __launch_bounds__(64) void k_attn_halo(const float* __restrict__ qkv, float* __restrict__ out) {
    int blk = blockIdx.x;
    int h = blockIdx.y;
    int tid = threadIdx.x;
    __shared__ float Ks[196][16];
    __shared__ float Vs[196][16];
    const float* base = qkv + (size_t)blk * 196 * 768 + h * 16;
    for (int idx = tid; idx < 196 * 4; idx += 64) {
        int kk = idx >> 2, part = idx & 3;
        const float* rowp = base + (size_t)kk * 768 + part * 4;
        *(float4*)&Ks[kk][part * 4] = *(const float4*)(rowp + 256);
        *(float4*)&Vs[kk][part * 4] = *(const float4*)(rowp + 512);
    }
    __syncthreads();
    int ci = tid >> 3, cj = tid & 7;
    int cpos = (3 + ci) * 14 + (3 + cj);
    float q[16];
    {
        const float4* qp = (const float4*)(base + (size_t)cpos * 768);
#pragma unroll
        for (int i = 0; i < 4; i++) {
            float4 v = qp[i];
            q[i * 4] = v.x; q[i * 4 + 1] = v.y; q[i * 4 + 2] = v.z; q[i * 4 + 3] = v.w;
        }
    }
    float l = 0.f, acc[16] = {};
    for (int k4 = 0; k4 < 196; k4 += 4) {
        float s[4] = {};
#pragma unroll
        for (int j = 0; j < 4; j++) {
            const float4* kp = (const float4*)&Ks[k4 + j][0];
#pragma unroll
            for (int i = 0; i < 4; i++) {
                float4 kv = kp[i];
                s[j] = fmaf(q[i * 4], kv.x, s[j]);
                s[j] = fmaf(q[i * 4 + 1], kv.y, s[j]);
                s[j] = fmaf(q[i * 4 + 2], kv.z, s[j]);
                s[j] = fmaf(q[i * 4 + 3], kv.w, s[j]);
            }
        }
        float e[4];
#pragma unroll
        for (int j = 0; j < 4; j++) e[j] = __expf(s[j] * 0.25f);
        l += (e[0] + e[1]) + (e[2] + e[3]);
#pragma unroll
        for (int j = 0; j < 4; j++) {
            const float4* vp = (const float4*)&Vs[k4 + j][0];
#pragma unroll
            for (int i = 0; i < 4; i++) {
                float4 vv = vp[i];
                acc[i * 4]     = fmaf(e[j], vv.x, acc[i * 4]);
                acc[i * 4 + 1] = fmaf(e[j], vv.y, acc[i * 4 + 1]);
                acc[i * 4 + 2] = fmaf(e[j], vv.z, acc[i * 4 + 2]);
                acc[i * 4 + 3] = fmaf(e[j], vv.w, acc[i * 4 + 3]);
            }
        }
    }
    float inv = 1.f / l;
    int b = blk >> 4, hb = (blk >> 2) & 3, wb = blk & 3;
    int t = (hb * 8 + ci) * 32 + wb * 8 + cj;
    float4* op = (float4*)(out + (size_t)(b * HWN + t) * CC + h * 16);
#pragma unroll
    for (int i = 0; i < 4; i++)
        op[i] = make_float4(acc[i * 4] * inv, acc[i * 4 + 1] * inv, acc[i * 4 + 2] * inv, acc[i * 4 + 3] * inv);
}

// ---------------- weighted combine ----------------
__global__ __launch_bounds__(256) void k_combine(const float* __restrict__ sp, const float* __restrict__ ha,
                                                 const float* __restrict__ qo, const float* __restrict__ ro,
                                                 const float* __restrict__ aw, float* __restrict__ comb) {
    int idx = blockIdx.x * 256 + threadIdx.x;
    float a0 = aw[0], a1 = aw[1], a2 = aw[2], a3 = aw[3];
    float mx = fmaxf(fmaxf(a0, a1), fmaxf(a2, a3));
    float e0 = __expf(a0 - mx), e1 = __expf(a1 - mx), e2 = __expf(a2 - mx), e3 = __expf(a3 - mx);
    float inv = 1.f / (e0 + e1 + e2 + e3);
    comb[idx] = (sp[idx] * e0 + ha[idx] * e1 + qo[idx] * e2 + ro[idx] * e3) * inv;
}

extern "C" void kernel_launch(void* const* d_in, const int* in_sizes, int n_in,
                              void* d_out, int out_size, void* d_ws, size_t ws_size,
                              hipStream_t stream) {
    const float* x        = (const float*)d_in[0];
    const float* sa_w1    = (const float*)d_in[1];
    const float* sa_b1    = (const float*)d_in[2];
    const float* sa_w2    = (const float*)d_in[3];
    const float* sa_b2    = (const float*)d_in[4];
    const float* sa_gn_w  = (const float*)d_in[5];
    const float* sa_gn_b  = (const float*)d_in[6];
    const float* ha_qkv_w = (const float*)d_in[7];
    const float* ha_proj_w= (const float*)d_in[8];
    const float* ha_proj_b= (const float*)d_in[9];
    const float* ra_gn_w  = (const float*)d_in[10];
    const float* ra_gn_b  = (const float*)d_in[11];
    const float* ra_qkv_w = (const float*)d_in[12];
    const float* ra_proj_w= (const float*)d_in[13];
    const float* ra_proj_b= (const float*)d_in[14];
    const float* gn_w     = (const float*)d_in[15];
    const float* gn_b     = (const float*)d_in[16];
    const float* toqkv_w  = (const float*)d_in[17];
    const float* toqkv_b  = (const float*)d_in[18];
    const float* attn_w   = (const float*)d_in[19];
    const float* proj_w   = (const float*)d_in[20];
    const float* proj_b   = (const float*)d_in[21];
    float* out = (float*)d_out;

    float* ws = (float*)d_ws;
    size_t off = 0;
    float* xT   = ws + off; off += 524288;
    float* sp   = ws + off; off += 524288;
    float* xn   = ws + off; off += 524288;
    float* nf   = ws + off; off += 524288;
    float* ha   = ws + off; off += 524288;
    float* ro   = ws + off; off += 524288;
    float* qo   = ws + off; off += 524288;
    float* abuf = ws + off; off += 524288;
    float* stats= ws + off; off += 256;
    float* big0 = ws + off; off += 4816896;
    float* big1 = ws + off; off += 1605632;
    // bf16 weight buffers ([N][K] transposed)
    ushort* wt_ha_qkv = (ushort*)(ws + off); off += 98304; // 768*256 bf16
    ushort* wt_ra_qkv = (ushort*)(ws + off); off += 98304;
    ushort* wt_toqkv  = (ushort*)(ws + off); off += 98304;
    ushort* wt_ha_pj  = (ushort*)(ws + off); off += 32768; // 256*256 bf16
    ushort* wt_ra_pj  = (ushort*)(ws + off); off += 32768;
    ushort* wt_pj     = (ushort*)(ws + off); off += 32768;
    float* comb = xn;
    float* otok = nf;
    float* qkv_ha = big0;
    float* qkv_ra = big0;
    float* qkv_g  = big0 + 1572864;
    float* pbuf = big1;
    float* s1   = big1;
    float* spre = big1 + 65536;

    dim3 blk256(256), blkT(32, 8);

    // ---- one-time weight transpose+convert to bf16 [N][K] ----
    k_wtc<<<dim3(24, 8), blkT, 0, stream>>>(ha_qkv_w, wt_ha_qkv, 256, 768);
    k_wtc<<<dim3(24, 8), blkT, 0, stream>>>(ra_qkv_w, wt_ra_qkv, 256, 768);
    k_wtc<<<dim3(24, 8), blkT, 0, stream>>>(toqkv_w,  wt_toqkv,  256, 768);
    k_wtc<<<dim3(8, 8),  blkT, 0, stream>>>(ha_proj_w, wt_ha_pj, 256, 256);
    k_wtc<<<dim3(8, 8),  blkT, 0, stream>>>(ra_proj_w, wt_ra_pj, 256, 256);
    k_wtc<<<dim3(8, 8),  blkT, 0, stream>>>(proj_w,    wt_pj,    256, 256);

    // x (B,256,1024) -> xT (B,1024,256) token-major
    k_transpose<<<dim3(32, 8, 2), blkT, 0, stream>>>(x, xT, 256, 1024);

    // ---- halo branch ----
    k_patch<<<dim3(6272), blk256, 0, stream>>>(xT, pbuf);
    k_mm_bf<<<dim3(12, 98), blk256, 0, stream>>>(pbuf, wt_ha_qkv, nullptr, nullptr, qkv_ha, 6272, 768, 256);
    k_attn_halo<<<dim3(32, 16), dim3(64), 0, stream>>>(qkv_ha, abuf);
    k_mm_bf<<<dim3(4, 32), blk256, 0, stream>>>(abuf, wt_ha_pj, ha_proj_b, nullptr, ha, 2048, 256, 256);

    // ---- spatial branch (small matmuls stay fp32) ----
    k_matmul<1><<<dim3(1, 32), blk256, 0, stream>>>(xT, sa_w1, sa_b1, nullptr, s1, 2048, 32, 256);
    k_matmul<3><<<dim3(4, 32), blk256, 0, stream>>>(s1, sa_w2, sa_b2, xT, spre, 2048, 256, 32);
    k_gstats<<<dim3(64), blk256, 0, stream>>>(spre, stats);
    k_gnorm_apply<<<dim3(2048), blk256, 0, stream>>>(spre, stats, sa_gn_w, sa_gn_b, sp);

    // ---- shared gnorm stats of x; two affines ----
    k_gstats<<<dim3(64), blk256, 0, stream>>>(xT, stats + 128);
    k_gnorm_apply<<<dim3(2048), blk256, 0, stream>>>(xT, stats + 128, ra_gn_w, ra_gn_b, xn);
    k_gnorm_apply<<<dim3(2048), blk256, 0, stream>>>(xT, stats + 128, gn_w, gn_b, nf);

    // ---- both qkv projections, then ONE batched attention over both sources ----
    k_mm_bf<<<dim3(12, 32), blk256, 0, stream>>>(xn, wt_ra_qkv, nullptr, nullptr, qkv_ra, 2048, 768, 256);
    k_mm_bf<<<dim3(12, 32), blk256, 0, stream>>>(nf, wt_toqkv, toqkv_b, nullptr, qkv_g, 2048, 768, 256);
    k_attn_batch<<<dim3(64, 16), blk256, 0, stream>>>(qkv_ra, qkv_g, abuf, qo);

    // ---- rotation proj (rotations identical by permutation equivariance) ----
    k_mm_bf<<<dim3(4, 32), blk256, 0, stream>>>(abuf, wt_ra_pj, ra_proj_b, xT, ro, 2048, 256, 256);

    // ---- combine + final proj + residual ----
    k_combine<<<dim3(2048), blk256, 0, stream>>>(sp, ha, qo, ro, attn_w, comb);
    k_mm_bf<<<dim3(4, 32), blk256, 0, stream>>>(comb, wt_pj, proj_b, xT, otok, 2048, 256, 256);
    k_transpose<<<dim3(8, 32, 2), blkT, 0, stream>>>(otok, out, 1024, 256);
}

// Round 10
// 327.801 us; speedup vs baseline: 2.7000x; 1.1792x over previous
//
#include <hip/hip_runtime.h>

#define CC 256
#define HWN 1024
#define EPSV 1e-5f

typedef __attribute__((ext_vector_type(8))) short bf16x8;
typedef __attribute__((ext_vector_type(4))) float f32x4;
typedef __attribute__((ext_vector_type(4))) unsigned short u16x4;

__device__ inline ushort f2bf(float f) {
    union { float f; unsigned u; } v; v.f = f;
    unsigned u = v.u;
    u += 0x7fffu + ((u >> 16) & 1u); // round-to-nearest-even
    return (ushort)(u >> 16);
}

// ---------------- transpose (R,Cd) -> (Cd,R), batched, fp32 ----------------
__global__ __launch_bounds__(256) void k_transpose(const float* __restrict__ in,
                                                   float* __restrict__ out, int R, int Cd) {
    __shared__ float tile[32][33];
    int b = blockIdx.z;
    int r0 = blockIdx.y * 32, c0 = blockIdx.x * 32;
    int tx = threadIdx.x, ty = threadIdx.y; // 32 x 8
    const float* inb = in + (size_t)b * R * Cd;
    float* outb = out + (size_t)b * R * Cd;
#pragma unroll
    for (int i = 0; i < 32; i += 8)
        tile[ty + i][tx] = inb[(size_t)(r0 + ty + i) * Cd + c0 + tx];
    __syncthreads();
#pragma unroll
    for (int i = 0; i < 32; i += 8)
        outb[(size_t)(c0 + ty + i) * R + r0 + tx] = tile[tx][ty + i];
}

// ---------------- weight transpose+convert: in fp32 [K][N] -> out bf16 [N][K] ----------------
__global__ __launch_bounds__(256) void k_wtc(const float* __restrict__ in, ushort* __restrict__ out,
                                             int K, int N) {
    __shared__ float tile[32][33];
    int k0 = blockIdx.y * 32, n0 = blockIdx.x * 32;
    int tx = threadIdx.x, ty = threadIdx.y; // 32 x 8
#pragma unroll
    for (int i = 0; i < 32; i += 8)
        tile[ty + i][tx] = in[(size_t)(k0 + ty + i) * N + n0 + tx];
    __syncthreads();
#pragma unroll
    for (int i = 0; i < 32; i += 8)
        out[(size_t)(n0 + ty + i) * K + k0 + tx] = f2bf(tile[tx][ty + i]);
}

// ---------------- bf16 MFMA matmul: out fp32[M,N] = A fp32[M,K] @ Wt bf16[N,K]^T ----------------
__global__ __launch_bounds__(256) void k_mm_bf(const float* __restrict__ A,
                                               const ushort* __restrict__ Wt,
                                               const float* __restrict__ bias,
                                               const float* __restrict__ res,
                                               float* __restrict__ Cp,
                                               int M, int N, int K) {
    __shared__ __align__(16) ushort As[64][40];
    __shared__ __align__(16) ushort Bs[64][40];
    int tid = threadIdx.x;
    int lane = tid & 63, wid = tid >> 6;
    int wr = (wid >> 1) * 32, wc = (wid & 1) * 32;
    int row0 = blockIdx.y * 64, col0 = blockIdx.x * 64;
    int sr = tid >> 2, skq = (tid & 3) * 8;
    int l16 = lane & 15, kg = (lane >> 4) * 8;
    f32x4 acc[2][2] = {};
    for (int k0 = 0; k0 < K; k0 += 32) {
        const float* ap = &A[(size_t)(row0 + sr) * K + k0 + skq];
        float4 a0 = *(const float4*)ap, a1 = *(const float4*)(ap + 4);
        bf16x8 av;
        av[0] = (short)f2bf(a0.x); av[1] = (short)f2bf(a0.y);
        av[2] = (short)f2bf(a0.z); av[3] = (short)f2bf(a0.w);
        av[4] = (short)f2bf(a1.x); av[5] = (short)f2bf(a1.y);
        av[6] = (short)f2bf(a1.z); av[7] = (short)f2bf(a1.w);
        *(bf16x8*)&As[sr][skq] = av;
        *(bf16x8*)&Bs[sr][skq] = *(const bf16x8*)&Wt[(size_t)(col0 + sr) * K + k0 + skq];
        __syncthreads();
        bf16x8 af0 = *(bf16x8*)&As[wr + l16][kg];
        bf16x8 af1 = *(bf16x8*)&As[wr + 16 + l16][kg];
        bf16x8 bf0 = *(bf16x8*)&Bs[wc + l16][kg];
        bf16x8 bf1 = *(bf16x8*)&Bs[wc + 16 + l16][kg];
        acc[0][0] = __builtin_amdgcn_mfma_f32_16x16x32_bf16(af0, bf0, acc[0][0], 0, 0, 0);
        acc[0][1] = __builtin_amdgcn_mfma_f32_16x16x32_bf16(af0, bf1, acc[0][1], 0, 0, 0);
        acc[1][0] = __builtin_amdgcn_mfma_f32_16x16x32_bf16(af1, bf0, acc[1][0], 0, 0, 0);
        acc[1][1] = __builtin_amdgcn_mfma_f32_16x16x32_bf16(af1, bf1, acc[1][1], 0, 0, 0);
        __syncthreads();
    }
#pragma unroll
    for (int fr = 0; fr < 2; fr++)
#pragma unroll
        for (int fc = 0; fc < 2; fc++)
#pragma unroll
            for (int reg = 0; reg < 4; reg++) {
                int r = row0 + wr + fr * 16 + (lane >> 4) * 4 + reg;
                int c = col0 + wc + fc * 16 + l16;
                float v = acc[fr][fc][reg];
                if (bias) v += bias[c];
                if (res) v += res[(size_t)r * N + c];
                Cp[(size_t)r * N + c] = v;
            }
}

// ---------------- tiled fp32 matmul (small spatial matmuls only) ----------------
template <int ACT>
__global__ __launch_bounds__(256) void k_matmul(const float* __restrict__ A,
                                                const float* __restrict__ W,
                                                const float* __restrict__ bias,
                                                const float* __restrict__ res,
                                                float* __restrict__ Cp,
                                                int M, int N, int K) {
    __shared__ float As[16][68];
    __shared__ float Bs[16][64];
    int tid = threadIdx.x;
    int tx = tid & 15, ty = tid >> 4;
    int row0 = blockIdx.y * 64, col0 = blockIdx.x * 64;
    float acc[4][4] = {};
    for (int k0 = 0; k0 < K; k0 += 16) {
#pragma unroll
        for (int l = 0; l < 4; l++) {
            int idx = tid + l * 256;
            int r = idx >> 4, kk = idx & 15;
            int gr = row0 + r, gk = k0 + kk;
            As[kk][r] = (gr < M && gk < K) ? A[(size_t)gr * K + gk] : 0.f;
        }
#pragma unroll
        for (int l = 0; l < 4; l++) {
            int idx = tid + l * 256;
            int kk = idx >> 6, c = idx & 63;
            int gk = k0 + kk, gc = col0 + c;
            Bs[kk][c] = (gk < K && gc < N) ? W[(size_t)gk * N + gc] : 0.f;
        }
        __syncthreads();
#pragma unroll
        for (int kk = 0; kk < 16; kk++) {
            float4 a4 = *(const float4*)&As[kk][ty * 4];
            float4 b4 = *(const float4*)&Bs[kk][tx * 4];
            float av[4] = {a4.x, a4.y, a4.z, a4.w};
            float bv[4] = {b4.x, b4.y, b4.z, b4.w};
#pragma unroll
            for (int i = 0; i < 4; i++)
#pragma unroll
                for (int j = 0; j < 4; j++)
                    acc[i][j] = fmaf(av[i], bv[j], acc[i][j]);
        }
        __syncthreads();
    }
#pragma unroll
    for (int i = 0; i < 4; i++) {
        int r = row0 + ty * 4 + i;
        if (r >= M) continue;
#pragma unroll
        for (int j = 0; j < 4; j++) {
            int c = col0 + tx * 4 + j;
            if (c >= N) continue;
            float v = acc[i][j];
            if (bias) v += bias[c];
            if (ACT == 1) v = fmaxf(v, 0.f);
            if (ACT == 3) {
                float s = 1.f / (1.f + __expf(-v));
                v = res[(size_t)r * N + c] * (1.f + s);
            } else if (res) {
                v += res[(size_t)r * N + c];
            }
            Cp[(size_t)r * N + c] = v;
        }
    }
}

// ---------------- group-norm stats ----------------
__global__ __launch_bounds__(256) void k_gstats(const float* __restrict__ in, float* __restrict__ stats) {
    int bg = blockIdx.x;
    int b = bg >> 5, g = bg & 31;
    int tid = threadIdx.x;
    float s = 0.f, s2 = 0.f;
    for (int idx = tid; idx < HWN * 8; idx += 256) {
        int t = idx >> 3, cc = idx & 7;
        float v = in[(size_t)(b * HWN + t) * CC + g * 8 + cc];
        s += v;
        s2 += v * v;
    }
    __shared__ float sh[2][256];
    sh[0][tid] = s; sh[1][tid] = s2;
    __syncthreads();
    for (int off = 128; off > 0; off >>= 1) {
        if (tid < off) { sh[0][tid] += sh[0][tid + off]; sh[1][tid] += sh[1][tid + off]; }
        __syncthreads();
    }
    if (tid == 0) {
        float mean = sh[0][0] * (1.f / (HWN * 8));
        float var = sh[1][0] * (1.f / (HWN * 8)) - mean * mean;
        stats[bg * 2] = mean;
        stats[bg * 2 + 1] = rsqrtf(var + EPSV);
    }
}

__global__ __launch_bounds__(256) void k_gnorm_apply(const float* __restrict__ in,
                                                     const float* __restrict__ stats,
                                                     const float* __restrict__ w,
                                                     const float* __restrict__ bb,
                                                     float* __restrict__ out) {
    int idx = blockIdx.x * 256 + threadIdx.x;
    int c = idx & 255;
    int t = idx >> 8;
    int b = t >> 10;
    int g = c >> 3;
    float mean = stats[(b * 32 + g) * 2], rstd = stats[(b * 32 + g) * 2 + 1];
    out[idx] = (in[idx] - mean) * rstd * w[c] + bb[c];
}

// ---------------- halo patch gather ----------------
__global__ __launch_bounds__(256) void k_patch(const float* __restrict__ xT, float* __restrict__ p) {
    int rowid = blockIdx.x;
    int blk = rowid / 196, pos = rowid % 196;
    int b = blk >> 4, hb = (blk >> 2) & 3, wb = blk & 3;
    int i = pos / 14, j = pos % 14;
    int y = hb * 8 + i - 3, xx = wb * 8 + j - 3;
    int c = threadIdx.x;
    float v = 0.f;
    if (y >= 0 && y < 32 && xx >= 0 && xx < 32)
        v = xT[(size_t)(b * HWN + y * 32 + xx) * CC + c];
    p[(size_t)rowid * CC + c] = v;
}

// ---------------- MFMA flash attention, both sources ----------------
// Grid (64,16): gx = src*32+bh, gy = 64-query chunk. Block = 4 waves; wave w owns
// queries [gy*64 + w*16, +16) over ALL 1024 keys. Per 32-key tile (cooperatively
// staged K[32][16] bf16 + V^T[16][32] bf16 in LDS, 2 barriers):
//   S^T(16k x 16q) = mfma_16x16x32( A=K-tile (d=16 zero-padded to 32), B=Q^T )
//   P = exp(S*0.25) in-register (branchless, no max: |s|<~6), pack bf16 -> P_lds
//   O(16q x 16d)  += mfma_16x16x32( A=P (K=32 keys), B=V )
// Fragment layouts identical to (HW-verified) k_mm_bf: A[row=l&15][k=(l>>4)*8+j],
// B[k=(l>>4)*8+j][col=l&15], D: col=l&15, row=(l>>4)*4+reg.
// l(q) = in-lane partial + shfl_xor(16,32); divide in epilogue via per-wave LDS.
__global__ __launch_bounds__(256, 4) void k_attn_mfma(const float* __restrict__ qkv0,
                                                      const float* __restrict__ qkv1,
                                                      float* __restrict__ out0,
                                                      float* __restrict__ out1) {
    __shared__ __align__(16) ushort K_lds[32][24];    // [key][16d + pad], 48B rows
    __shared__ __align__(16) ushort V_lds[16][40];    // [d][32key + pad], 80B rows
    __shared__ __align__(16) ushort P_lds[4][16][40]; // per-wave [q][32key + pad]
    __shared__ float l_sh[4][16];
    int gx = blockIdx.x;
    int src = gx >> 5, bh = gx & 31;
    int b = bh >> 4, h = bh & 15;
    const float* qkv = src ? qkv1 : qkv0;
    float* out = src ? out1 : out0;
    int tid = threadIdx.x;
    int lane = tid & 63, wid = tid >> 6;
    int l16 = lane & 15, g = lane >> 4;
    const float* base = qkv + (size_t)b * HWN * 768 + h * 16;
    // Q^T fragment (per-wave constant): lane holds Q[q0+l16][g*8..+7], zero for g>=2
    int q0 = blockIdx.y * 64 + wid * 16;
    bf16x8 qf = {};
    if (g < 2) {
        const float* qp = base + (size_t)(q0 + l16) * 768 + g * 8;
        float4 qa = *(const float4*)qp, qb = *(const float4*)(qp + 4);
        qf[0] = (short)f2bf(qa.x); qf[1] = (short)f2bf(qa.y);
        qf[2] = (short)f2bf(qa.z); qf[3] = (short)f2bf(qa.w);
        qf[4] = (short)f2bf(qb.x); qf[5] = (short)f2bf(qb.y);
        qf[6] = (short)f2bf(qb.z); qf[7] = (short)f2bf(qb.w);
    }
    f32x4 acc = {};
    float lsum = 0.f;
    int skey = tid >> 3, spiece = tid & 7; // staging: 32 keys x 8 float4-pieces
    for (int kb = 0; kb < 32; kb++) {
        __syncthreads(); // prev tile's compute reads done before restage
        {
            const float* rp = base + (size_t)(kb * 32 + skey) * 768;
            if (spiece < 4) {
                float4 kv = *(const float4*)(rp + 256 + spiece * 4);
                u16x4 k4;
                k4[0] = f2bf(kv.x); k4[1] = f2bf(kv.y);
                k4[2] = f2bf(kv.z); k4[3] = f2bf(kv.w);
                *(u16x4*)&K_lds[skey][spiece * 4] = k4;
            } else {
                int dd = (spiece - 4) * 4;
                float4 vv = *(const float4*)(rp + 512 + dd);
                V_lds[dd][skey]     = f2bf(vv.x);
                V_lds[dd + 1][skey] = f2bf(vv.y);
                V_lds[dd + 2][skey] = f2bf(vv.z);
                V_lds[dd + 3][skey] = f2bf(vv.w);
            }
        }
        __syncthreads(); // tile staged
#pragma unroll
        for (int sb = 0; sb < 2; sb++) {
            bf16x8 kf = {};
            if (g < 2)
                kf = *(const bf16x8*)&K_lds[sb * 16 + l16][g * 8];
            f32x4 st = {};
            st = __builtin_amdgcn_mfma_f32_16x16x32_bf16(kf, qf, st, 0, 0, 0);
            float e0 = __expf(st[0] * 0.25f);
            float e1 = __expf(st[1] * 0.25f);
            float e2 = __expf(st[2] * 0.25f);
            float e3 = __expf(st[3] * 0.25f);
            lsum += (e0 + e1) + (e2 + e3);
            u16x4 pp;
            pp[0] = f2bf(e0); pp[1] = f2bf(e1); pp[2] = f2bf(e2); pp[3] = f2bf(e3);
            // S^T elem r = [key = sb*16 + g*4 + r][q = l16]
            *(u16x4*)&P_lds[wid][l16][sb * 16 + g * 4] = pp;
        }
        bf16x8 pf = *(const bf16x8*)&P_lds[wid][l16][g * 8]; // P[q=l16][keys g*8..+7]
        bf16x8 vf = *(const bf16x8*)&V_lds[l16][g * 8];      // V[keys g*8..+7][d=l16]
        acc = __builtin_amdgcn_mfma_f32_16x16x32_bf16(pf, vf, acc, 0, 0, 0);
    }
    // softmax denominator: sum lane partials across the 4 k-groups of each q
    lsum += __shfl_xor(lsum, 16);
    lsum += __shfl_xor(lsum, 32);
    if (g == 0) l_sh[wid][l16] = lsum;
    // O layout: lane holds O[q = g*4+r][d = l16]
#pragma unroll
    for (int r = 0; r < 4; r++) {
        float inv = 1.f / l_sh[wid][g * 4 + r];
        out[(size_t)(b * HWN + q0 + g * 4 + r) * CC + h * 16 + l16] = acc[r] * inv;
    }
}

// ---------------- halo attention (unchanged) ----------------
__global__ __launch_bounds__(64) void k_attn_halo(const float* __restrict__ qkv, float* __restrict__ out) {
    int blk = blockIdx.x;
    int h = blockIdx.y;
    int tid = threadIdx.x;
    __shared__ float Ks[196][16];
    __shared__ float Vs[196][16];
    const float* base = qkv + (size_t)blk * 196 * 768 + h * 16;
    for (int idx = tid; idx < 196 * 4; idx += 64) {
        int kk = idx >> 2, part = idx & 3;
        const float* rowp = base + (size_t)kk * 768 + part * 4;
        *(float4*)&Ks[kk][part * 4] = *(const float4*)(rowp + 256);
        *(float4*)&Vs[kk][part * 4] = *(const float4*)(rowp + 512);
    }
    __syncthreads();
    int ci = tid >> 3, cj = tid & 7;
    int cpos = (3 + ci) * 14 + (3 + cj);
    float q[16];
    {
        const float4* qp = (const float4*)(base + (size_t)cpos * 768);
#pragma unroll
        for (int i = 0; i < 4; i++) {
            float4 v = qp[i];
            q[i * 4] = v.x; q[i * 4 + 1] = v.y; q[i * 4 + 2] = v.z; q[i * 4 + 3] = v.w;
        }
    }
    float l = 0.f, acc[16] = {};
    for (int k4 = 0; k4 < 196; k4 += 4) {
        float s[4] = {};
#pragma unroll
        for (int j = 0; j < 4; j++) {
            const float4* kp = (const float4*)&Ks[k4 + j][0];
#pragma unroll
            for (int i = 0; i < 4; i++) {
                float4 kv = kp[i];
                s[j] = fmaf(q[i * 4], kv.x, s[j]);
                s[j] = fmaf(q[i * 4 + 1], kv.y, s[j]);
                s[j] = fmaf(q[i * 4 + 2], kv.z, s[j]);
                s[j] = fmaf(q[i * 4 + 3], kv.w, s[j]);
            }
        }
        float e[4];
#pragma unroll
        for (int j = 0; j < 4; j++) e[j] = __expf(s[j] * 0.25f);
        l += (e[0] + e[1]) + (e[2] + e[3]);
#pragma unroll
        for (int j = 0; j < 4; j++) {
            const float4* vp = (const float4*)&Vs[k4 + j][0];
#pragma unroll
            for (int i = 0; i < 4; i++) {
                float4 vv = vp[i];
                acc[i * 4]     = fmaf(e[j], vv.x, acc[i * 4]);
                acc[i * 4 + 1] = fmaf(e[j], vv.y, acc[i * 4 + 1]);
                acc[i * 4 + 2] = fmaf(e[j], vv.z, acc[i * 4 + 2]);
                acc[i * 4 + 3] = fmaf(e[j], vv.w, acc[i * 4 + 3]);
            }
        }
    }
    float inv = 1.f / l;
    int b = blk >> 4, hb = (blk >> 2) & 3, wb = blk & 3;
    int t = (hb * 8 + ci) * 32 + wb * 8 + cj;
    float4* op = (float4*)(out + (size_t)(b * HWN + t) * CC + h * 16);
#pragma unroll
    for (int i = 0; i < 4; i++)
        op[i] = make_float4(acc[i * 4] * inv, acc[i * 4 + 1] * inv, acc[i * 4 + 2] * inv, acc[i * 4 + 3] * inv);
}

// ---------------- weighted combine ----------------
__global__ __launch_bounds__(256) void k_combine(const float* __restrict__ sp, const float* __restrict__ ha,
                                                 const float* __restrict__ qo, const float* __restrict__ ro,
                                                 const float* __restrict__ aw, float* __restrict__ comb) {
    int idx = blockIdx.x * 256 + threadIdx.x;
    float a0 = aw[0], a1 = aw[1], a2 = aw[2], a3 = aw[3];
    float mx = fmaxf(fmaxf(a0, a1), fmaxf(a2, a3));
    float e0 = __expf(a0 - mx), e1 = __expf(a1 - mx), e2 = __expf(a2 - mx), e3 = __expf(a3 - mx);
    float inv = 1.f / (e0 + e1 + e2 + e3);
    comb[idx] = (sp[idx] * e0 + ha[idx] * e1 + qo[idx] * e2 + ro[idx] * e3) * inv;
}

extern "C" void kernel_launch(void* const* d_in, const int* in_sizes, int n_in,
                              void* d_out, int out_size, void* d_ws, size_t ws_size,
                              hipStream_t stream) {
    const float* x        = (const float*)d_in[0];
    const float* sa_w1    = (const float*)d_in[1];
    const float* sa_b1    = (const float*)d_in[2];
    const float* sa_w2    = (const float*)d_in[3];
    const float* sa_b2    = (const float*)d_in[4];
    const float* sa_gn_w  = (const float*)d_in[5];
    const float* sa_gn_b  = (const float*)d_in[6];
    const float* ha_qkv_w = (const float*)d_in[7];
    const float* ha_proj_w= (const float*)d_in[8];
    const float* ha_proj_b= (const float*)d_in[9];
    const float* ra_gn_w  = (const float*)d_in[10];
    const float* ra_gn_b  = (const float*)d_in[11];
    const float* ra_qkv_w = (const float*)d_in[12];
    const float* ra_proj_w= (const float*)d_in[13];
    const float* ra_proj_b= (const float*)d_in[14];
    const float* gn_w     = (const float*)d_in[15];
    const float* gn_b     = (const float*)d_in[16];
    const float* toqkv_w  = (const float*)d_in[17];
    const float* toqkv_b  = (const float*)d_in[18];
    const float* attn_w   = (const float*)d_in[19];
    const float* proj_w   = (const float*)d_in[20];
    const float* proj_b   = (const float*)d_in[21];
    float* out = (float*)d_out;

    float* ws = (float*)d_ws;
    size_t off = 0;
    float* xT   = ws + off; off += 524288;
    float* sp   = ws + off; off += 524288;
    float* xn   = ws + off; off += 524288;
    float* nf   = ws + off; off += 524288;
    float* ha   = ws + off; off += 524288;
    float* ro   = ws + off; off += 524288;
    float* qo   = ws + off; off += 524288;
    float* abuf = ws + off; off += 524288;
    float* stats= ws + off; off += 256;
    float* big0 = ws + off; off += 4816896;
    float* big1 = ws + off; off += 1605632;
    // bf16 weight buffers ([N][K] transposed)
    ushort* wt_ha_qkv = (ushort*)(ws + off); off += 98304; // 768*256 bf16
    ushort* wt_ra_qkv = (ushort*)(ws + off); off += 98304;
    ushort* wt_toqkv  = (ushort*)(ws + off); off += 98304;
    ushort* wt_ha_pj  = (ushort*)(ws + off); off += 32768; // 256*256 bf16
    ushort* wt_ra_pj  = (ushort*)(ws + off); off += 32768;
    ushort* wt_pj     = (ushort*)(ws + off); off += 32768;
    float* comb = xn;
    float* otok = nf;
    float* qkv_ha = big0;
    float* qkv_ra = big0;
    float* qkv_g  = big0 + 1572864;
    float* pbuf = big1;
    float* s1   = big1;
    float* spre = big1 + 65536;

    dim3 blk256(256), blkT(32, 8);

    // ---- one-time weight transpose+convert to bf16 [N][K] ----
    k_wtc<<<dim3(24, 8), blkT, 0, stream>>>(ha_qkv_w, wt_ha_qkv, 256, 768);
    k_wtc<<<dim3(24, 8), blkT, 0, stream>>>(ra_qkv_w, wt_ra_qkv, 256, 768);
    k_wtc<<<dim3(24, 8), blkT, 0, stream>>>(toqkv_w,  wt_toqkv,  256, 768);
    k_wtc<<<dim3(8, 8),  blkT, 0, stream>>>(ha_proj_w, wt_ha_pj, 256, 256);
    k_wtc<<<dim3(8, 8),  blkT, 0, stream>>>(ra_proj_w, wt_ra_pj, 256, 256);
    k_wtc<<<dim3(8, 8),  blkT, 0, stream>>>(proj_w,    wt_pj,    256, 256);

    // x (B,256,1024) -> xT (B,1024,256) token-major
    k_transpose<<<dim3(32, 8, 2), blkT, 0, stream>>>(x, xT, 256, 1024);

    // ---- halo branch ----
    k_patch<<<dim3(6272), blk256, 0, stream>>>(xT, pbuf);
    k_mm_bf<<<dim3(12, 98), blk256, 0, stream>>>(pbuf, wt_ha_qkv, nullptr, nullptr, qkv_ha, 6272, 768, 256);
    k_attn_halo<<<dim3(32, 16), dim3(64), 0, stream>>>(qkv_ha, abuf);
    k_mm_bf<<<dim3(4, 32), blk256, 0, stream>>>(abuf, wt_ha_pj, ha_proj_b, nullptr, ha, 2048, 256, 256);

    // ---- spatial branch (small matmuls stay fp32) ----
    k_matmul<1><<<dim3(1, 32), blk256, 0, stream>>>(xT, sa_w1, sa_b1, nullptr, s1, 2048, 32, 256);
    k_matmul<3><<<dim3(4, 32), blk256, 0, stream>>>(s1, sa_w2, sa_b2, xT, spre, 2048, 256, 32);
    k_gstats<<<dim3(64), blk256, 0, stream>>>(spre, stats);
    k_gnorm_apply<<<dim3(2048), blk256, 0, stream>>>(spre, stats, sa_gn_w, sa_gn_b, sp);

    // ---- shared gnorm stats of x; two affines ----
    k_gstats<<<dim3(64), blk256, 0, stream>>>(xT, stats + 128);
    k_gnorm_apply<<<dim3(2048), blk256, 0, stream>>>(xT, stats + 128, ra_gn_w, ra_gn_b, xn);
    k_gnorm_apply<<<dim3(2048), blk256, 0, stream>>>(xT, stats + 128, gn_w, gn_b, nf);

    // ---- both qkv projections, then ONE MFMA attention over both sources ----
    k_mm_bf<<<dim3(12, 32), blk256, 0, stream>>>(xn, wt_ra_qkv, nullptr, nullptr, qkv_ra, 2048, 768, 256);
    k_mm_bf<<<dim3(12, 32), blk256, 0, stream>>>(nf, wt_toqkv, toqkv_b, nullptr, qkv_g, 2048, 768, 256);
    k_attn_mfma<<<dim3(64, 16), blk256, 0, stream>>>(qkv_ra, qkv_g, abuf, qo);

    // ---- rotation proj (rotations identical by permutation equivariance) ----
    k_mm_bf<<<dim3(4, 32), blk256, 0, stream>>>(abuf, wt_ra_pj, ra_proj_b, xT, ro, 2048, 256, 256);

    // ---- combine + final proj + residual ----
    k_combine<<<dim3(2048), blk256, 0, stream>>>(sp, ha, qo, ro, attn_w, comb);
    k_mm_bf<<<dim3(4, 32), blk256, 0, stream>>>(comb, wt_pj, proj_b, xT, otok, 2048, 256, 256);
    k_transpose<<<dim3(8, 32, 2), blkT, 0, stream>>>(otok, out, 1024, 256);
}

// Round 11
// 283.549 us; speedup vs baseline: 3.1213x; 1.1561x over previous
//
#include <hip/hip_runtime.h>

#define CC 256
#define HWN 1024
#define EPSV 1e-5f

typedef __attribute__((ext_vector_type(8))) short bf16x8;
typedef __attribute__((ext_vector_type(4))) float f32x4;
typedef __attribute__((ext_vector_type(4))) unsigned short u16x4;

__device__ inline ushort f2bf(float f) {
    union { float f; unsigned u; } v; v.f = f;
    unsigned u = v.u;
    u += 0x7fffu + ((u >> 16) & 1u); // round-to-nearest-even
    return (ushort)(u >> 16);
}

// ---------------- transpose (R,Cd) -> (Cd,R), batched, fp32 ----------------
__global__ __launch_bounds__(256) void k_transpose(const float* __restrict__ in,
                                                   float* __restrict__ out, int R, int Cd) {
    __shared__ float tile[32][33];
    int b = blockIdx.z;
    int r0 = blockIdx.y * 32, c0 = blockIdx.x * 32;
    int tx = threadIdx.x, ty = threadIdx.y; // 32 x 8
    const float* inb = in + (size_t)b * R * Cd;
    float* outb = out + (size_t)b * R * Cd;
#pragma unroll
    for (int i = 0; i < 32; i += 8)
        tile[ty + i][tx] = inb[(size_t)(r0 + ty + i) * Cd + c0 + tx];
    __syncthreads();
#pragma unroll
    for (int i = 0; i < 32; i += 8)
        outb[(size_t)(c0 + ty + i) * R + r0 + tx] = tile[tx][ty + i];
}

// ---------------- weight transpose+convert: in fp32 [K][N] -> out bf16 [N][K] ----------------
__global__ __launch_bounds__(256) void k_wtc(const float* __restrict__ in, ushort* __restrict__ out,
                                             int K, int N) {
    __shared__ float tile[32][33];
    int k0 = blockIdx.y * 32, n0 = blockIdx.x * 32;
    int tx = threadIdx.x, ty = threadIdx.y; // 32 x 8
#pragma unroll
    for (int i = 0; i < 32; i += 8)
        tile[ty + i][tx] = in[(size_t)(k0 + ty + i) * N + n0 + tx];
    __syncthreads();
#pragma unroll
    for (int i = 0; i < 32; i += 8)
        out[(size_t)(n0 + ty + i) * K + k0 + tx] = f2bf(tile[tx][ty + i]);
}

// ---------------- bf16 MFMA matmul: out fp32[M,N] = A fp32[M,K] @ Wt bf16[N,K]^T ----------------
__global__ __launch_bounds__(256) void k_mm_bf(const float* __restrict__ A,
                                               const ushort* __restrict__ Wt,
                                               const float* __restrict__ bias,
                                               const float* __restrict__ res,
                                               float* __restrict__ Cp,
                                               int M, int N, int K) {
    __shared__ __align__(16) ushort As[64][40];
    __shared__ __align__(16) ushort Bs[64][40];
    int tid = threadIdx.x;
    int lane = tid & 63, wid = tid >> 6;
    int wr = (wid >> 1) * 32, wc = (wid & 1) * 32;
    int row0 = blockIdx.y * 64, col0 = blockIdx.x * 64;
    int sr = tid >> 2, skq = (tid & 3) * 8;
    int l16 = lane & 15, kg = (lane >> 4) * 8;
    f32x4 acc[2][2] = {};
    for (int k0 = 0; k0 < K; k0 += 32) {
        const float* ap = &A[(size_t)(row0 + sr) * K + k0 + skq];
        float4 a0 = *(const float4*)ap, a1 = *(const float4*)(ap + 4);
        bf16x8 av;
        av[0] = (short)f2bf(a0.x); av[1] = (short)f2bf(a0.y);
        av[2] = (short)f2bf(a0.z); av[3] = (short)f2bf(a0.w);
        av[4] = (short)f2bf(a1.x); av[5] = (short)f2bf(a1.y);
        av[6] = (short)f2bf(a1.z); av[7] = (short)f2bf(a1.w);
        *(bf16x8*)&As[sr][skq] = av;
        *(bf16x8*)&Bs[sr][skq] = *(const bf16x8*)&Wt[(size_t)(col0 + sr) * K + k0 + skq];
        __syncthreads();
        bf16x8 af0 = *(bf16x8*)&As[wr + l16][kg];
        bf16x8 af1 = *(bf16x8*)&As[wr + 16 + l16][kg];
        bf16x8 bf0 = *(bf16x8*)&Bs[wc + l16][kg];
        bf16x8 bf1 = *(bf16x8*)&Bs[wc + 16 + l16][kg];
        acc[0][0] = __builtin_amdgcn_mfma_f32_16x16x32_bf16(af0, bf0, acc[0][0], 0, 0, 0);
        acc[0][1] = __builtin_amdgcn_mfma_f32_16x16x32_bf16(af0, bf1, acc[0][1], 0, 0, 0);
        acc[1][0] = __builtin_amdgcn_mfma_f32_16x16x32_bf16(af1, bf0, acc[1][0], 0, 0, 0);
        acc[1][1] = __builtin_amdgcn_mfma_f32_16x16x32_bf16(af1, bf1, acc[1][1], 0, 0, 0);
        __syncthreads();
    }
#pragma unroll
    for (int fr = 0; fr < 2; fr++)
#pragma unroll
        for (int fc = 0; fc < 2; fc++)
#pragma unroll
            for (int reg = 0; reg < 4; reg++) {
                int r = row0 + wr + fr * 16 + (lane >> 4) * 4 + reg;
                int c = col0 + wc + fc * 16 + l16;
                float v = acc[fr][fc][reg];
                if (bias) v += bias[c];
                if (res) v += res[(size_t)r * N + c];
                Cp[(size_t)r * N + c] = v;
            }
}

// ---------------- fused spatial gate: spre = x * (1 + sigmoid(relu(x@w1+b1)@w2+b2)) ----------------
// Grid 128 blocks x 16 tokens. w1 (256x32), w2 (32x256), x-tile staged in LDS once;
// both matmuls register-resident; 2 barriers total (vs 32 global-round-trip iters before).
__global__ __launch_bounds__(256) void k_spatial(const float* __restrict__ xT,
                                                 const float* __restrict__ w1,
                                                 const float* __restrict__ b1,
                                                 const float* __restrict__ w2,
                                                 const float* __restrict__ b2,
                                                 float* __restrict__ spre) {
    __shared__ float w1s[8192];    // [k][col] flat, 32 KB
    __shared__ float w2s[8192];    // [k][col] flat, 32 KB
    __shared__ float xs[16][260];  // [tok][k], pad 260 (bank spread, 16B-aligned rows)
    __shared__ float s1s[16][36];  // [tok][col], pad 36
    int tid = threadIdx.x;
    int tok0 = blockIdx.x * 16;
    {
        const float4* w1v = (const float4*)w1;
        const float4* w2v = (const float4*)w2;
        float4* w1sv = (float4*)w1s;
        float4* w2sv = (float4*)w2s;
        for (int i = tid; i < 2048; i += 256) {
            w1sv[i] = w1v[i];
            w2sv[i] = w2v[i];
        }
        for (int i = tid; i < 1024; i += 256) {
            int tok = i >> 6, part = i & 63;
            *(float4*)&xs[tok][part * 4] =
                *(const float4*)&xT[(size_t)(tok0 + tok) * 256 + part * 4];
        }
    }
    __syncthreads();
    int tok = tid >> 4, col = tid & 15;
    // phase 1: s1[tok][0..31] = relu(x @ w1 + b1), 2 cols/thread
    {
        float a0 = b1[col], a1 = b1[col + 16];
        for (int k = 0; k < 256; k++) {
            float xv = xs[tok][k];
            a0 = fmaf(xv, w1s[k * 32 + col], a0);
            a1 = fmaf(xv, w1s[k * 32 + col + 16], a1);
        }
        s1s[tok][col] = fmaxf(a0, 0.f);
        s1s[tok][col + 16] = fmaxf(a1, 0.f);
    }
    __syncthreads();
    // phase 2: spre[tok][c] = x * (1 + sigmoid(s1 @ w2 + b2)), 16 cols/thread
#pragma unroll 4
    for (int j = 0; j < 16; j++) {
        int c = col + j * 16;
        float a = b2[c];
#pragma unroll
        for (int k = 0; k < 32; k++)
            a = fmaf(s1s[tok][k], w2s[k * 256 + c], a);
        float sg = 1.f / (1.f + __expf(-a));
        spre[(size_t)(tok0 + tok) * 256 + c] = xs[tok][c] * (1.f + sg);
    }
}

// ---------------- group-norm stats ----------------
__global__ __launch_bounds__(256) void k_gstats(const float* __restrict__ in, float* __restrict__ stats) {
    int bg = blockIdx.x;
    int b = bg >> 5, g = bg & 31;
    int tid = threadIdx.x;
    float s = 0.f, s2 = 0.f;
    for (int idx = tid; idx < HWN * 8; idx += 256) {
        int t = idx >> 3, cc = idx & 7;
        float v = in[(size_t)(b * HWN + t) * CC + g * 8 + cc];
        s += v;
        s2 += v * v;
    }
    __shared__ float sh[2][256];
    sh[0][tid] = s; sh[1][tid] = s2;
    __syncthreads();
    for (int off = 128; off > 0; off >>= 1) {
        if (tid < off) { sh[0][tid] += sh[0][tid + off]; sh[1][tid] += sh[1][tid + off]; }
        __syncthreads();
    }
    if (tid == 0) {
        float mean = sh[0][0] * (1.f / (HWN * 8));
        float var = sh[1][0] * (1.f / (HWN * 8)) - mean * mean;
        stats[bg * 2] = mean;
        stats[bg * 2 + 1] = rsqrtf(var + EPSV);
    }
}

__global__ __launch_bounds__(256) void k_gnorm_apply(const float* __restrict__ in,
                                                     const float* __restrict__ stats,
                                                     const float* __restrict__ w,
                                                     const float* __restrict__ bb,
                                                     float* __restrict__ out) {
    int idx = blockIdx.x * 256 + threadIdx.x;
    int c = idx & 255;
    int t = idx >> 8;
    int b = t >> 10;
    int g = c >> 3;
    float mean = stats[(b * 32 + g) * 2], rstd = stats[(b * 32 + g) * 2 + 1];
    out[idx] = (in[idx] - mean) * rstd * w[c] + bb[c];
}

// ---------------- halo patch gather ----------------
__global__ __launch_bounds__(256) void k_patch(const float* __restrict__ xT, float* __restrict__ p) {
    int rowid = blockIdx.x;
    int blk = rowid / 196, pos = rowid % 196;
    int b = blk >> 4, hb = (blk >> 2) & 3, wb = blk & 3;
    int i = pos / 14, j = pos % 14;
    int y = hb * 8 + i - 3, xx = wb * 8 + j - 3;
    int c = threadIdx.x;
    float v = 0.f;
    if (y >= 0 && y < 32 && xx >= 0 && xx < 32)
        v = xT[(size_t)(b * HWN + y * 32 + xx) * CC + c];
    p[(size_t)rowid * CC + c] = v;
}

// ---------------- MFMA flash attention, both sources (unchanged from R10) ----------------
__global__ __launch_bounds__(256, 4) void k_attn_mfma(const float* __restrict__ qkv0,
                                                      const float* __restrict__ qkv1,
                                                      float* __restrict__ out0,
                                                      float* __restrict__ out1) {
    __shared__ __align__(16) ushort K_lds[32][24];
    __shared__ __align__(16) ushort V_lds[16][40];
    __shared__ __align__(16) ushort P_lds[4][16][40];
    __shared__ float l_sh[4][16];
    int gx = blockIdx.x;
    int src = gx >> 5, bh = gx & 31;
    int b = bh >> 4, h = bh & 15;
    const float* qkv = src ? qkv1 : qkv0;
    float* out = src ? out1 : out0;
    int tid = threadIdx.x;
    int lane = tid & 63, wid = tid >> 6;
    int l16 = lane & 15, g = lane >> 4;
    const float* base = qkv + (size_t)b * HWN * 768 + h * 16;
    int q0 = blockIdx.y * 64 + wid * 16;
    bf16x8 qf = {};
    if (g < 2) {
        const float* qp = base + (size_t)(q0 + l16) * 768 + g * 8;
        float4 qa = *(const float4*)qp, qb = *(const float4*)(qp + 4);
        qf[0] = (short)f2bf(qa.x); qf[1] = (short)f2bf(qa.y);
        qf[2] = (short)f2bf(qa.z); qf[3] = (short)f2bf(qa.w);
        qf[4] = (short)f2bf(qb.x); qf[5] = (short)f2bf(qb.y);
        qf[6] = (short)f2bf(qb.z); qf[7] = (short)f2bf(qb.w);
    }
    f32x4 acc = {};
    float lsum = 0.f;
    int skey = tid >> 3, spiece = tid & 7;
    for (int kb = 0; kb < 32; kb++) {
        __syncthreads();
        {
            const float* rp = base + (size_t)(kb * 32 + skey) * 768;
            if (spiece < 4) {
                float4 kv = *(const float4*)(rp + 256 + spiece * 4);
                u16x4 k4;
                k4[0] = f2bf(kv.x); k4[1] = f2bf(kv.y);
                k4[2] = f2bf(kv.z); k4[3] = f2bf(kv.w);
                *(u16x4*)&K_lds[skey][spiece * 4] = k4;
            } else {
                int dd = (spiece - 4) * 4;
                float4 vv = *(const float4*)(rp + 512 + dd);
                V_lds[dd][skey]     = f2bf(vv.x);
                V_lds[dd + 1][skey] = f2bf(vv.y);
                V_lds[dd + 2][skey] = f2bf(vv.z);
                V_lds[dd + 3][skey] = f2bf(vv.w);
            }
        }
        __syncthreads();
#pragma unroll
        for (int sb = 0; sb < 2; sb++) {
            bf16x8 kf = {};
            if (g < 2)
                kf = *(const bf16x8*)&K_lds[sb * 16 + l16][g * 8];
            f32x4 st = {};
            st = __builtin_amdgcn_mfma_f32_16x16x32_bf16(kf, qf, st, 0, 0, 0);
            float e0 = __expf(st[0] * 0.25f);
            float e1 = __expf(st[1] * 0.25f);
            float e2 = __expf(st[2] * 0.25f);
            float e3 = __expf(st[3] * 0.25f);
            lsum += (e0 + e1) + (e2 + e3);
            u16x4 pp;
            pp[0] = f2bf(e0); pp[1] = f2bf(e1); pp[2] = f2bf(e2); pp[3] = f2bf(e3);
            *(u16x4*)&P_lds[wid][l16][sb * 16 + g * 4] = pp;
        }
        bf16x8 pf = *(const bf16x8*)&P_lds[wid][l16][g * 8];
        bf16x8 vf = *(const bf16x8*)&V_lds[l16][g * 8];
        acc = __builtin_amdgcn_mfma_f32_16x16x32_bf16(pf, vf, acc, 0, 0, 0);
    }
    lsum += __shfl_xor(lsum, 16);
    lsum += __shfl_xor(lsum, 32);
    if (g == 0) l_sh[wid][l16] = lsum;
#pragma unroll
    for (int r = 0; r < 4; r++) {
        float inv = 1.f / l_sh[wid][g * 4 + r];
        out[(size_t)(b * HWN + q0 + g * 4 + r) * CC + h * 16 + l16] = acc[r] * inv;
    }
}

// ---------------- halo attention (unchanged) ----------------
__global__ __launch_bounds__(64) void k_attn_halo(const float* __restrict__ qkv, float* __restrict__ out) {
    int blk = blockIdx.x;
    int h = blockIdx.y;
    int tid = threadIdx.x;
    __shared__ float Ks[196][16];
    __shared__ float Vs[196][16];
    const float* base = qkv + (size_t)blk * 196 * 768 + h * 16;
    for (int idx = tid; idx < 196 * 4; idx += 64) {
        int kk = idx >> 2, part = idx & 3;
        const float* rowp = base + (size_t)kk * 768 + part * 4;
        *(float4*)&Ks[kk][part * 4] = *(const float4*)(rowp + 256);
        *(float4*)&Vs[kk][part * 4] = *(const float4*)(rowp + 512);
    }
    __syncthreads();
    int ci = tid >> 3, cj = tid & 7;
    int cpos = (3 + ci) * 14 + (3 + cj);
    float q[16];
    {
        const float4* qp = (const float4*)(base + (size_t)cpos * 768);
#pragma unroll
        for (int i = 0; i < 4; i++) {
            float4 v = qp[i];
            q[i * 4] = v.x; q[i * 4 + 1] = v.y; q[i * 4 + 2] = v.z; q[i * 4 + 3] = v.w;
        }
    }
    float l = 0.f, acc[16] = {};
    for (int k4 = 0; k4 < 196; k4 += 4) {
        float s[4] = {};
#pragma unroll
        for (int j = 0; j < 4; j++) {
            const float4* kp = (const float4*)&Ks[k4 + j][0];
#pragma unroll
            for (int i = 0; i < 4; i++) {
                float4 kv = kp[i];
                s[j] = fmaf(q[i * 4], kv.x, s[j]);
                s[j] = fmaf(q[i * 4 + 1], kv.y, s[j]);
                s[j] = fmaf(q[i * 4 + 2], kv.z, s[j]);
                s[j] = fmaf(q[i * 4 + 3], kv.w, s[j]);
            }
        }
        float e[4];
#pragma unroll
        for (int j = 0; j < 4; j++) e[j] = __expf(s[j] * 0.25f);
        l += (e[0] + e[1]) + (e[2] + e[3]);
#pragma unroll
        for (int j = 0; j < 4; j++) {
            const float4* vp = (const float4*)&Vs[k4 + j][0];
#pragma unroll
            for (int i = 0; i < 4; i++) {
                float4 vv = vp[i];
                acc[i * 4]     = fmaf(e[j], vv.x, acc[i * 4]);
                acc[i * 4 + 1] = fmaf(e[j], vv.y, acc[i * 4 + 1]);
                acc[i * 4 + 2] = fmaf(e[j], vv.z, acc[i * 4 + 2]);
                acc[i * 4 + 3] = fmaf(e[j], vv.w, acc[i * 4 + 3]);
            }
        }
    }
    float inv = 1.f / l;
    int b = blk >> 4, hb = (blk >> 2) & 3, wb = blk & 3;
    int t = (hb * 8 + ci) * 32 + wb * 8 + cj;
    float4* op = (float4*)(out + (size_t)(b * HWN + t) * CC + h * 16);
#pragma unroll
    for (int i = 0; i < 4; i++)
        op[i] = make_float4(acc[i * 4] * inv, acc[i * 4 + 1] * inv, acc[i * 4 + 2] * inv, acc[i * 4 + 3] * inv);
}

// ---------------- weighted combine ----------------
__global__ __launch_bounds__(256) void k_combine(const float* __restrict__ sp, const float* __restrict__ ha,
                                                 const float* __restrict__ qo, const float* __restrict__ ro,
                                                 const float* __restrict__ aw, float* __restrict__ comb) {
    int idx = blockIdx.x * 256 + threadIdx.x;
    float a0 = aw[0], a1 = aw[1], a2 = aw[2], a3 = aw[3];
    float mx = fmaxf(fmaxf(a0, a1), fmaxf(a2, a3));
    float e0 = __expf(a0 - mx), e1 = __expf(a1 - mx), e2 = __expf(a2 - mx), e3 = __expf(a3 - mx);
    float inv = 1.f / (e0 + e1 + e2 + e3);
    comb[idx] = (sp[idx] * e0 + ha[idx] * e1 + qo[idx] * e2 + ro[idx] * e3) * inv;
}

extern "C" void kernel_launch(void* const* d_in, const int* in_sizes, int n_in,
                              void* d_out, int out_size, void* d_ws, size_t ws_size,
                              hipStream_t stream) {
    const float* x        = (const float*)d_in[0];
    const float* sa_w1    = (const float*)d_in[1];
    const float* sa_b1    = (const float*)d_in[2];
    const float* sa_w2    = (const float*)d_in[3];
    const float* sa_b2    = (const float*)d_in[4];
    const float* sa_gn_w  = (const float*)d_in[5];
    const float* sa_gn_b  = (const float*)d_in[6];
    const float* ha_qkv_w = (const float*)d_in[7];
    const float* ha_proj_w= (const float*)d_in[8];
    const float* ha_proj_b= (const float*)d_in[9];
    const float* ra_gn_w  = (const float*)d_in[10];
    const float* ra_gn_b  = (const float*)d_in[11];
    const float* ra_qkv_w = (const float*)d_in[12];
    const float* ra_proj_w= (const float*)d_in[13];
    const float* ra_proj_b= (const float*)d_in[14];
    const float* gn_w     = (const float*)d_in[15];
    const float* gn_b     = (const float*)d_in[16];
    const float* toqkv_w  = (const float*)d_in[17];
    const float* toqkv_b  = (const float*)d_in[18];
    const float* attn_w   = (const float*)d_in[19];
    const float* proj_w   = (const float*)d_in[20];
    const float* proj_b   = (const float*)d_in[21];
    float* out = (float*)d_out;

    float* ws = (float*)d_ws;
    size_t off = 0;
    float* xT   = ws + off; off += 524288;
    float* sp   = ws + off; off += 524288;
    float* xn   = ws + off; off += 524288;
    float* nf   = ws + off; off += 524288;
    float* ha   = ws + off; off += 524288;
    float* ro   = ws + off; off += 524288;
    float* qo   = ws + off; off += 524288;
    float* abuf = ws + off; off += 524288;
    float* stats= ws + off; off += 256;
    float* big0 = ws + off; off += 4816896;
    float* big1 = ws + off; off += 1605632;
    // bf16 weight buffers ([N][K] transposed)
    ushort* wt_ha_qkv = (ushort*)(ws + off); off += 98304; // 768*256 bf16
    ushort* wt_ra_qkv = (ushort*)(ws + off); off += 98304;
    ushort* wt_toqkv  = (ushort*)(ws + off); off += 98304;
    ushort* wt_ha_pj  = (ushort*)(ws + off); off += 32768; // 256*256 bf16
    ushort* wt_ra_pj  = (ushort*)(ws + off); off += 32768;
    ushort* wt_pj     = (ushort*)(ws + off); off += 32768;
    float* comb = xn;
    float* otok = nf;
    float* qkv_ha = big0;
    float* qkv_ra = big0;
    float* qkv_g  = big0 + 1572864;
    float* pbuf = big1;
    float* spre = big1 + 65536;

    dim3 blk256(256), blkT(32, 8);

    // ---- one-time weight transpose+convert to bf16 [N][K] ----
    k_wtc<<<dim3(24, 8), blkT, 0, stream>>>(ha_qkv_w, wt_ha_qkv, 256, 768);
    k_wtc<<<dim3(24, 8), blkT, 0, stream>>>(ra_qkv_w, wt_ra_qkv, 256, 768);
    k_wtc<<<dim3(24, 8), blkT, 0, stream>>>(toqkv_w,  wt_toqkv,  256, 768);
    k_wtc<<<dim3(8, 8),  blkT, 0, stream>>>(ha_proj_w, wt_ha_pj, 256, 256);
    k_wtc<<<dim3(8, 8),  blkT, 0, stream>>>(ra_proj_w, wt_ra_pj, 256, 256);
    k_wtc<<<dim3(8, 8),  blkT, 0, stream>>>(proj_w,    wt_pj,    256, 256);

    // x (B,256,1024) -> xT (B,1024,256) token-major
    k_transpose<<<dim3(32, 8, 2), blkT, 0, stream>>>(x, xT, 256, 1024);

    // ---- halo branch ----
    k_patch<<<dim3(6272), blk256, 0, stream>>>(xT, pbuf);
    k_mm_bf<<<dim3(12, 98), blk256, 0, stream>>>(pbuf, wt_ha_qkv, nullptr, nullptr, qkv_ha, 6272, 768, 256);
    k_attn_halo<<<dim3(32, 16), dim3(64), 0, stream>>>(qkv_ha, abuf);
    k_mm_bf<<<dim3(4, 32), blk256, 0, stream>>>(abuf, wt_ha_pj, ha_proj_b, nullptr, ha, 2048, 256, 256);

    // ---- spatial branch: fused gate (was 2 latency-bound fp32 matmuls) ----
    k_spatial<<<dim3(128), blk256, 0, stream>>>(xT, sa_w1, sa_b1, sa_w2, sa_b2, spre);
    k_gstats<<<dim3(64), blk256, 0, stream>>>(spre, stats);
    k_gnorm_apply<<<dim3(2048), blk256, 0, stream>>>(spre, stats, sa_gn_w, sa_gn_b, sp);

    // ---- shared gnorm stats of x; two affines ----
    k_gstats<<<dim3(64), blk256, 0, stream>>>(xT, stats + 128);
    k_gnorm_apply<<<dim3(2048), blk256, 0, stream>>>(xT, stats + 128, ra_gn_w, ra_gn_b, xn);
    k_gnorm_apply<<<dim3(2048), blk256, 0, stream>>>(xT, stats + 128, gn_w, gn_b, nf);

    // ---- both qkv projections, then ONE MFMA attention over both sources ----
    k_mm_bf<<<dim3(12, 32), blk256, 0, stream>>>(xn, wt_ra_qkv, nullptr, nullptr, qkv_ra, 2048, 768, 256);
    k_mm_bf<<<dim3(12, 32), blk256, 0, stream>>>(nf, wt_toqkv, toqkv_b, nullptr, qkv_g, 2048, 768, 256);
    k_attn_mfma<<<dim3(64, 16), blk256, 0, stream>>>(qkv_ra, qkv_g, abuf, qo);

    // ---- rotation proj (rotations identical by permutation equivariance) ----
    k_mm_bf<<<dim3(4, 32), blk256, 0, stream>>>(abuf, wt_ra_pj, ra_proj_b, xT, ro, 2048, 256, 256);

    // ---- combine + final proj + residual ----
    k_combine<<<dim3(2048), blk256, 0, stream>>>(sp, ha, qo, ro, attn_w, comb);
    k_mm_bf<<<dim3(4, 32), blk256, 0, stream>>>(comb, wt_pj, proj_b, xT, otok, 2048, 256, 256);
    k_transpose<<<dim3(8, 32, 2), blkT, 0, stream>>>(otok, out, 1024, 256);
}

// Round 14
// 271.639 us; speedup vs baseline: 3.2582x; 1.0438x over previous
//
#include <hip/hip_runtime.h>

#define CC 256
#define HWN 1024
#define EPSV 1e-5f

typedef __attribute__((ext_vector_type(8))) short bf16x8;
typedef __attribute__((ext_vector_type(4))) float f32x4;
typedef __attribute__((ext_vector_type(4))) unsigned short u16x4;

__device__ inline ushort f2bf(float f) {
    union { float f; unsigned u; } v; v.f = f;
    unsigned u = v.u;
    u += 0x7fffu + ((u >> 16) & 1u); // round-to-nearest-even
    return (ushort)(u >> 16);
}
__device__ inline void store_out(float* p, float v) { *p = v; }
__device__ inline void store_out(ushort* p, float v) { *p = f2bf(v); }

// ---------------- transpose (R,Cd) -> (Cd,R), batched, fp32 ----------------
__global__ __launch_bounds__(256) void k_transpose(const float* __restrict__ in,
                                                   float* __restrict__ out, int R, int Cd) {
    __shared__ float tile[32][33];
    int b = blockIdx.z;
    int r0 = blockIdx.y * 32, c0 = blockIdx.x * 32;
    int tx = threadIdx.x, ty = threadIdx.y; // 32 x 8
    const float* inb = in + (size_t)b * R * Cd;
    float* outb = out + (size_t)b * R * Cd;
#pragma unroll
    for (int i = 0; i < 32; i += 8)
        tile[ty + i][tx] = inb[(size_t)(r0 + ty + i) * Cd + c0 + tx];
    __syncthreads();
#pragma unroll
    for (int i = 0; i < 32; i += 8)
        outb[(size_t)(c0 + ty + i) * R + r0 + tx] = tile[tx][ty + i];
}

// ---------------- all six weight transpose+converts in ONE launch ----------------
// in fp32 [256][N] -> out bf16 [N][256]; z selects the weight; grid (24,8,6), proj z>=3 guard.
__global__ __launch_bounds__(256) void k_wtc_all(const float* __restrict__ s0, const float* __restrict__ s1,
                                                 const float* __restrict__ s2, const float* __restrict__ s3,
                                                 const float* __restrict__ s4, const float* __restrict__ s5,
                                                 ushort* __restrict__ d0, ushort* __restrict__ d1,
                                                 ushort* __restrict__ d2, ushort* __restrict__ d3,
                                                 ushort* __restrict__ d4, ushort* __restrict__ d5) {
    __shared__ float tile[32][33];
    int z = blockIdx.z;
    const float* in; ushort* out; int N;
    switch (z) {
        case 0: in = s0; out = d0; N = 768; break;
        case 1: in = s1; out = d1; N = 768; break;
        case 2: in = s2; out = d2; N = 768; break;
        case 3: in = s3; out = d3; N = 256; break;
        case 4: in = s4; out = d4; N = 256; break;
        default: in = s5; out = d5; N = 256; break;
    }
    int n0 = blockIdx.x * 32;
    if (n0 >= N) return;
    int k0 = blockIdx.y * 32;
    int tx = threadIdx.x, ty = threadIdx.y; // 32 x 8
#pragma unroll
    for (int i = 0; i < 32; i += 8)
        tile[ty + i][tx] = in[(size_t)(k0 + ty + i) * N + n0 + tx];
    __syncthreads();
#pragma unroll
    for (int i = 0; i < 32; i += 8)
        out[(size_t)(n0 + ty + i) * 256 + k0 + tx] = f2bf(tile[tx][ty + i]);
}

// ---------------- bf16 MFMA matmul: out[M,N] = A fp32[M,K] @ Wt bf16[N,K]^T ----------------
// OT = float (fp32 out) or ushort (bf16 out, for attention-consumed qkv).
template <typename OT>
__global__ __launch_bounds__(256) void k_mm_bf(const float* __restrict__ A,
                                               const ushort* __restrict__ Wt,
                                               const float* __restrict__ bias,
                                               const float* __restrict__ res,
                                               OT* __restrict__ Cp,
                                               int M, int N, int K) {
    __shared__ __align__(16) ushort As[64][40];
    __shared__ __align__(16) ushort Bs[64][40];
    int tid = threadIdx.x;
    int lane = tid & 63, wid = tid >> 6;
    int wr = (wid >> 1) * 32, wc = (wid & 1) * 32;
    int row0 = blockIdx.y * 64, col0 = blockIdx.x * 64;
    int sr = tid >> 2, skq = (tid & 3) * 8;
    int l16 = lane & 15, kg = (lane >> 4) * 8;
    f32x4 acc[2][2] = {};
    for (int k0 = 0; k0 < K; k0 += 32) {
        const float* ap = &A[(size_t)(row0 + sr) * K + k0 + skq];
        float4 a0 = *(const float4*)ap, a1 = *(const float4*)(ap + 4);
        bf16x8 av;
        av[0] = (short)f2bf(a0.x); av[1] = (short)f2bf(a0.y);
        av[2] = (short)f2bf(a0.z); av[3] = (short)f2bf(a0.w);
        av[4] = (short)f2bf(a1.x); av[5] = (short)f2bf(a1.y);
        av[6] = (short)f2bf(a1.z); av[7] = (short)f2bf(a1.w);
        *(bf16x8*)&As[sr][skq] = av;
        *(bf16x8*)&Bs[sr][skq] = *(const bf16x8*)&Wt[(size_t)(col0 + sr) * K + k0 + skq];
        __syncthreads();
        bf16x8 af0 = *(bf16x8*)&As[wr + l16][kg];
        bf16x8 af1 = *(bf16x8*)&As[wr + 16 + l16][kg];
        bf16x8 bf0 = *(bf16x8*)&Bs[wc + l16][kg];
        bf16x8 bf1 = *(bf16x8*)&Bs[wc + 16 + l16][kg];
        acc[0][0] = __builtin_amdgcn_mfma_f32_16x16x32_bf16(af0, bf0, acc[0][0], 0, 0, 0);
        acc[0][1] = __builtin_amdgcn_mfma_f32_16x16x32_bf16(af0, bf1, acc[0][1], 0, 0, 0);
        acc[1][0] = __builtin_amdgcn_mfma_f32_16x16x32_bf16(af1, bf0, acc[1][0], 0, 0, 0);
        acc[1][1] = __builtin_amdgcn_mfma_f32_16x16x32_bf16(af1, bf1, acc[1][1], 0, 0, 0);
        __syncthreads();
    }
#pragma unroll
    for (int fr = 0; fr < 2; fr++)
#pragma unroll
        for (int fc = 0; fc < 2; fc++)
#pragma unroll
            for (int reg = 0; reg < 4; reg++) {
                int r = row0 + wr + fr * 16 + (lane >> 4) * 4 + reg;
                int c = col0 + wc + fc * 16 + l16;
                float v = acc[fr][fc][reg];
                if (bias) v += bias[c];
                if (res) v += res[(size_t)r * N + c];
                store_out(&Cp[(size_t)r * N + c], v);
            }
}

// ---------------- fused spatial gate (unchanged from R11) ----------------
__global__ __launch_bounds__(256) void k_spatial(const float* __restrict__ xT,
                                                 const float* __restrict__ w1,
                                                 const float* __restrict__ b1,
                                                 const float* __restrict__ w2,
                                                 const float* __restrict__ b2,
                                                 float* __restrict__ spre) {
    __shared__ float w1s[8192];
    __shared__ float w2s[8192];
    __shared__ float xs[16][260];
    __shared__ float s1s[16][36];
    int tid = threadIdx.x;
    int tok0 = blockIdx.x * 16;
    {
        const float4* w1v = (const float4*)w1;
        const float4* w2v = (const float4*)w2;
        float4* w1sv = (float4*)w1s;
        float4* w2sv = (float4*)w2s;
        for (int i = tid; i < 2048; i += 256) {
            w1sv[i] = w1v[i];
            w2sv[i] = w2v[i];
        }
        for (int i = tid; i < 1024; i += 256) {
            int tok = i >> 6, part = i & 63;
            *(float4*)&xs[tok][part * 4] =
                *(const float4*)&xT[(size_t)(tok0 + tok) * 256 + part * 4];
        }
    }
    __syncthreads();
    int tok = tid >> 4, col = tid & 15;
    {
        float a0 = b1[col], a1 = b1[col + 16];
        for (int k = 0; k < 256; k++) {
            float xv = xs[tok][k];
            a0 = fmaf(xv, w1s[k * 32 + col], a0);
            a1 = fmaf(xv, w1s[k * 32 + col + 16], a1);
        }
        s1s[tok][col] = fmaxf(a0, 0.f);
        s1s[tok][col + 16] = fmaxf(a1, 0.f);
    }
    __syncthreads();
#pragma unroll 4
    for (int j = 0; j < 16; j++) {
        int c = col + j * 16;
        float a = b2[c];
#pragma unroll
        for (int k = 0; k < 32; k++)
            a = fmaf(s1s[tok][k], w2s[k * 256 + c], a);
        float sg = 1.f / (1.f + __expf(-a));
        spre[(size_t)(tok0 + tok) * 256 + c] = xs[tok][c] * (1.f + sg);
    }
}

// ---------------- group-norm stats ----------------
__global__ __launch_bounds__(256) void k_gstats(const float* __restrict__ in, float* __restrict__ stats) {
    int bg = blockIdx.x;
    int b = bg >> 5, g = bg & 31;
    int tid = threadIdx.x;
    float s = 0.f, s2 = 0.f;
    for (int idx = tid; idx < HWN * 8; idx += 256) {
        int t = idx >> 3, cc = idx & 7;
        float v = in[(size_t)(b * HWN + t) * CC + g * 8 + cc];
        s += v;
        s2 += v * v;
    }
    __shared__ float sh[2][256];
    sh[0][tid] = s; sh[1][tid] = s2;
    __syncthreads();
    for (int off = 128; off > 0; off >>= 1) {
        if (tid < off) { sh[0][tid] += sh[0][tid + off]; sh[1][tid] += sh[1][tid + off]; }
        __syncthreads();
    }
    if (tid == 0) {
        float mean = sh[0][0] * (1.f / (HWN * 8));
        float var = sh[1][0] * (1.f / (HWN * 8)) - mean * mean;
        stats[bg * 2] = mean;
        stats[bg * 2 + 1] = rsqrtf(var + EPSV);
    }
}

__global__ __launch_bounds__(256) void k_gnorm_apply(const float* __restrict__ in,
                                                     const float* __restrict__ stats,
                                                     const float* __restrict__ w,
                                                     const float* __restrict__ bb,
                                                     float* __restrict__ out) {
    int idx = blockIdx.x * 256 + threadIdx.x;
    int c = idx & 255;
    int t = idx >> 8;
    int b = t >> 10;
    int g = c >> 3;
    float mean = stats[(b * 32 + g) * 2], rstd = stats[(b * 32 + g) * 2 + 1];
    out[idx] = (in[idx] - mean) * rstd * w[c] + bb[c];
}

// ---------------- halo patch gather ----------------
__global__ __launch_bounds__(256) void k_patch(const float* __restrict__ xT, float* __restrict__ p) {
    int rowid = blockIdx.x;
    int blk = rowid / 196, pos = rowid % 196;
    int b = blk >> 4, hb = (blk >> 2) & 3, wb = blk & 3;
    int i = pos / 14, j = pos % 14;
    int y = hb * 8 + i - 3, xx = wb * 8 + j - 3;
    int c = threadIdx.x;
    float v = 0.f;
    if (y >= 0 && y < 32 && xx >= 0 && xx < 32)
        v = xT[(size_t)(b * HWN + y * 32 + xx) * CC + c];
    p[(size_t)rowid * CC + c] = v;
}

// ---------------- MFMA flash attention, bf16 qkv inputs ----------------
// Same structure as R10 (HW-verified), but qkv is pre-converted bf16 from the
// producer matmul: staging is plain ushort copies (no f2bf), Q frag is a direct
// 16B load. Grid (64,16), 4 waves, wave = 16 queries x all 1024 keys.
__global__ __launch_bounds__(256, 4) void k_attn_mfma(const ushort* __restrict__ qkv0,
                                                      const ushort* __restrict__ qkv1,
                                                      float* __restrict__ out0,
                                                      float* __restrict__ out1) {
    __shared__ __align__(16) ushort K_lds[32][24];    // [key][16d + pad]
    __shared__ __align__(16) ushort V_lds[16][40];    // [d][32key + pad]
    __shared__ __align__(16) ushort P_lds[4][16][40]; // per-wave [q][32key + pad]
    __shared__ float l_sh[4][16];
    int gx = blockIdx.x;
    int src = gx >> 5, bh = gx & 31;
    int b = bh >> 4, h = bh & 15;
    const ushort* qkv = src ? qkv1 : qkv0;
    float* out = src ? out1 : out0;
    int tid = threadIdx.x;
    int lane = tid & 63, wid = tid >> 6;
    int l16 = lane & 15, g = lane >> 4;
    const ushort* base = qkv + (size_t)b * HWN * 768 + h * 16;
    int q0 = blockIdx.y * 64 + wid * 16;
    bf16x8 qf = {};
    if (g < 2)
        qf = *(const bf16x8*)(base + (size_t)(q0 + l16) * 768 + g * 8);
    f32x4 acc = {};
    float lsum = 0.f;
    int skey = tid >> 3, spiece = tid & 7; // 32 keys x 8 pieces
    for (int kb = 0; kb < 32; kb++) {
        __syncthreads();
        {
            const ushort* rp = base + (size_t)(kb * 32 + skey) * 768;
            if (spiece < 4) {
                *(u16x4*)&K_lds[skey][spiece * 4] = *(const u16x4*)(rp + 256 + spiece * 4);
            } else {
                int dd = (spiece - 4) * 4;
                u16x4 vv = *(const u16x4*)(rp + 512 + dd);
                V_lds[dd][skey]     = vv[0];
                V_lds[dd + 1][skey] = vv[1];
                V_lds[dd + 2][skey] = vv[2];
                V_lds[dd + 3][skey] = vv[3];
            }
        }
        __syncthreads();
#pragma unroll
        for (int sb = 0; sb < 2; sb++) {
            bf16x8 kf = {};
            if (g < 2)
                kf = *(const bf16x8*)&K_lds[sb * 16 + l16][g * 8];
            f32x4 st = {};
            st = __builtin_amdgcn_mfma_f32_16x16x32_bf16(kf, qf, st, 0, 0, 0);
            float e0 = __expf(st[0] * 0.25f);
            float e1 = __expf(st[1] * 0.25f);
            float e2 = __expf(st[2] * 0.25f);
            float e3 = __expf(st[3] * 0.25f);
            lsum += (e0 + e1) + (e2 + e3);
            u16x4 pp;
            pp[0] = f2bf(e0); pp[1] = f2bf(e1); pp[2] = f2bf(e2); pp[3] = f2bf(e3);
            *(u16x4*)&P_lds[wid][l16][sb * 16 + g * 4] = pp;
        }
        bf16x8 pf = *(const bf16x8*)&P_lds[wid][l16][g * 8];
        bf16x8 vf = *(const bf16x8*)&V_lds[l16][g * 8];
        acc = __builtin_amdgcn_mfma_f32_16x16x32_bf16(pf, vf, acc, 0, 0, 0);
    }
    lsum += __shfl_xor(lsum, 16);
    lsum += __shfl_xor(lsum, 32);
    if (g == 0) l_sh[wid][l16] = lsum;
#pragma unroll
    for (int r = 0; r < 4; r++) {
        float inv = 1.f / l_sh[wid][g * 4 + r];
        out[(size_t)(b * HWN + q0 + g * 4 + r) * CC + h * 16 + l16] = acc[r] * inv;
    }
}

// ---------------- halo attention (unchanged, fp32 qkv) ----------------
__global__ __launch_bounds__(64) void k_attn_halo(const float* __restrict__ qkv, float* __restrict__ out) {
    int blk = blockIdx.x;
    int h = blockIdx.y;
    int tid = threadIdx.x;
    __shared__ float Ks[196][16];
    __shared__ float Vs[196][16];
    const float* base = qkv + (size_t)blk * 196 * 768 + h * 16;
    for (int idx = tid; idx < 196 * 4; idx += 64) {
        int kk = idx >> 2, part = idx & 3;
        const float* rowp = base + (size_t)kk * 768 + part * 4;
        *(float4*)&Ks[kk][part * 4] = *(const float4*)(rowp + 256);
        *(float4*)&Vs[kk][part * 4] = *(const float4*)(rowp + 512);
    }
    __syncthreads();
    int ci = tid >> 3, cj = tid & 7;
    int cpos = (3 + ci) * 14 + (3 + cj);
    float q[16];
    {
        const float4* qp = (const float4*)(base + (size_t)cpos * 768);
#pragma unroll
        for (int i = 0; i < 4; i++) {
            float4 v = qp[i];
            q[i * 4] = v.x; q[i * 4 + 1] = v.y; q[i * 4 + 2] = v.z; q[i * 4 + 3] = v.w;
        }
    }
    float l = 0.f, acc[16] = {};
    for (int k4 = 0; k4 < 196; k4 += 4) {
        float s[4] = {};
#pragma unroll
        for (int j = 0; j < 4; j++) {
            const float4* kp = (const float4*)&Ks[k4 + j][0];
#pragma unroll
            for (int i = 0; i < 4; i++) {
                float4 kv = kp[i];
                s[j] = fmaf(q[i * 4], kv.x, s[j]);
                s[j] = fmaf(q[i * 4 + 1], kv.y, s[j]);
                s[j] = fmaf(q[i * 4 + 2], kv.z, s[j]);
                s[j] = fmaf(q[i * 4 + 3], kv.w, s[j]);
            }
        }
        float e[4];
#pragma unroll
        for (int j = 0; j < 4; j++) e[j] = __expf(s[j] * 0.25f);
        l += (e[0] + e[1]) + (e[2] + e[3]);
#pragma unroll
        for (int j = 0; j < 4; j++) {
            const float4* vp = (const float4*)&Vs[k4 + j][0];
#pragma unroll
            for (int i = 0; i < 4; i++) {
                float4 vv = vp[i];
                acc[i * 4]     = fmaf(e[j], vv.x, acc[i * 4]);
                acc[i * 4 + 1] = fmaf(e[j], vv.y, acc[i * 4 + 1]);
                acc[i * 4 + 2] = fmaf(e[j], vv.z, acc[i * 4 + 2]);
                acc[i * 4 + 3] = fmaf(e[j], vv.w, acc[i * 4 + 3]);
            }
        }
    }
    float inv = 1.f / l;
    int b = blk >> 4, hb = (blk >> 2) & 3, wb = blk & 3;
    int t = (hb * 8 + ci) * 32 + wb * 8 + cj;
    float4* op = (float4*)(out + (size_t)(b * HWN + t) * CC + h * 16);
#pragma unroll
    for (int i = 0; i < 4; i++)
        op[i] = make_float4(acc[i * 4] * inv, acc[i * 4 + 1] * inv, acc[i * 4 + 2] * inv, acc[i * 4 + 3] * inv);
}

// ---------------- weighted combine ----------------
__global__ __launch_bounds__(256) void k_combine(const float* __restrict__ sp, const float* __restrict__ ha,
                                                 const float* __restrict__ qo, const float* __restrict__ ro,
                                                 const float* __restrict__ aw, float* __restrict__ comb) {
    int idx = blockIdx.x * 256 + threadIdx.x;
    float a0 = aw[0], a1 = aw[1], a2 = aw[2], a3 = aw[3];
    float mx = fmaxf(fmaxf(a0, a1), fmaxf(a2, a3));
    float e0 = __expf(a0 - mx), e1 = __expf(a1 - mx), e2 = __expf(a2 - mx), e3 = __expf(a3 - mx);
    float inv = 1.f / (e0 + e1 + e2 + e3);
    comb[idx] = (sp[idx] * e0 + ha[idx] * e1 + qo[idx] * e2 + ro[idx] * e3) * inv;
}

extern "C" void kernel_launch(void* const* d_in, const int* in_sizes, int n_in,
                              void* d_out, int out_size, void* d_ws, size_t ws_size,
                              hipStream_t stream) {
    const float* x        = (const float*)d_in[0];
    const float* sa_w1    = (const float*)d_in[1];
    const float* sa_b1    = (const float*)d_in[2];
    const float* sa_w2    = (const float*)d_in[3];
    const float* sa_b2    = (const float*)d_in[4];
    const float* sa_gn_w  = (const float*)d_in[5];
    const float* sa_gn_b  = (const float*)d_in[6];
    const float* ha_qkv_w = (const float*)d_in[7];
    const float* ha_proj_w= (const float*)d_in[8];
    const float* ha_proj_b= (const float*)d_in[9];
    const float* ra_gn_w  = (const float*)d_in[10];
    const float* ra_gn_b  = (const float*)d_in[11];
    const float* ra_qkv_w = (const float*)d_in[12];
    const float* ra_proj_w= (const float*)d_in[13];
    const float* ra_proj_b= (const float*)d_in[14];
    const float* gn_w     = (const float*)d_in[15];
    const float* gn_b     = (const float*)d_in[16];
    const float* toqkv_w  = (const float*)d_in[17];
    const float* toqkv_b  = (const float*)d_in[18];
    const float* attn_w   = (const float*)d_in[19];
    const float* proj_w   = (const float*)d_in[20];
    const float* proj_b   = (const float*)d_in[21];
    float* out = (float*)d_out;

    float* ws = (float*)d_ws;
    size_t off = 0;
    float* xT   = ws + off; off += 524288;
    float* sp   = ws + off; off += 524288;
    float* xn   = ws + off; off += 524288;
    float* nf   = ws + off; off += 524288;
    float* ha   = ws + off; off += 524288;
    float* ro   = ws + off; off += 524288;
    float* qo   = ws + off; off += 524288;
    float* abuf = ws + off; off += 524288;
    float* stats= ws + off; off += 256;
    float* big0 = ws + off; off += 4816896;
    float* big1 = ws + off; off += 1605632;
    // bf16 weight buffers ([N][K] transposed)
    ushort* wt_ha_qkv = (ushort*)(ws + off); off += 98304; // 768*256 bf16
    ushort* wt_ra_qkv = (ushort*)(ws + off); off += 98304;
    ushort* wt_toqkv  = (ushort*)(ws + off); off += 98304;
    ushort* wt_ha_pj  = (ushort*)(ws + off); off += 32768; // 256*256 bf16
    ushort* wt_ra_pj  = (ushort*)(ws + off); off += 32768;
    ushort* wt_pj     = (ushort*)(ws + off); off += 32768;
    float* comb = xn;
    float* otok = nf;
    float* qkv_ha = big0;                               // fp32, halo only
    ushort* qkv_ra_bf = (ushort*)big0;                  // bf16, after halo done
    ushort* qkv_g_bf  = (ushort*)(big0 + 786432);       // bf16 (3 MB offset)
    float* pbuf = big1;
    float* spre = big1 + 65536;

    dim3 blk256(256), blkT(32, 8);

    // ---- one-time weight transpose+convert (single launch for all six) ----
    k_wtc_all<<<dim3(24, 8, 6), blkT, 0, stream>>>(
        ha_qkv_w, ra_qkv_w, toqkv_w, ha_proj_w, ra_proj_w, proj_w,
        wt_ha_qkv, wt_ra_qkv, wt_toqkv, wt_ha_pj, wt_ra_pj, wt_pj);

    // x (B,256,1024) -> xT (B,1024,256) token-major
    k_transpose<<<dim3(32, 8, 2), blkT, 0, stream>>>(x, xT, 256, 1024);

    // ---- halo branch ----
    k_patch<<<dim3(6272), blk256, 0, stream>>>(xT, pbuf);
    k_mm_bf<float><<<dim3(12, 98), blk256, 0, stream>>>(pbuf, wt_ha_qkv, nullptr, nullptr, qkv_ha, 6272, 768, 256);
    k_attn_halo<<<dim3(32, 16), dim3(64), 0, stream>>>(qkv_ha, abuf);
    k_mm_bf<float><<<dim3(4, 32), blk256, 0, stream>>>(abuf, wt_ha_pj, ha_proj_b, nullptr, ha, 2048, 256, 256);

    // ---- spatial branch: fused gate ----
    k_spatial<<<dim3(128), blk256, 0, stream>>>(xT, sa_w1, sa_b1, sa_w2, sa_b2, spre);
    k_gstats<<<dim3(64), blk256, 0, stream>>>(spre, stats);
    k_gnorm_apply<<<dim3(2048), blk256, 0, stream>>>(spre, stats, sa_gn_w, sa_gn_b, sp);

    // ---- shared gnorm stats of x; two affines ----
    k_gstats<<<dim3(64), blk256, 0, stream>>>(xT, stats + 128);
    k_gnorm_apply<<<dim3(2048), blk256, 0, stream>>>(xT, stats + 128, ra_gn_w, ra_gn_b, xn);
    k_gnorm_apply<<<dim3(2048), blk256, 0, stream>>>(xT, stats + 128, gn_w, gn_b, nf);

    // ---- both qkv projections (bf16 out), then ONE MFMA attention ----
    k_mm_bf<ushort><<<dim3(12, 32), blk256, 0, stream>>>(xn, wt_ra_qkv, nullptr, nullptr, qkv_ra_bf, 2048, 768, 256);
    k_mm_bf<ushort><<<dim3(12, 32), blk256, 0, stream>>>(nf, wt_toqkv, toqkv_b, nullptr, qkv_g_bf, 2048, 768, 256);
    k_attn_mfma<<<dim3(64, 16), blk256, 0, stream>>>(qkv_ra_bf, qkv_g_bf, abuf, qo);

    // ---- rotation proj (rotations identical by permutation equivariance) ----
    k_mm_bf<float><<<dim3(4, 32), blk256, 0, stream>>>(abuf, wt_ra_pj, ra_proj_b, xT, ro, 2048, 256, 256);

    // ---- combine + final proj + residual ----
    k_combine<<<dim3(2048), blk256, 0, stream>>>(sp, ha, qo, ro, attn_w, comb);
    k_mm_bf<float><<<dim3(4, 32), blk256, 0, stream>>>(comb, wt_pj, proj_b, xT, otok, 2048, 256, 256);
    k_transpose<<<dim3(8, 32, 2), blkT, 0, stream>>>(otok, out, 1024, 256);
}

// Round 15
// 261.735 us; speedup vs baseline: 3.3815x; 1.0378x over previous
//
#include <hip/hip_runtime.h>

#define CC 256
#define HWN 1024
#define EPSV 1e-5f

typedef __attribute__((ext_vector_type(8))) short bf16x8;
typedef __attribute__((ext_vector_type(4))) float f32x4;
typedef __attribute__((ext_vector_type(4))) unsigned short u16x4;

__device__ inline ushort f2bf(float f) {
    union { float f; unsigned u; } v; v.f = f;
    unsigned u = v.u;
    u += 0x7fffu + ((u >> 16) & 1u); // round-to-nearest-even
    return (ushort)(u >> 16);
}
__device__ inline void store_out(float* p, float v) { *p = v; }
__device__ inline void store_out(ushort* p, float v) { *p = f2bf(v); }

// ---------------- transpose (R,Cd) -> (Cd,R), batched, fp32 ----------------
__global__ __launch_bounds__(256) void k_transpose(const float* __restrict__ in,
                                                   float* __restrict__ out, int R, int Cd) {
    __shared__ float tile[32][33];
    int b = blockIdx.z;
    int r0 = blockIdx.y * 32, c0 = blockIdx.x * 32;
    int tx = threadIdx.x, ty = threadIdx.y; // 32 x 8
    const float* inb = in + (size_t)b * R * Cd;
    float* outb = out + (size_t)b * R * Cd;
#pragma unroll
    for (int i = 0; i < 32; i += 8)
        tile[ty + i][tx] = inb[(size_t)(r0 + ty + i) * Cd + c0 + tx];
    __syncthreads();
#pragma unroll
    for (int i = 0; i < 32; i += 8)
        outb[(size_t)(c0 + ty + i) * R + r0 + tx] = tile[tx][ty + i];
}

// ---------------- all six weight transpose+converts in ONE launch ----------------
__global__ __launch_bounds__(256) void k_wtc_all(const float* __restrict__ s0, const float* __restrict__ s1,
                                                 const float* __restrict__ s2, const float* __restrict__ s3,
                                                 const float* __restrict__ s4, const float* __restrict__ s5,
                                                 ushort* __restrict__ d0, ushort* __restrict__ d1,
                                                 ushort* __restrict__ d2, ushort* __restrict__ d3,
                                                 ushort* __restrict__ d4, ushort* __restrict__ d5) {
    __shared__ float tile[32][33];
    int z = blockIdx.z;
    const float* in; ushort* out; int N;
    switch (z) {
        case 0: in = s0; out = d0; N = 768; break;
        case 1: in = s1; out = d1; N = 768; break;
        case 2: in = s2; out = d2; N = 768; break;
        case 3: in = s3; out = d3; N = 256; break;
        case 4: in = s4; out = d4; N = 256; break;
        default: in = s5; out = d5; N = 256; break;
    }
    int n0 = blockIdx.x * 32;
    if (n0 >= N) return;
    int k0 = blockIdx.y * 32;
    int tx = threadIdx.x, ty = threadIdx.y; // 32 x 8
#pragma unroll
    for (int i = 0; i < 32; i += 8)
        tile[ty + i][tx] = in[(size_t)(k0 + ty + i) * N + n0 + tx];
    __syncthreads();
#pragma unroll
    for (int i = 0; i < 32; i += 8)
        out[(size_t)(n0 + ty + i) * 256 + k0 + tx] = f2bf(tile[tx][ty + i]);
}

// ---------------- bf16 MFMA matmul: out[M,N] = A fp32[M,K] @ Wt bf16[N,K]^T ----------------
template <typename OT>
__global__ __launch_bounds__(256) void k_mm_bf(const float* __restrict__ A,
                                               const ushort* __restrict__ Wt,
                                               const float* __restrict__ bias,
                                               const float* __restrict__ res,
                                               OT* __restrict__ Cp,
                                               int M, int N, int K) {
    __shared__ __align__(16) ushort As[64][40];
    __shared__ __align__(16) ushort Bs[64][40];
    int tid = threadIdx.x;
    int lane = tid & 63, wid = tid >> 6;
    int wr = (wid >> 1) * 32, wc = (wid & 1) * 32;
    int row0 = blockIdx.y * 64, col0 = blockIdx.x * 64;
    int sr = tid >> 2, skq = (tid & 3) * 8;
    int l16 = lane & 15, kg = (lane >> 4) * 8;
    f32x4 acc[2][2] = {};
    for (int k0 = 0; k0 < K; k0 += 32) {
        const float* ap = &A[(size_t)(row0 + sr) * K + k0 + skq];
        float4 a0 = *(const float4*)ap, a1 = *(const float4*)(ap + 4);
        bf16x8 av;
        av[0] = (short)f2bf(a0.x); av[1] = (short)f2bf(a0.y);
        av[2] = (short)f2bf(a0.z); av[3] = (short)f2bf(a0.w);
        av[4] = (short)f2bf(a1.x); av[5] = (short)f2bf(a1.y);
        av[6] = (short)f2bf(a1.z); av[7] = (short)f2bf(a1.w);
        *(bf16x8*)&As[sr][skq] = av;
        *(bf16x8*)&Bs[sr][skq] = *(const bf16x8*)&Wt[(size_t)(col0 + sr) * K + k0 + skq];
        __syncthreads();
        bf16x8 af0 = *(bf16x8*)&As[wr + l16][kg];
        bf16x8 af1 = *(bf16x8*)&As[wr + 16 + l16][kg];
        bf16x8 bf0 = *(bf16x8*)&Bs[wc + l16][kg];
        bf16x8 bf1 = *(bf16x8*)&Bs[wc + 16 + l16][kg];
        acc[0][0] = __builtin_amdgcn_mfma_f32_16x16x32_bf16(af0, bf0, acc[0][0], 0, 0, 0);
        acc[0][1] = __builtin_amdgcn_mfma_f32_16x16x32_bf16(af0, bf1, acc[0][1], 0, 0, 0);
        acc[1][0] = __builtin_amdgcn_mfma_f32_16x16x32_bf16(af1, bf0, acc[1][0], 0, 0, 0);
        acc[1][1] = __builtin_amdgcn_mfma_f32_16x16x32_bf16(af1, bf1, acc[1][1], 0, 0, 0);
        __syncthreads();
    }
#pragma unroll
    for (int fr = 0; fr < 2; fr++)
#pragma unroll
        for (int fc = 0; fc < 2; fc++)
#pragma unroll
            for (int reg = 0; reg < 4; reg++) {
                int r = row0 + wr + fr * 16 + (lane >> 4) * 4 + reg;
                int c = col0 + wc + fc * 16 + l16;
                float v = acc[fr][fc][reg];
                if (bias) v += bias[c];
                if (res) v += res[(size_t)r * N + c];
                store_out(&Cp[(size_t)r * N + c], v);
            }
}

// ---------------- final proj with fused 4-way softmax combine ----------------
// A = w0*sp + w1*ha + w2*qo + w3*ro (softmax(attn_w)); out = A@Wt + bias + res.
// M=2048, N=256, K=256 fixed-shape use.
__global__ __launch_bounds__(256) void k_mm_comb(const float* __restrict__ sp,
                                                 const float* __restrict__ hab,
                                                 const float* __restrict__ qo,
                                                 const float* __restrict__ ro,
                                                 const float* __restrict__ aw,
                                                 const ushort* __restrict__ Wt,
                                                 const float* __restrict__ bias,
                                                 const float* __restrict__ res,
                                                 float* __restrict__ Cp) {
    __shared__ __align__(16) ushort As[64][40];
    __shared__ __align__(16) ushort Bs[64][40];
    const int N = 256, K = 256;
    int tid = threadIdx.x;
    int lane = tid & 63, wid = tid >> 6;
    int wr = (wid >> 1) * 32, wc = (wid & 1) * 32;
    int row0 = blockIdx.y * 64, col0 = blockIdx.x * 64;
    int sr = tid >> 2, skq = (tid & 3) * 8;
    int l16 = lane & 15, kg = (lane >> 4) * 8;
    float a0 = aw[0], a1 = aw[1], a2 = aw[2], a3 = aw[3];
    float mx = fmaxf(fmaxf(a0, a1), fmaxf(a2, a3));
    float e0 = __expf(a0 - mx), e1 = __expf(a1 - mx), e2 = __expf(a2 - mx), e3 = __expf(a3 - mx);
    float inv = 1.f / (e0 + e1 + e2 + e3);
    float w0 = e0 * inv, w1 = e1 * inv, w2 = e2 * inv, w3 = e3 * inv;
    f32x4 acc[2][2] = {};
    for (int k0 = 0; k0 < K; k0 += 32) {
        size_t aoff = (size_t)(row0 + sr) * K + k0 + skq;
        float4 s0 = *(const float4*)&sp[aoff],  s1 = *(const float4*)&sp[aoff + 4];
        float4 h0 = *(const float4*)&hab[aoff], h1 = *(const float4*)&hab[aoff + 4];
        float4 q0 = *(const float4*)&qo[aoff],  q1 = *(const float4*)&qo[aoff + 4];
        float4 r0 = *(const float4*)&ro[aoff],  r1 = *(const float4*)&ro[aoff + 4];
        bf16x8 av;
        av[0] = (short)f2bf(w0 * s0.x + w1 * h0.x + w2 * q0.x + w3 * r0.x);
        av[1] = (short)f2bf(w0 * s0.y + w1 * h0.y + w2 * q0.y + w3 * r0.y);
        av[2] = (short)f2bf(w0 * s0.z + w1 * h0.z + w2 * q0.z + w3 * r0.z);
        av[3] = (short)f2bf(w0 * s0.w + w1 * h0.w + w2 * q0.w + w3 * r0.w);
        av[4] = (short)f2bf(w0 * s1.x + w1 * h1.x + w2 * q1.x + w3 * r1.x);
        av[5] = (short)f2bf(w0 * s1.y + w1 * h1.y + w2 * q1.y + w3 * r1.y);
        av[6] = (short)f2bf(w0 * s1.z + w1 * h1.z + w2 * q1.z + w3 * r1.z);
        av[7] = (short)f2bf(w0 * s1.w + w1 * h1.w + w2 * q1.w + w3 * r1.w);
        *(bf16x8*)&As[sr][skq] = av;
        *(bf16x8*)&Bs[sr][skq] = *(const bf16x8*)&Wt[(size_t)(col0 + sr) * K + k0 + skq];
        __syncthreads();
        bf16x8 af0 = *(bf16x8*)&As[wr + l16][kg];
        bf16x8 af1 = *(bf16x8*)&As[wr + 16 + l16][kg];
        bf16x8 bf0 = *(bf16x8*)&Bs[wc + l16][kg];
        bf16x8 bf1 = *(bf16x8*)&Bs[wc + 16 + l16][kg];
        acc[0][0] = __builtin_amdgcn_mfma_f32_16x16x32_bf16(af0, bf0, acc[0][0], 0, 0, 0);
        acc[0][1] = __builtin_amdgcn_mfma_f32_16x16x32_bf16(af0, bf1, acc[0][1], 0, 0, 0);
        acc[1][0] = __builtin_amdgcn_mfma_f32_16x16x32_bf16(af1, bf0, acc[1][0], 0, 0, 0);
        acc[1][1] = __builtin_amdgcn_mfma_f32_16x16x32_bf16(af1, bf1, acc[1][1], 0, 0, 0);
        __syncthreads();
    }
#pragma unroll
    for (int fr = 0; fr < 2; fr++)
#pragma unroll
        for (int fc = 0; fc < 2; fc++)
#pragma unroll
            for (int reg = 0; reg < 4; reg++) {
                int r = row0 + wr + fr * 16 + (lane >> 4) * 4 + reg;
                int c = col0 + wc + fc * 16 + l16;
                float v = acc[fr][fc][reg] + bias[c] + res[(size_t)r * N + c];
                Cp[(size_t)r * N + c] = v;
            }
}

// ---------------- fused spatial gate (unchanged) ----------------
__global__ __launch_bounds__(256) void k_spatial(const float* __restrict__ xT,
                                                 const float* __restrict__ w1,
                                                 const float* __restrict__ b1,
                                                 const float* __restrict__ w2,
                                                 const float* __restrict__ b2,
                                                 float* __restrict__ spre) {
    __shared__ float w1s[8192];
    __shared__ float w2s[8192];
    __shared__ float xs[16][260];
    __shared__ float s1s[16][36];
    int tid = threadIdx.x;
    int tok0 = blockIdx.x * 16;
    {
        const float4* w1v = (const float4*)w1;
        const float4* w2v = (const float4*)w2;
        float4* w1sv = (float4*)w1s;
        float4* w2sv = (float4*)w2s;
        for (int i = tid; i < 2048; i += 256) {
            w1sv[i] = w1v[i];
            w2sv[i] = w2v[i];
        }
        for (int i = tid; i < 1024; i += 256) {
            int tok = i >> 6, part = i & 63;
            *(float4*)&xs[tok][part * 4] =
                *(const float4*)&xT[(size_t)(tok0 + tok) * 256 + part * 4];
        }
    }
    __syncthreads();
    int tok = tid >> 4, col = tid & 15;
    {
        float a0 = b1[col], a1 = b1[col + 16];
        for (int k = 0; k < 256; k++) {
            float xv = xs[tok][k];
            a0 = fmaf(xv, w1s[k * 32 + col], a0);
            a1 = fmaf(xv, w1s[k * 32 + col + 16], a1);
        }
        s1s[tok][col] = fmaxf(a0, 0.f);
        s1s[tok][col + 16] = fmaxf(a1, 0.f);
    }
    __syncthreads();
#pragma unroll 4
    for (int j = 0; j < 16; j++) {
        int c = col + j * 16;
        float a = b2[c];
#pragma unroll
        for (int k = 0; k < 32; k++)
            a = fmaf(s1s[tok][k], w2s[k * 256 + c], a);
        float sg = 1.f / (1.f + __expf(-a));
        spre[(size_t)(tok0 + tok) * 256 + c] = xs[tok][c] * (1.f + sg);
    }
}

// ---------------- group-norm stats ----------------
__global__ __launch_bounds__(256) void k_gstats(const float* __restrict__ in, float* __restrict__ stats) {
    int bg = blockIdx.x;
    int b = bg >> 5, g = bg & 31;
    int tid = threadIdx.x;
    float s = 0.f, s2 = 0.f;
    for (int idx = tid; idx < HWN * 8; idx += 256) {
        int t = idx >> 3, cc = idx & 7;
        float v = in[(size_t)(b * HWN + t) * CC + g * 8 + cc];
        s += v;
        s2 += v * v;
    }
    __shared__ float sh[2][256];
    sh[0][tid] = s; sh[1][tid] = s2;
    __syncthreads();
    for (int off = 128; off > 0; off >>= 1) {
        if (tid < off) { sh[0][tid] += sh[0][tid + off]; sh[1][tid] += sh[1][tid + off]; }
        __syncthreads();
    }
    if (tid == 0) {
        float mean = sh[0][0] * (1.f / (HWN * 8));
        float var = sh[1][0] * (1.f / (HWN * 8)) - mean * mean;
        stats[bg * 2] = mean;
        stats[bg * 2 + 1] = rsqrtf(var + EPSV);
    }
}

__global__ __launch_bounds__(256) void k_gnorm_apply(const float* __restrict__ in,
                                                     const float* __restrict__ stats,
                                                     const float* __restrict__ w,
                                                     const float* __restrict__ bb,
                                                     float* __restrict__ out) {
    int idx = blockIdx.x * 256 + threadIdx.x;
    int c = idx & 255;
    int t = idx >> 8;
    int b = t >> 10;
    int g = c >> 3;
    float mean = stats[(b * 32 + g) * 2], rstd = stats[(b * 32 + g) * 2 + 1];
    out[idx] = (in[idx] - mean) * rstd * w[c] + bb[c];
}

// dual-affine: one xT read, two gnorm outputs (ra-norm and global-norm share stats)
__global__ __launch_bounds__(256) void k_gnorm_apply2(const float* __restrict__ in,
                                                      const float* __restrict__ stats,
                                                      const float* __restrict__ w1,
                                                      const float* __restrict__ b1,
                                                      const float* __restrict__ w2,
                                                      const float* __restrict__ b2,
                                                      float* __restrict__ o1,
                                                      float* __restrict__ o2) {
    int idx = blockIdx.x * 256 + threadIdx.x;
    int c = idx & 255;
    int t = idx >> 8;
    int b = t >> 10;
    int g = c >> 3;
    float mean = stats[(b * 32 + g) * 2], rstd = stats[(b * 32 + g) * 2 + 1];
    float nrm = (in[idx] - mean) * rstd;
    o1[idx] = nrm * w1[c] + b1[c];
    o2[idx] = nrm * w2[c] + b2[c];
}

// ---------------- MFMA flash attention, bf16 qkv inputs (unchanged from R14) ----------------
__global__ __launch_bounds__(256, 4) void k_attn_mfma(const ushort* __restrict__ qkv0,
                                                      const ushort* __restrict__ qkv1,
                                                      float* __restrict__ out0,
                                                      float* __restrict__ out1) {
    __shared__ __align__(16) ushort K_lds[32][24];
    __shared__ __align__(16) ushort V_lds[16][40];
    __shared__ __align__(16) ushort P_lds[4][16][40];
    __shared__ float l_sh[4][16];
    int gx = blockIdx.x;
    int src = gx >> 5, bh = gx & 31;
    int b = bh >> 4, h = bh & 15;
    const ushort* qkv = src ? qkv1 : qkv0;
    float* out = src ? out1 : out0;
    int tid = threadIdx.x;
    int lane = tid & 63, wid = tid >> 6;
    int l16 = lane & 15, g = lane >> 4;
    const ushort* base = qkv + (size_t)b * HWN * 768 + h * 16;
    int q0 = blockIdx.y * 64 + wid * 16;
    bf16x8 qf = {};
    if (g < 2)
        qf = *(const bf16x8*)(base + (size_t)(q0 + l16) * 768 + g * 8);
    f32x4 acc = {};
    float lsum = 0.f;
    int skey = tid >> 3, spiece = tid & 7;
    for (int kb = 0; kb < 32; kb++) {
        __syncthreads();
        {
            const ushort* rp = base + (size_t)(kb * 32 + skey) * 768;
            if (spiece < 4) {
                *(u16x4*)&K_lds[skey][spiece * 4] = *(const u16x4*)(rp + 256 + spiece * 4);
            } else {
                int dd = (spiece - 4) * 4;
                u16x4 vv = *(const u16x4*)(rp + 512 + dd);
                V_lds[dd][skey]     = vv[0];
                V_lds[dd + 1][skey] = vv[1];
                V_lds[dd + 2][skey] = vv[2];
                V_lds[dd + 3][skey] = vv[3];
            }
        }
        __syncthreads();
#pragma unroll
        for (int sb = 0; sb < 2; sb++) {
            bf16x8 kf = {};
            if (g < 2)
                kf = *(const bf16x8*)&K_lds[sb * 16 + l16][g * 8];
            f32x4 st = {};
            st = __builtin_amdgcn_mfma_f32_16x16x32_bf16(kf, qf, st, 0, 0, 0);
            float e0 = __expf(st[0] * 0.25f);
            float e1 = __expf(st[1] * 0.25f);
            float e2 = __expf(st[2] * 0.25f);
            float e3 = __expf(st[3] * 0.25f);
            lsum += (e0 + e1) + (e2 + e3);
            u16x4 pp;
            pp[0] = f2bf(e0); pp[1] = f2bf(e1); pp[2] = f2bf(e2); pp[3] = f2bf(e3);
            *(u16x4*)&P_lds[wid][l16][sb * 16 + g * 4] = pp;
        }
        bf16x8 pf = *(const bf16x8*)&P_lds[wid][l16][g * 8];
        bf16x8 vf = *(const bf16x8*)&V_lds[l16][g * 8];
        acc = __builtin_amdgcn_mfma_f32_16x16x32_bf16(pf, vf, acc, 0, 0, 0);
    }
    lsum += __shfl_xor(lsum, 16);
    lsum += __shfl_xor(lsum, 32);
    if (g == 0) l_sh[wid][l16] = lsum;
#pragma unroll
    for (int r = 0; r < 4; r++) {
        float inv = 1.f / l_sh[wid][g * 4 + r];
        out[(size_t)(b * HWN + q0 + g * 4 + r) * CC + h * 16 + l16] = acc[r] * inv;
    }
}

// ---------------- halo attention with in-kernel gather ----------------
// qkv_tok: (B*HWN, 768) token-major fp32 (q|k|v). Gather K/V by halo geometry
// (patch pos (i,j) -> token y*32+xx, zero OOB — identical to patch(x)@W since
// halo qkv has no bias). Queries read at center tokens directly.
__global__ __launch_bounds__(64) void k_attn_halo(const float* __restrict__ qkv_tok,
                                                  float* __restrict__ out) {
    int blk = blockIdx.x;
    int h = blockIdx.y;
    int tid = threadIdx.x;
    __shared__ float Ks[196][16];
    __shared__ float Vs[196][16];
    int b = blk >> 4, hb = (blk >> 2) & 3, wb = blk & 3;
    const float* base = qkv_tok + (size_t)b * HWN * 768;
    for (int idx = tid; idx < 196 * 4; idx += 64) {
        int kk = idx >> 2, part = idx & 3;
        int i = kk / 14, j = kk % 14;
        int y = hb * 8 + i - 3, xx = wb * 8 + j - 3;
        float4 kv = make_float4(0.f, 0.f, 0.f, 0.f);
        float4 vv = make_float4(0.f, 0.f, 0.f, 0.f);
        if (y >= 0 && y < 32 && xx >= 0 && xx < 32) {
            const float* rowp = base + (size_t)(y * 32 + xx) * 768 + h * 16 + part * 4;
            kv = *(const float4*)(rowp + 256);
            vv = *(const float4*)(rowp + 512);
        }
        *(float4*)&Ks[kk][part * 4] = kv;
        *(float4*)&Vs[kk][part * 4] = vv;
    }
    __syncthreads();
    int ci = tid >> 3, cj = tid & 7;
    int tq = (hb * 8 + ci) * 32 + wb * 8 + cj;
    float q[16];
    {
        const float4* qp = (const float4*)(base + (size_t)tq * 768 + h * 16);
#pragma unroll
        for (int i = 0; i < 4; i++) {
            float4 v = qp[i];
            q[i * 4] = v.x; q[i * 4 + 1] = v.y; q[i * 4 + 2] = v.z; q[i * 4 + 3] = v.w;
        }
    }
    float l = 0.f, acc[16] = {};
    for (int k4 = 0; k4 < 196; k4 += 4) {
        float s[4] = {};
#pragma unroll
        for (int j = 0; j < 4; j++) {
            const float4* kp = (const float4*)&Ks[k4 + j][0];
#pragma unroll
            for (int i = 0; i < 4; i++) {
                float4 kv = kp[i];
                s[j] = fmaf(q[i * 4], kv.x, s[j]);
                s[j] = fmaf(q[i * 4 + 1], kv.y, s[j]);
                s[j] = fmaf(q[i * 4 + 2], kv.z, s[j]);
                s[j] = fmaf(q[i * 4 + 3], kv.w, s[j]);
            }
        }
        float e[4];
#pragma unroll
        for (int j = 0; j < 4; j++) e[j] = __expf(s[j] * 0.25f);
        l += (e[0] + e[1]) + (e[2] + e[3]);
#pragma unroll
        for (int j = 0; j < 4; j++) {
            const float4* vp = (const float4*)&Vs[k4 + j][0];
#pragma unroll
            for (int i = 0; i < 4; i++) {
                float4 vv = vp[i];
                acc[i * 4]     = fmaf(e[j], vv.x, acc[i * 4]);
                acc[i * 4 + 1] = fmaf(e[j], vv.y, acc[i * 4 + 1]);
                acc[i * 4 + 2] = fmaf(e[j], vv.z, acc[i * 4 + 2]);
                acc[i * 4 + 3] = fmaf(e[j], vv.w, acc[i * 4 + 3]);
            }
        }
    }
    float inv = 1.f / l;
    float4* op = (float4*)(out + (size_t)(b * HWN + tq) * CC + h * 16);
#pragma unroll
    for (int i = 0; i < 4; i++)
        op[i] = make_float4(acc[i * 4] * inv, acc[i * 4 + 1] * inv, acc[i * 4 + 2] * inv, acc[i * 4 + 3] * inv);
}

extern "C" void kernel_launch(void* const* d_in, const int* in_sizes, int n_in,
                              void* d_out, int out_size, void* d_ws, size_t ws_size,
                              hipStream_t stream) {
    const float* x        = (const float*)d_in[0];
    const float* sa_w1    = (const float*)d_in[1];
    const float* sa_b1    = (const float*)d_in[2];
    const float* sa_w2    = (const float*)d_in[3];
    const float* sa_b2    = (const float*)d_in[4];
    const float* sa_gn_w  = (const float*)d_in[5];
    const float* sa_gn_b  = (const float*)d_in[6];
    const float* ha_qkv_w = (const float*)d_in[7];
    const float* ha_proj_w= (const float*)d_in[8];
    const float* ha_proj_b= (const float*)d_in[9];
    const float* ra_gn_w  = (const float*)d_in[10];
    const float* ra_gn_b  = (const float*)d_in[11];
    const float* ra_qkv_w = (const float*)d_in[12];
    const float* ra_proj_w= (const float*)d_in[13];
    const float* ra_proj_b= (const float*)d_in[14];
    const float* gn_w     = (const float*)d_in[15];
    const float* gn_b     = (const float*)d_in[16];
    const float* toqkv_w  = (const float*)d_in[17];
    const float* toqkv_b  = (const float*)d_in[18];
    const float* attn_w   = (const float*)d_in[19];
    const float* proj_w   = (const float*)d_in[20];
    const float* proj_b   = (const float*)d_in[21];
    float* out = (float*)d_out;

    float* ws = (float*)d_ws;
    size_t off = 0;
    float* xT   = ws + off; off += 524288;
    float* sp   = ws + off; off += 524288;
    float* xn   = ws + off; off += 524288;
    float* nf   = ws + off; off += 524288;
    float* ha   = ws + off; off += 524288;
    float* ro   = ws + off; off += 524288;
    float* qo   = ws + off; off += 524288;
    float* abuf = ws + off; off += 524288;
    float* stats= ws + off; off += 256;
    float* big0 = ws + off; off += 4816896;
    float* big1 = ws + off; off += 1605632;
    // bf16 weight buffers ([N][K] transposed)
    ushort* wt_ha_qkv = (ushort*)(ws + off); off += 98304;
    ushort* wt_ra_qkv = (ushort*)(ws + off); off += 98304;
    ushort* wt_toqkv  = (ushort*)(ws + off); off += 98304;
    ushort* wt_ha_pj  = (ushort*)(ws + off); off += 32768;
    ushort* wt_ra_pj  = (ushort*)(ws + off); off += 32768;
    ushort* wt_pj     = (ushort*)(ws + off); off += 32768;
    float* otok = nf; // nf dead after qkv_g
    float* qkv_tok_ha = big0;                                 // fp32 2048x768
    ushort* qkv_ra_bf = (ushort*)(big0 + 1572864);            // bf16 2048x768
    ushort* qkv_g_bf  = (ushort*)(big0 + 1572864 + 786432);   // bf16 2048x768
    float* spre = big1;

    dim3 blk256(256), blkT(32, 8);

    // ---- weights (one launch) ----
    k_wtc_all<<<dim3(24, 8, 6), blkT, 0, stream>>>(
        ha_qkv_w, ra_qkv_w, toqkv_w, ha_proj_w, ra_proj_w, proj_w,
        wt_ha_qkv, wt_ra_qkv, wt_toqkv, wt_ha_pj, wt_ra_pj, wt_pj);

    // x (B,256,1024) -> xT (B,1024,256) token-major
    k_transpose<<<dim3(32, 8, 2), blkT, 0, stream>>>(x, xT, 256, 1024);

    // ---- halo branch: qkv on TOKENS (3x less matmul), gather inside attention ----
    k_mm_bf<float><<<dim3(12, 32), blk256, 0, stream>>>(xT, wt_ha_qkv, nullptr, nullptr, qkv_tok_ha, 2048, 768, 256);
    k_attn_halo<<<dim3(32, 16), dim3(64), 0, stream>>>(qkv_tok_ha, abuf);
    k_mm_bf<float><<<dim3(4, 32), blk256, 0, stream>>>(abuf, wt_ha_pj, ha_proj_b, nullptr, ha, 2048, 256, 256);

    // ---- spatial branch ----
    k_spatial<<<dim3(128), blk256, 0, stream>>>(xT, sa_w1, sa_b1, sa_w2, sa_b2, spre);
    k_gstats<<<dim3(64), blk256, 0, stream>>>(spre, stats);
    k_gnorm_apply<<<dim3(2048), blk256, 0, stream>>>(spre, stats, sa_gn_w, sa_gn_b, sp);

    // ---- shared gnorm stats of x; dual affine in one pass ----
    k_gstats<<<dim3(64), blk256, 0, stream>>>(xT, stats + 128);
    k_gnorm_apply2<<<dim3(2048), blk256, 0, stream>>>(xT, stats + 128, ra_gn_w, ra_gn_b, gn_w, gn_b, xn, nf);

    // ---- both qkv projections (bf16 out), then ONE MFMA attention ----
    k_mm_bf<ushort><<<dim3(12, 32), blk256, 0, stream>>>(xn, wt_ra_qkv, nullptr, nullptr, qkv_ra_bf, 2048, 768, 256);
    k_mm_bf<ushort><<<dim3(12, 32), blk256, 0, stream>>>(nf, wt_toqkv, toqkv_b, nullptr, qkv_g_bf, 2048, 768, 256);
    k_attn_mfma<<<dim3(64, 16), blk256, 0, stream>>>(qkv_ra_bf, qkv_g_bf, abuf, qo);

    // ---- rotation proj ----
    k_mm_bf<float><<<dim3(4, 32), blk256, 0, stream>>>(abuf, wt_ra_pj, ra_proj_b, xT, ro, 2048, 256, 256);

    // ---- fused combine + final proj + residual ----
    k_mm_comb<<<dim3(4, 32), blk256, 0, stream>>>(sp, ha, qo, ro, attn_w, wt_pj, proj_b, xT, otok);
    k_transpose<<<dim3(8, 32, 2), blkT, 0, stream>>>(otok, out, 1024, 256);
}